// Round 15
// baseline (655.758 us; speedup 1.0000x reference)
//
#include <hip/hip_runtime.h>
#include <hip/hip_bf16.h>
#include <math.h>

#define BB 8
#define HH 128
#define WW 128
#define HW (HH*WW)          // 16384
#define NPIX (BB*HW)        // 131072

typedef unsigned short u16;
typedef __attribute__((ext_vector_type(4))) float  floatx4;
typedef __attribute__((ext_vector_type(4))) short  short4v;
typedef __attribute__((ext_vector_type(8))) short  short8v;

static __device__ __forceinline__ float gelu_exact(float x){
    return 0.5f*x*(1.0f+erff(x*0.70710678118654752440f));
}
static __device__ __forceinline__ float b2f(u16 v){
    union { unsigned u; float f; } x; x.u = ((unsigned)v)<<16; return x.f;
}
static __device__ __forceinline__ u16 f2b(float f){
    __hip_bfloat16 h = __float2bfloat16(f);
    return *(u16*)&h;
}

// ---------- weight prep: fp32 -> bf16 GEMM weights + transposed pos weights ----------
#define WQ 27648
#define WP 36864
#define WG 18432
#define WF1 49152
#define WF2 49152
#define WTOT (WQ+WP+WG+WF1+WF2)   // 181248
__global__ __launch_bounds__(256) void wprep_k(const float* __restrict__ a,
    const float* __restrict__ b, const float* __restrict__ c,
    const float* __restrict__ d, const float* __restrict__ e,
    const float* __restrict__ posw, u16* __restrict__ o, float* __restrict__ wT)
{
    int i = blockIdx.x*256 + threadIdx.x;
    if (i < 1728){   // wT[tap][192]: wT[tap*192+c] = posw[c*9+tap]
        wT[i] = posw[(i%192)*9 + (i/192)];
    }
    if (i >= WTOT) return;
    float v;
    if (i < WQ) v = a[i];
    else if (i < WQ+WP) v = b[i-WQ];
    else if (i < WQ+WP+WG) v = c[i-WQ-WP];
    else if (i < WQ+WP+WG+WF1) v = d[i-WQ-WP-WG];
    else v = e[i-WQ-WP-WG-WF1];
    o[i] = f2b(v);
}

// ---------- fused pos depthwise 3x3 + bias + residual + LN1 -> A(bf16), Y(bf16) ----------
// block = 192 thr = 4 pixels x 48 c4-groups; per-pixel LDS reduction (deterministic)
__global__ __launch_bounds__(192) void pos_conv_ln_k(const float* __restrict__ x,
    const float* __restrict__ wT, const float* __restrict__ bias,
    const float* __restrict__ ln1g, const float* __restrict__ ln1b,
    u16* __restrict__ outA, u16* __restrict__ outY)
{
    __shared__ float sred[4][48];
    __shared__ float qred[4][48];
    int bid = blockIdx.x;
    int sb = (bid & 7)*(gridDim.x >> 3) + (bid >> 3);   // XCD image-slice swizzle
    int t = threadIdx.x;
    int c4 = t % 48;
    int p  = t / 48;
    size_t pix = (size_t)sb*4 + p;
    int wx = (int)(pix % WW);
    int hy = (int)((pix / WW) % HH);
    int b  = (int)(pix / HW);
    int c0 = c4*4;

    int hcl[3], wcl[3];
    float my[3], mx[3];
    #pragma unroll
    for (int i=0;i<3;i++){
        int hh = hy + i - 1;
        my[i] = ((unsigned)hh < HH) ? 1.f : 0.f;
        hcl[i] = min(max(hh,0),HH-1);
        int ww2 = wx + i - 1;
        mx[i] = ((unsigned)ww2 < WW) ? 1.f : 0.f;
        wcl[i] = min(max(ww2,0),WW-1);
    }
    const float4* x4 = (const float4*)x;
    float4 xv[3][3];
    #pragma unroll
    for (int i=0;i<3;i++){
        size_t rb = ((size_t)(b*HH + hcl[i])*WW)*48 + c4;
        #pragma unroll
        for (int k=0;k<3;k++)
            xv[i][k] = x4[rb + (size_t)wcl[k]*48];
    }
    floatx4 wv[9];
    #pragma unroll
    for (int tap=0; tap<9; tap++)
        wv[tap] = *(const floatx4*)&wT[tap*192 + c0];

    float4 acc = *(const float4*)(bias + c0);
    #pragma unroll
    for (int i=0;i<3;i++){
        #pragma unroll
        for (int k=0;k<3;k++){
            float m = my[i]*mx[k];
            floatx4 w = wv[i*3+k];
            acc.x = fmaf(w[0]*m, xv[i][k].x, acc.x);
            acc.y = fmaf(w[1]*m, xv[i][k].y, acc.y);
            acc.z = fmaf(w[2]*m, xv[i][k].z, acc.z);
            acc.w = fmaf(w[3]*m, xv[i][k].w, acc.w);
        }
    }
    acc.x += xv[1][1].x; acc.y += xv[1][1].y; acc.z += xv[1][1].z; acc.w += xv[1][1].w;

    // store A (bf16)
    short4v oa; oa.x=(short)f2b(acc.x); oa.y=(short)f2b(acc.y);
    oa.z=(short)f2b(acc.z); oa.w=(short)f2b(acc.w);
    *(short4v*)(outA + pix*192 + c0) = oa;

    // LN1 over the 192 channels of this pixel (fp32 pre-rounded values)
    sred[p][c4] = acc.x + acc.y + acc.z + acc.w;
    qred[p][c4] = acc.x*acc.x + acc.y*acc.y + acc.z*acc.z + acc.w*acc.w;
    __syncthreads();
    float ssum = 0.f, qsum = 0.f;
    #pragma unroll
    for (int j=0;j<48;j++){ ssum += sred[p][j]; qsum += qred[p][j]; }
    float mean = ssum*(1.f/192.f);
    float var  = qsum*(1.f/192.f) - mean*mean;
    float inv  = rsqrtf(var + 1e-6f);
    floatx4 g4 = *(const floatx4*)(ln1g + c0);
    floatx4 b4 = *(const floatx4*)(ln1b + c0);
    short4v oy;
    oy.x = (short)f2b((acc.x-mean)*inv*g4[0] + b4[0]);
    oy.y = (short)f2b((acc.y-mean)*inv*g4[1] + b4[1]);
    oy.z = (short)f2b((acc.z-mean)*inv*g4[2] + b4[2]);
    oy.w = (short)f2b((acc.w-mean)*inv*g4[3] + b4[3]);
    *(short4v*)(outY + pix*192 + c0) = oy;
}

// ---------- standalone pos conv (multi-chunk fallback) ----------
__global__ __launch_bounds__(192) void pos_conv_k(const float* __restrict__ x,
    const float* __restrict__ wT, const float* __restrict__ bias, u16* __restrict__ out)
{
    int bid = blockIdx.x;
    int sb = (bid & 7)*(gridDim.x >> 3) + (bid >> 3);
    int t = threadIdx.x;
    int c4 = t % 48;
    size_t pix = (size_t)sb*4 + (t/48);
    int wx = (int)(pix % WW);
    int hy = (int)((pix / WW) % HH);
    int b  = (int)(pix / HW);
    int c0 = c4*4;
    int hcl[3], wcl[3];
    float my[3], mx[3];
    #pragma unroll
    for (int i=0;i<3;i++){
        int hh = hy + i - 1;
        my[i] = ((unsigned)hh < HH) ? 1.f : 0.f;
        hcl[i] = min(max(hh,0),HH-1);
        int ww2 = wx + i - 1;
        mx[i] = ((unsigned)ww2 < WW) ? 1.f : 0.f;
        wcl[i] = min(max(ww2,0),WW-1);
    }
    const float4* x4 = (const float4*)x;
    float4 xv[3][3];
    #pragma unroll
    for (int i=0;i<3;i++){
        size_t rb = ((size_t)(b*HH + hcl[i])*WW)*48 + c4;
        #pragma unroll
        for (int k=0;k<3;k++)
            xv[i][k] = x4[rb + (size_t)wcl[k]*48];
    }
    floatx4 wv[9];
    #pragma unroll
    for (int tap=0; tap<9; tap++)
        wv[tap] = *(const floatx4*)&wT[tap*192 + c0];
    float4 acc = *(const float4*)(bias + c0);
    #pragma unroll
    for (int i=0;i<3;i++){
        #pragma unroll
        for (int k=0;k<3;k++){
            float m = my[i]*mx[k];
            floatx4 w = wv[i*3+k];
            acc.x = fmaf(w[0]*m, xv[i][k].x, acc.x);
            acc.y = fmaf(w[1]*m, xv[i][k].y, acc.y);
            acc.z = fmaf(w[2]*m, xv[i][k].z, acc.z);
            acc.w = fmaf(w[3]*m, xv[i][k].w, acc.w);
        }
    }
    acc.x += xv[1][1].x; acc.y += xv[1][1].y; acc.z += xv[1][1].z; acc.w += xv[1][1].w;
    short4v o; o.x=(short)f2b(acc.x); o.y=(short)f2b(acc.y);
    o.z=(short)f2b(acc.z); o.w=(short)f2b(acc.w);
    *(short4v*)(out + pix*192 + c0) = o;
}

// ---------- LayerNorm over C=192, bf16 in -> bf16 out, wave per pixel ----------
__global__ __launch_bounds__(256) void ln_k(const u16* __restrict__ in,
    const float* __restrict__ g, const float* __restrict__ bta, u16* __restrict__ out)
{
    int wid = threadIdx.x >> 6, lane = threadIdx.x & 63;
    size_t pix = (size_t)blockIdx.x*4 + wid;
    const u16* row = in + pix*192;
    float x0 = b2f(row[lane]), x1 = b2f(row[lane+64]), x2 = b2f(row[lane+128]);
    float s = x0+x1+x2;
    float q = x0*x0 + x1*x1 + x2*x2;
    #pragma unroll
    for (int off=32; off; off>>=1){ s += __shfl_xor(s,off,64); q += __shfl_xor(q,off,64); }
    float mean = s*(1.f/192.f);
    float var  = q*(1.f/192.f) - mean*mean;
    float inv  = rsqrtf(var + 1e-6f);
    u16* orow = out + pix*192;
    orow[lane]     = f2b((x0-mean)*inv*g[lane]     + bta[lane]);
    orow[lane+64]  = f2b((x1-mean)*inv*g[lane+64]  + bta[lane+64]);
    orow[lane+128] = f2b((x2-mean)*inv*g[lane+128] + bta[lane+128]);
}

// ---------- bf16 MFMA GEMM: W-in-LDS once, A streamed; grid=(m,n) for XCD A-locality ----------
#define GM_NONE 0
#define GM_RES 1
#define GM_GELU_BN 2
#define GM_BN_RES 3
#define GM_BIAS_RELU 4
#define WSTR 264   // LDS row stride in shorts: 528B = 132 dw; 132%32=4 -> 2-way only

template<int MODE, int K, bool SPLIT=false>
__global__ __launch_bounds__(256) void gemm_bf16_k(
    const u16* __restrict__ A, int lda,
    const u16* __restrict__ A2, int lda2,
    const u16* __restrict__ W,
    void* __restrict__ Cv, int ldc,
    const u16* __restrict__ R, int ldr,
    const float* __restrict__ bg, const float* __restrict__ bb,
    const float* __restrict__ bm_, const float* __restrict__ bv,
    int N)
{
    __shared__ u16 Ws[64*WSTR];
    int t = threadIdx.x;
    int bn = blockIdx.y * 64;
    int bm = blockIdx.x * 256;
    {
        constexpr int KQ = K/4;
        int brow = t >> 2, bq = t & 3;
        int n = bn + brow;
        bool nv = n < N;
        const u16* src = W + (size_t)n*K + bq*KQ;
        #pragma unroll
        for (int j=0; j<KQ; j+=8){
            short8v v = {};
            if (nv) v = *(const short8v*)(src + j);
            *(short8v*)&Ws[brow*WSTR + bq*KQ + j] = v;
        }
    }
    __syncthreads();
    int wave = t >> 6, lane = t & 63;
    int wm = wave*64;
    int lr = lane & 15, lk = lane >> 4;
    const u16* arow  = A + (size_t)(bm + wm + lr)*lda + lk*8;
    const u16* arow2 = SPLIT ? (A2 + (size_t)(bm + wm + lr)*lda2 + lk*8) : nullptr;
    floatx4 acc[4][4] = {};
    #pragma unroll
    for (int k0 = 0; k0 < K; k0 += 32){
        short8v afr[4];
        if (SPLIT && k0 >= 96){
            #pragma unroll
            for (int m=0;m<4;m++)
                afr[m] = *(const short8v*)(arow2 + (size_t)(m*16)*lda2 + (k0-96));
        } else {
            #pragma unroll
            for (int m=0;m<4;m++)
                afr[m] = *(const short8v*)(arow + (size_t)(m*16)*lda + k0);
        }
        #pragma unroll
        for (int n2=0;n2<4;n2++){
            short8v bfr = *(const short8v*)&Ws[(n2*16+lr)*WSTR + k0 + lk*8];
            #pragma unroll
            for (int m=0;m<4;m++)
                acc[m][n2] = __builtin_amdgcn_mfma_f32_16x16x32_bf16(afr[m], bfr, acc[m][n2], 0,0,0);
        }
    }
    #pragma unroll
    for (int m=0;m<4;m++){
        #pragma unroll
        for (int n2=0;n2<4;n2++){
            int gcol = bn + n2*16 + lr;
            if (gcol >= N) continue;
            #pragma unroll
            for (int rg=0; rg<4; rg++){
                int grow = bm + wm + m*16 + lk*4 + rg;
                float v = acc[m][n2][rg];
                if (MODE == GM_RES){
                    v += b2f(R[(size_t)grow*ldr + gcol]);
                    ((u16*)Cv)[(size_t)grow*ldc + gcol] = f2b(v);
                } else if (MODE == GM_BN_RES){
                    float bnv = (v - bm_[gcol])*rsqrtf(bv[gcol]+1e-5f)*bg[gcol] + bb[gcol];
                    ((float*)Cv)[(size_t)grow*ldc + gcol] = bnv + b2f(R[(size_t)grow*ldr + gcol]);
                } else if (MODE == GM_GELU_BN){
                    float gl = gelu_exact(v);
                    v = (gl - bm_[gcol])*rsqrtf(bv[gcol]+1e-5f)*bg[gcol] + bb[gcol];
                    ((u16*)Cv)[(size_t)grow*ldc + gcol] = f2b(v);
                } else if (MODE == GM_BIAS_RELU){
                    ((u16*)Cv)[(size_t)grow*ldc + gcol] = f2b(fmaxf(v + bg[gcol], 0.f));
                } else {
                    ((u16*)Cv)[(size_t)grow*ldc + gcol] = f2b(v);
                }
            }
        }
    }
}

// ---------- gate stage 2: sigmoid(G1 @ w2 + b2) per pixel, G1 bf16 ----------
__global__ __launch_bounds__(256) void gate2_k(const u16* __restrict__ G1,
    const float* __restrict__ w2, const float* __restrict__ b2, float* __restrict__ gpix)
{
    int pix = blockIdx.x*256 + threadIdx.x;
    const short4v* g4 = (const short4v*)(G1 + (size_t)pix*96);
    const float4* w4 = (const float4*)w2;
    float s = b2[0];
    #pragma unroll
    for (int j=0;j<24;j++){
        short4v g = g4[j]; float4 w = w4[j];
        s += b2f((u16)g.x)*w.x + b2f((u16)g.y)*w.y + b2f((u16)g.z)*w.z + b2f((u16)g.w)*w.w;
    }
    gpix[pix] = 1.f/(1.f+expf(-s));
}

// ---------- deterministic mean of gpix -> dyn_k ----------
__global__ __launch_bounds__(1024) void gate_reduce_k(const float* __restrict__ gpix,
                                                      float* __restrict__ dynk)
{
    __shared__ float sm[16];
    float s = 0.f;
    for (int i=threadIdx.x; i<NPIX; i+=1024) s += gpix[i];
    #pragma unroll
    for (int off=32; off; off>>=1) s += __shfl_xor(s,off,64);
    int wid = threadIdx.x>>6, lane = threadIdx.x&63;
    if (lane==0) sm[wid]=s;
    __syncthreads();
    if (threadIdx.x==0){
        float tot=0.f; for (int i=0;i<16;i++) tot+=sm[i];
        *dynk = floorf(12.0f * (tot/(float)NPIX));
    }
}

// ---------- qkv depthwise 3x3 (288 ch), 4-col sweep, LDS weights, XCD-swizzled ----------
#define QPOS(c8) ((c8)*8 + ((c8)>>2)*4)
#define QTAPSTRIDE 324
__global__ __launch_bounds__(256) void qkv_dw_k(const u16* __restrict__ in,
    const float* __restrict__ w, u16* __restrict__ out, size_t planeStride)
{
    __shared__ float wlds[9*QTAPSTRIDE];
    int t = threadIdx.x;
    for (int i=t; i<2592; i+=256){
        int tap = i/288, cc = i%288;
        wlds[tap*QTAPSTRIDE + QPOS(cc>>3) + (cc&7)] = w[cc*9+tap];
    }
    __syncthreads();
    int bid = blockIdx.x;
    int sb = (bid & 7)*(gridDim.x >> 3) + (bid >> 3);
    int idx = sb*256 + t;
    int c8 = idx % 36; int pq = idx / 36;
    int xg = pq & 31; int hy = (pq >> 5) & 127; int img = pq >> 12;
    int x0 = xg*4;
    int c0 = c8*8;
    int wofs = QPOS(c8);
    float acc[4][8] = {{0.f}};
    #pragma unroll
    for (int ky=0; ky<3; ky++){
        int hh = hy + ky - 1; if ((unsigned)hh >= HH) continue;
        float wr[3][8];
        #pragma unroll
        for (int kx=0; kx<3; kx++){
            floatx4 wa = *(const floatx4*)&wlds[(ky*3+kx)*QTAPSTRIDE + wofs];
            floatx4 wb = *(const floatx4*)&wlds[(ky*3+kx)*QTAPSTRIDE + wofs + 4];
            #pragma unroll
            for (int j=0;j<4;j++){ wr[kx][j]=wa[j]; wr[kx][4+j]=wb[j]; }
        }
        const u16* rowp = in + ((size_t)(img*HH+hh)*WW)*288 + c0;
        #pragma unroll
        for (int cc=0; cc<6; cc++){
            int cx = x0 - 1 + cc;
            if ((unsigned)cx >= WW) continue;
            short8v v = *(const short8v*)(rowp + (size_t)cx*288);
            float vf[8];
            #pragma unroll
            for (int j=0;j<8;j++) vf[j] = b2f((u16)v[j]);
            #pragma unroll
            for (int dx=0; dx<4; dx++){
                int kx = cc - dx;
                if (kx < 0 || kx >= 3) continue;
                #pragma unroll
                for (int j=0;j<8;j++) acc[dx][j] = fmaf(wr[kx][j], vf[j], acc[dx][j]);
            }
        }
    }
    size_t pix0 = (size_t)(img*HH+hy)*WW + x0;
    int sec = c0/96, qc0 = c0 - sec*96;
    u16* outp = out + (size_t)sec*planeStride + qc0;
    #pragma unroll
    for (int dx=0; dx<4; dx++){
        short8v o;
        #pragma unroll
        for (int j=0;j<8;j++) o[j] = (short)f2b(acc[dx][j]);
        *(short8v*)(outp + (pix0+dx)*96) = o;
    }
}

// ---------- Gram partials per (img,head,slice), Q/K planes, vectorized staging ----------
__global__ __launch_bounds__(256) void gram_k(const u16* __restrict__ Qp,
    const u16* __restrict__ Kp, float* __restrict__ part)
{
    int bh = blockIdx.x;
    int slice = blockIdx.y;
    int img = bh >> 3, h = bh & 7;
    const u16* Qb = Qp + (size_t)img*HW*96 + h*12;
    const u16* Kb = Kp + (size_t)img*HW*96 + h*12;
    __shared__ float qs[64][12];
    __shared__ float ks[64][12];
    int t = threadIdx.x;
    float acc = 0.f;
    int c = (t<144) ? t/12 : (t<156 ? t-144 : t-156);
    int d = (t<144) ? t%12 : 0;
    for (int st=0; st<16; st++){
        int pix0 = slice*1024 + st*64;
        __syncthreads();
        for (int i=t; i<384; i+=256){
            int p = i/6, j = i%6;
            const u16* src = (j<3) ? (Qb + (size_t)(pix0+p)*96 + j*4)
                                   : (Kb + (size_t)(pix0+p)*96 + (j-3)*4);
            short4v v = *(const short4v*)src;
            float f0=b2f((u16)v.x), f1=b2f((u16)v.y), f2=b2f((u16)v.z), f3=b2f((u16)v.w);
            if (j<3){ int jj=j*4;     qs[p][jj]=f0; qs[p][jj+1]=f1; qs[p][jj+2]=f2; qs[p][jj+3]=f3; }
            else    { int jj=(j-3)*4; ks[p][jj]=f0; ks[p][jj+1]=f1; ks[p][jj+2]=f2; ks[p][jj+3]=f3; }
        }
        __syncthreads();
        if (t<144){        for (int p=0;p<64;p++) acc = fmaf(qs[p][c], ks[p][d], acc); }
        else if (t<156){   for (int p=0;p<64;p++) acc = fmaf(qs[p][c], qs[p][c], acc); }
        else if (t<168){   for (int p=0;p<64;p++) acc = fmaf(ks[p][c], ks[p][c], acc); }
    }
    if (t<168) part[((size_t)bh*16 + slice)*168 + t] = acc;
}

__global__ __launch_bounds__(256) void gram_combine_k(const float* __restrict__ part,
                                                      float* __restrict__ gram, int n)
{
    int i = blockIdx.x*256 + threadIdx.x;
    if (i >= n) return;
    int bh = i/168, t = i%168;
    float s = 0.f;
    for (int sl=0; sl<16; sl++) s += part[((size_t)bh*16+sl)*168 + t];
    gram[i] = s;
}

// ---------- attn 12x12: normalize, temperature, top-k mask, softmax ----------
__global__ __launch_bounds__(256) void attn_k(const float* __restrict__ gram,
    const float* __restrict__ temp, const float* __restrict__ dynk_p,
    const float* __restrict__ a1, const float* __restrict__ a2,
    const float* __restrict__ a3, const float* __restrict__ a4,
    float* __restrict__ attnW)
{
    int bh = blockIdx.x;
    int h = bh & 7;
    __shared__ float av[12][12];
    __shared__ float mv[12][12];
    __shared__ float nq[12], nk[12];
    int t = threadIdx.x;
    if (t < 12) nq[t] = fmaxf(sqrtf(gram[bh*168+144+t]), 1e-12f);
    else if (t < 24) nk[t-12] = fmaxf(sqrtf(gram[bh*168+156+(t-12)]), 1e-12f);
    __syncthreads();
    if (t < 144){
        int c=t/12, d=t%12;
        av[c][d] = gram[bh*168+t] / (nq[c]*nk[d]) * temp[h];
    }
    __syncthreads();
    float dk = *dynk_p;
    if (t < 144){
        int c=t/12, d=t%12; float v = av[c][d];
        int r = 0;
        #pragma unroll
        for (int j=0;j<12;j++){
            float o = av[c][j];
            r += (o > v) ? 1 : ((o == v && j < d) ? 1 : 0);
        }
        mv[c][d] = ((float)r < dk) ? v : -INFINITY;
    }
    __syncthreads();
    if (t < 12){
        float mx = -INFINITY;
        for (int d2=0; d2<12; d2++) mx = fmaxf(mx, mv[t][d2]);
        float e[12]; float s = 0.f;
        for (int d2=0; d2<12; d2++){ e[d2] = expf(mv[t][d2]-mx); s += e[d2]; }
        float sc = (a1[0]+a2[0]+a3[0]+a4[0]) / s;
        for (int d2=0; d2<12; d2++) attnW[(size_t)bh*144 + t*12 + d2] = e[d2]*sc;
    }
}

// ---------- attn apply -> P96 bf16 (V plane input); thread = (pixel, head) ----------
__global__ __launch_bounds__(256) void attn_apply_k(const u16* __restrict__ Vp,
    const float* __restrict__ attnW, u16* __restrict__ P)
{
    int gid = blockIdx.x*256 + threadIdx.x;
    int h = gid % 8; size_t pix = (size_t)(gid / 8);
    int img = (int)(pix >> 14);
    const u16* vp = Vp + pix*96 + h*12;
    float vf[12];
    #pragma unroll
    for (int j=0;j<3;j++){
        short4v v = *(const short4v*)(vp + j*4);
        vf[j*4+0]=b2f((u16)v.x); vf[j*4+1]=b2f((u16)v.y);
        vf[j*4+2]=b2f((u16)v.z); vf[j*4+3]=b2f((u16)v.w);
    }
    const float* awb = attnW + ((size_t)(img*8+h))*144;
    u16 o[12];
    #pragma unroll
    for (int cc=0; cc<12; cc++){
        const float4* ap = (const float4*)(awb + cc*12);
        float4 a0 = ap[0], a1 = ap[1], a2 = ap[2];
        float s = a0.x*vf[0] + a0.y*vf[1] + a0.z*vf[2] + a0.w*vf[3]
                + a1.x*vf[4] + a1.y*vf[5] + a1.z*vf[6] + a1.w*vf[7]
                + a2.x*vf[8] + a2.y*vf[9] + a2.z*vf[10]+ a2.w*vf[11];
        o[cc] = f2b(s);
    }
    u16* op = P + pix*96 + h*12;
    *(short4v*)(op)   = *(short4v*)&o[0];
    *(short4v*)(op+4) = *(short4v*)&o[4];
    *(short4v*)(op+8) = *(short4v*)&o[8];
}

// ---------- FFN multi-scale depthwise, row-sweep per scale, XCD-swizzled ----------
template<int KS>
__global__ __launch_bounds__(256) void ffn_dw_g(const u16* __restrict__ V0,
    const float* __restrict__ wsrc, const float* __restrict__ bsrc, int cbase,
    const float* __restrict__ bn2g, const float* __restrict__ bn2b,
    const float* __restrict__ bn2m, const float* __restrict__ bn2v,
    u16* __restrict__ U)
{
    constexpr int PAD = KS/2;
    __shared__ float wlds[KS*KS*64];
    __shared__ float bng[64], bnb[64], bnm[64], bnvr[64];
    int t = threadIdx.x;
    for (int i=t; i<KS*KS*64; i+=256){
        int tap = i >> 6, cc = i & 63;
        wlds[tap*64 + cc] = wsrc[cc*KS*KS + tap];
    }
    if (t < 64){
        bng[t] = bn2g[cbase+t]; bnb[t] = bn2b[cbase+t];
        bnm[t] = bn2m[cbase+t]; bnvr[t] = rsqrtf(bn2v[cbase+t]+1e-5f);
    }
    __syncthreads();
    int ci = t & 7, seg = t >> 3;
    int bid = blockIdx.x;
    int rowid = (bid & 7)*(gridDim.x >> 3) + (bid >> 3);
    int img = rowid >> 7, hy = rowid & 127;
    int c0r = ci*8;
    int c0 = cbase + c0r;
    int x0 = seg*4;
    float acc[4][8];
    {
        floatx4 b0 = *(const floatx4*)(bsrc + c0r);
        floatx4 b1 = *(const floatx4*)(bsrc + c0r + 4);
        #pragma unroll
        for (int dx=0;dx<4;dx++){
            #pragma unroll
            for (int j=0;j<4;j++){ acc[dx][j]=b0[j]; acc[dx][4+j]=b1[j]; }
        }
    }
    #pragma unroll
    for (int ky=0; ky<KS; ky++){
        int hh = hy + ky - PAD;
        if ((unsigned)hh >= HH) continue;
        float wr[KS][8];
        #pragma unroll
        for (int kx=0; kx<KS; kx++){
            floatx4 wa = *(const floatx4*)&wlds[(ky*KS+kx)*64 + c0r];
            floatx4 wb = *(const floatx4*)&wlds[(ky*KS+kx)*64 + c0r + 4];
            #pragma unroll
            for (int j=0;j<4;j++){ wr[kx][j]=wa[j]; wr[kx][4+j]=wb[j]; }
        }
        const u16* rowp = V0 + ((size_t)(img*HH+hh)*WW)*256 + c0;
        #pragma unroll
        for (int cc=0; cc<4+2*PAD; cc++){
            int cx = x0 - PAD + cc;
            if ((unsigned)cx >= WW) continue;
            short8v v = *(const short8v*)(rowp + (size_t)cx*256);
            float vf[8];
            #pragma unroll
            for (int j=0;j<8;j++) vf[j] = b2f((u16)v[j]);
            #pragma unroll
            for (int dx=0; dx<4; dx++){
                int kx = cc - dx;
                if (kx < 0 || kx >= KS) continue;
                #pragma unroll
                for (int j=0;j<8;j++) acc[dx][j] = fmaf(wr[kx][j], vf[j], acc[dx][j]);
            }
        }
    }
    size_t rbase = (size_t)(img*HH+hy)*WW;
    #pragma unroll
    for (int dx=0; dx<4; dx++){
        size_t pix = rbase + x0 + dx;
        short8v vc = *(const short8v*)(V0 + pix*256 + c0);
        short8v o;
        #pragma unroll
        for (int j=0;j<8;j++){
            float v0c = b2f((u16)vc[j]);
            float u1 = acc[dx][j] + v0c;
            float gl = gelu_exact(u1);
            float bn = (gl - bnm[c0r+j])*bnvr[c0r+j]*bng[c0r+j] + bnb[c0r+j];
            o[j] = (short)f2b(bn*v0c);
        }
        *(short8v*)(U + pix*256 + c0) = o;
    }
}

extern "C" void kernel_launch(void* const* d_in, const int* in_sizes, int n_in,
                              void* d_out, int out_size, void* d_ws, size_t ws_size,
                              hipStream_t stream)
{
    const float* x     = (const float*)d_in[0];
    const float* pos_w = (const float*)d_in[1];
    const float* pos_b = (const float*)d_in[2];
    const float* ln1g  = (const float*)d_in[3];
    const float* ln1b  = (const float*)d_in[4];
    const float* temp  = (const float*)d_in[5];
    const float* qkvw  = (const float*)d_in[6];
    const float* qkvdw = (const float*)d_in[7];
    const float* projw = (const float*)d_in[8];
    const float* gw1   = (const float*)d_in[9];
    const float* gb1   = (const float*)d_in[10];
    const float* gw2   = (const float*)d_in[11];
    const float* gb2   = (const float*)d_in[12];
    const float* a1    = (const float*)d_in[13];
    const float* a2    = (const float*)d_in[14];
    const float* a3    = (const float*)d_in[15];
    const float* a4    = (const float*)d_in[16];
    const float* ln2g  = (const float*)d_in[17];
    const float* ln2b  = (const float*)d_in[18];
    const float* fc1w  = (const float*)d_in[19];
    const float* bn1g  = (const float*)d_in[20];
    const float* bn1b  = (const float*)d_in[21];
    const float* bn1m  = (const float*)d_in[22];
    const float* bn1v  = (const float*)d_in[23];
    const float* bn2g  = (const float*)d_in[24];
    const float* bn2b  = (const float*)d_in[25];
    const float* bn2m  = (const float*)d_in[26];
    const float* bn2v  = (const float*)d_in[27];
    const float* fc2w  = (const float*)d_in[28];
    const float* bn3g  = (const float*)d_in[29];
    const float* bn3b  = (const float*)d_in[30];
    const float* bn3m  = (const float*)d_in[31];
    const float* bn3v  = (const float*)d_in[32];
    const float* dw0w  = (const float*)d_in[33];
    const float* dw0b  = (const float*)d_in[34];
    const float* dw1w  = (const float*)d_in[35];
    const float* dw1b  = (const float*)d_in[36];
    const float* dw2w  = (const float*)d_in[37];
    const float* dw2b  = (const float*)d_in[38];
    const float* dw3w  = (const float*)d_in[39];
    const float* dw3b  = (const float*)d_in[40];

    float* OUT = (float*)d_out;      // final fp32 output (written once by fc2)

    // ---- fixed small buffers + bf16 residual stream A ----
    char* p = (char*)d_ws;
    float* gpix  = (float*)p;                 p += (size_t)NPIX*4;
    float* dynk  = (float*)p;                 p += 256;
    float* gpart = (float*)p;                 p += 64*16*168*4;
    float* gram  = (float*)p;                 p += 64*168*4;
    float* attnW = (float*)p;                 p += 64*144*4;
    float* wposT = (float*)p;                 p += 1728*4;
    u16*   wbf   = (u16*)p;                   p += (size_t)WTOT*2;
    u16*   Abf   = (u16*)p;                   p += (size_t)NPIX*192*2;   // 50.3 MB
    size_t fixedB = (size_t)(p - (char*)d_ws);

    // ---- choose chunk size from ws_size: per-image = Y(192)+B1(288)+B2(288) bf16 ----
    size_t perImg = (size_t)HW*2*(192+288+288);   // 25,165,824
    int CBr = 2;
    if (ws_size >= fixedB + 8*perImg) CBr = 8;
    else if (ws_size >= fixedB + 4*perImg) CBr = 4;
    int NCHUNKr = BB/CBr;
    size_t CHWr = (size_t)CBr*HW;

    u16* Ybf = (u16*)p;                   p += CHWr*192*2;
    u16* B1  = (u16*)p;                   p += CHWr*288*2;
    u16* B2  = (u16*)p;
    u16* qkvwb = wbf;
    u16* projwb= wbf + WQ;
    u16* gw1b  = wbf + WQ + WP;
    u16* fc1b  = wbf + WQ + WP + WG;
    u16* fc2b  = wbf + WQ + WP + WG + WF1;
    u16* G1bf  = B1;     // gate phase
    u16* QKVbf = B1;     // qkv out (288 interleaved)
    u16* QKVdbf= B2;     // qkv_dw out: Q|K|V planes of CHWr*96 each
    u16* P96   = B1;     // attn out (QKV dead)
    u16* Zbf   = B2;     // LN2 out (QKVd dead)
    u16* V0bf  = B1;     // fc1 out (P96 dead)
    u16* Ubf   = B2;     // ffn out (Z dead)

    wprep_k<<<(WTOT+255)/256, 256, 0, stream>>>(qkvw, projw, gw1, fc1w, fc2w,
                                                pos_w, wbf, wposT);
    if (NCHUNKr == 1){
        // fused pos-conv + LN1: writes full A and full Y in one pass
        pos_conv_ln_k<<<NPIX/4, 192, 0, stream>>>(x, wposT, pos_b, ln1g, ln1b, Abf, Ybf);
    } else {
        pos_conv_k<<<NPIX/4, 192, 0, stream>>>(x, wposT, pos_b, Abf);
    }

    // gate phase
    for (int c=0; c<NCHUNKr; c++){
        const u16* Ab = Abf + (size_t)c*CHWr*192;
        if (NCHUNKr > 1)
            ln_k<<<CHWr/4, 256, 0, stream>>>(Ab, ln1g, ln1b, Ybf);
        dim3 g(CHWr/256, 2);
        gemm_bf16_k<GM_BIAS_RELU,192><<<g, 256, 0, stream>>>(Ybf, 192, nullptr, 0,
            gw1b, G1bf, 96, nullptr, 0, gb1, nullptr, nullptr, nullptr, 96);
        gate2_k<<<CHWr/256, 256, 0, stream>>>(G1bf, gw2, gb2, gpix + (size_t)c*CHWr);
    }
    gate_reduce_k<<<1, 1024, 0, stream>>>(gpix, dynk);

    // main phase
    for (int c=0; c<NCHUNKr; c++){
        u16* Ab = Abf + (size_t)c*CHWr*192;
        if (NCHUNKr > 1)   // single-chunk mode: Ybf from fused kernel is still valid
            ln_k<<<CHWr/4, 256, 0, stream>>>(Ab, ln1g, ln1b, Ybf);
        {
            dim3 g(CHWr/256, 5);
            gemm_bf16_k<GM_NONE,96><<<g, 256, 0, stream>>>(Ybf, 192, nullptr, 0,
                qkvwb, QKVbf, 288, nullptr, 0, nullptr,nullptr,nullptr,nullptr, 288);
        }
        size_t pstr = CHWr*96;
        qkv_dw_k<<<CHWr/4*36/256, 256, 0, stream>>>(QKVbf, qkvdw, QKVdbf, pstr);
        { dim3 g(CBr*8, 16); gram_k<<<g, 256, 0, stream>>>(QKVdbf, QKVdbf + pstr, gpart); }
        gram_combine_k<<<(CBr*8*168+255)/256, 256, 0, stream>>>(gpart, gram, CBr*8*168);
        attn_k<<<CBr*8, 256, 0, stream>>>(gram, temp, dynk, a1,a2,a3,a4, attnW);
        attn_apply_k<<<CHWr*8/256, 256, 0, stream>>>(QKVdbf + 2*pstr, attnW, P96);
        {   // proj + residual: A += [P96 | Y[:,96:]] @ projw^T  (bf16 in-place)
            dim3 g(CHWr/256, 3);
            gemm_bf16_k<GM_RES,192,true><<<g, 256, 0, stream>>>(P96, 96, Ybf+96, 192,
                projwb, Ab, 192, Ab, 192, nullptr,nullptr,nullptr,nullptr, 192);
        }
        ln_k<<<CHWr/4, 256, 0, stream>>>(Ab, ln2g, ln2b, Zbf);
        {
            dim3 g(CHWr/256, 4);
            gemm_bf16_k<GM_GELU_BN,192><<<g, 256, 0, stream>>>(Zbf, 192, nullptr, 0,
                fc1b, V0bf, 256, nullptr, 0, bn1g,bn1b,bn1m,bn1v, 256);
        }
        int rows = (int)(CHWr/WW);
        ffn_dw_g<1><<<rows, 256, 0, stream>>>(V0bf, dw0w, dw0b, 0,
            bn2g,bn2b,bn2m,bn2v, Ubf);
        ffn_dw_g<3><<<rows, 256, 0, stream>>>(V0bf, dw1w, dw1b, 64,
            bn2g,bn2b,bn2m,bn2v, Ubf);
        ffn_dw_g<5><<<rows, 256, 0, stream>>>(V0bf, dw2w, dw2b, 128,
            bn2g,bn2b,bn2m,bn2v, Ubf);
        ffn_dw_g<7><<<rows, 256, 0, stream>>>(V0bf, dw3w, dw3b, 192,
            bn2g,bn2b,bn2m,bn2v, Ubf);
        {   // fc2 + bn3 + residual -> fp32 OUT
            dim3 g(CHWr/256, 3);
            gemm_bf16_k<GM_BN_RES,256><<<g, 256, 0, stream>>>(Ubf, 256, nullptr, 0,
                fc2b, OUT + (size_t)c*CHWr*192, 192, Ab, 192, bn3g,bn3b,bn3m,bn3v, 192);
        }
    }
}

// Round 16
// 634.778 us; speedup vs baseline: 1.0331x; 1.0331x over previous
//
#include <hip/hip_runtime.h>
#include <hip/hip_bf16.h>
#include <math.h>

#define BB 8
#define HH 128
#define WW 128
#define HW (HH*WW)          // 16384
#define NPIX (BB*HW)        // 131072

typedef unsigned short u16;
typedef __attribute__((ext_vector_type(4))) float  floatx4;
typedef __attribute__((ext_vector_type(4))) short  short4v;
typedef __attribute__((ext_vector_type(8))) short  short8v;

static __device__ __forceinline__ float gelu_exact(float x){
    return 0.5f*x*(1.0f+erff(x*0.70710678118654752440f));
}
static __device__ __forceinline__ float b2f(u16 v){
    union { unsigned u; float f; } x; x.u = ((unsigned)v)<<16; return x.f;
}
static __device__ __forceinline__ u16 f2b(float f){
    __hip_bfloat16 h = __float2bfloat16(f);
    return *(u16*)&h;
}

// ---------- weight prep: fp32 -> bf16 GEMM weights + transposed pos weights ----------
#define WQ 27648
#define WP 36864
#define WG 18432
#define WF1 49152
#define WF2 49152
#define WTOT (WQ+WP+WG+WF1+WF2)   // 181248
__global__ __launch_bounds__(256) void wprep_k(const float* __restrict__ a,
    const float* __restrict__ b, const float* __restrict__ c,
    const float* __restrict__ d, const float* __restrict__ e,
    const float* __restrict__ posw, u16* __restrict__ o, float* __restrict__ wT)
{
    int i = blockIdx.x*256 + threadIdx.x;
    if (i < 1728){   // wT[tap][192]: wT[tap*192+c] = posw[c*9+tap]
        wT[i] = posw[(i%192)*9 + (i/192)];
    }
    if (i >= WTOT) return;
    float v;
    if (i < WQ) v = a[i];
    else if (i < WQ+WP) v = b[i-WQ];
    else if (i < WQ+WP+WG) v = c[i-WQ-WP];
    else if (i < WQ+WP+WG+WF1) v = d[i-WQ-WP-WG];
    else v = e[i-WQ-WP-WG-WF1];
    o[i] = f2b(v);
}

// ---------- pos depthwise 3x3 + bias + residual -> bf16 A; LDS halo tile ----------
// block = 192 thr = 4 consecutive pixels x 48 c4; stage 3x6x192ch halo in LDS (13.8 KB)
__global__ __launch_bounds__(192) void pos_conv_k(const float* __restrict__ x,
    const float* __restrict__ wT, const float* __restrict__ bias, u16* __restrict__ out)
{
    __shared__ float4 lds[3][6][48];
    int bid = blockIdx.x;
    int sb = (bid & 7)*(gridDim.x >> 3) + (bid >> 3);   // XCD image-slice swizzle
    int t = threadIdx.x;
    int quad = sb;                       // over NPIX/4 column-quads
    int x0 = (quad & 31)*4;
    int hy = (quad >> 5) & 127;
    int b  = quad >> 12;

    const float4* x4 = (const float4*)x;
    float4 z4 = make_float4(0.f,0.f,0.f,0.f);
    // stage 18 (row,col) positions x 48 c4 groups = 864 float4 slots
    for (int i = t; i < 864; i += 192){
        int c4s = i % 48;
        int rc  = i / 48;
        int r   = rc / 6;
        int cp  = rc % 6;
        int hh  = hy + r - 1;
        int cx  = x0 + cp - 1;
        float4 v = z4;
        if ((unsigned)hh < HH && (unsigned)cx < WW)
            v = x4[((size_t)(b*HH+hh)*WW + cx)*48 + c4s];
        lds[r][cp][c4s] = v;
    }
    __syncthreads();

    int c4 = t % 48;
    int p  = t / 48;
    int c0 = c4*4;
    floatx4 wv[9];
    #pragma unroll
    for (int tap=0; tap<9; tap++)
        wv[tap] = *(const floatx4*)&wT[tap*192 + c0];

    float4 acc = *(const float4*)(bias + c0);
    #pragma unroll
    for (int i=0;i<3;i++){
        #pragma unroll
        for (int k=0;k<3;k++){
            float4 xv = lds[i][p+k][c4];
            floatx4 w = wv[i*3+k];
            acc.x = fmaf(w[0], xv.x, acc.x);
            acc.y = fmaf(w[1], xv.y, acc.y);
            acc.z = fmaf(w[2], xv.z, acc.z);
            acc.w = fmaf(w[3], xv.w, acc.w);
        }
    }
    float4 xc = lds[1][p+1][c4];   // original x at output pixel (always in range)
    acc.x += xc.x; acc.y += xc.y; acc.z += xc.z; acc.w += xc.w;

    size_t pix = (size_t)(b*HH + hy)*WW + x0 + p;
    short4v o; o.x=(short)f2b(acc.x); o.y=(short)f2b(acc.y);
    o.z=(short)f2b(acc.z); o.w=(short)f2b(acc.w);
    *(short4v*)(out + pix*192 + c0) = o;
}

// ---------- LayerNorm over C=192, bf16 in -> bf16 out, wave per pixel ----------
__global__ __launch_bounds__(256) void ln_k(const u16* __restrict__ in,
    const float* __restrict__ g, const float* __restrict__ bta, u16* __restrict__ out)
{
    int wid = threadIdx.x >> 6, lane = threadIdx.x & 63;
    size_t pix = (size_t)blockIdx.x*4 + wid;
    const u16* row = in + pix*192;
    float x0 = b2f(row[lane]), x1 = b2f(row[lane+64]), x2 = b2f(row[lane+128]);
    float s = x0+x1+x2;
    float q = x0*x0 + x1*x1 + x2*x2;
    #pragma unroll
    for (int off=32; off; off>>=1){ s += __shfl_xor(s,off,64); q += __shfl_xor(q,off,64); }
    float mean = s*(1.f/192.f);
    float var  = q*(1.f/192.f) - mean*mean;
    float inv  = rsqrtf(var + 1e-6f);
    u16* orow = out + pix*192;
    orow[lane]     = f2b((x0-mean)*inv*g[lane]     + bta[lane]);
    orow[lane+64]  = f2b((x1-mean)*inv*g[lane+64]  + bta[lane+64]);
    orow[lane+128] = f2b((x2-mean)*inv*g[lane+128] + bta[lane+128]);
}

// ---------- bf16 MFMA GEMM: W-in-LDS once, A streamed; grid=(m,n) for XCD A-locality ----------
#define GM_NONE 0
#define GM_RES 1
#define GM_GELU_BN 2
#define GM_BN_RES 3
#define GM_BIAS_RELU 4
#define WSTR 264   // LDS row stride in shorts: 528B = 132 dw; 132%32=4 -> 2-way only

template<int MODE, int K, bool SPLIT=false>
__global__ __launch_bounds__(256) void gemm_bf16_k(
    const u16* __restrict__ A, int lda,
    const u16* __restrict__ A2, int lda2,
    const u16* __restrict__ W,
    void* __restrict__ Cv, int ldc,
    const u16* __restrict__ R, int ldr,
    const float* __restrict__ bg, const float* __restrict__ bb,
    const float* __restrict__ bm_, const float* __restrict__ bv,
    int N)
{
    __shared__ u16 Ws[64*WSTR];
    int t = threadIdx.x;
    int bn = blockIdx.y * 64;
    int bm = blockIdx.x * 256;
    {
        constexpr int KQ = K/4;
        int brow = t >> 2, bq = t & 3;
        int n = bn + brow;
        bool nv = n < N;
        const u16* src = W + (size_t)n*K + bq*KQ;
        #pragma unroll
        for (int j=0; j<KQ; j+=8){
            short8v v = {};
            if (nv) v = *(const short8v*)(src + j);
            *(short8v*)&Ws[brow*WSTR + bq*KQ + j] = v;
        }
    }
    __syncthreads();
    int wave = t >> 6, lane = t & 63;
    int wm = wave*64;
    int lr = lane & 15, lk = lane >> 4;
    const u16* arow  = A + (size_t)(bm + wm + lr)*lda + lk*8;
    const u16* arow2 = SPLIT ? (A2 + (size_t)(bm + wm + lr)*lda2 + lk*8) : nullptr;
    floatx4 acc[4][4] = {};
    #pragma unroll
    for (int k0 = 0; k0 < K; k0 += 32){
        short8v afr[4];
        if (SPLIT && k0 >= 96){
            #pragma unroll
            for (int m=0;m<4;m++)
                afr[m] = *(const short8v*)(arow2 + (size_t)(m*16)*lda2 + (k0-96));
        } else {
            #pragma unroll
            for (int m=0;m<4;m++)
                afr[m] = *(const short8v*)(arow + (size_t)(m*16)*lda + k0);
        }
        #pragma unroll
        for (int n2=0;n2<4;n2++){
            short8v bfr = *(const short8v*)&Ws[(n2*16+lr)*WSTR + k0 + lk*8];
            #pragma unroll
            for (int m=0;m<4;m++)
                acc[m][n2] = __builtin_amdgcn_mfma_f32_16x16x32_bf16(afr[m], bfr, acc[m][n2], 0,0,0);
        }
    }
    #pragma unroll
    for (int m=0;m<4;m++){
        #pragma unroll
        for (int n2=0;n2<4;n2++){
            int gcol = bn + n2*16 + lr;
            if (gcol >= N) continue;
            #pragma unroll
            for (int rg=0; rg<4; rg++){
                int grow = bm + wm + m*16 + lk*4 + rg;
                float v = acc[m][n2][rg];
                if (MODE == GM_RES){
                    v += b2f(R[(size_t)grow*ldr + gcol]);
                    ((u16*)Cv)[(size_t)grow*ldc + gcol] = f2b(v);
                } else if (MODE == GM_BN_RES){
                    float bnv = (v - bm_[gcol])*rsqrtf(bv[gcol]+1e-5f)*bg[gcol] + bb[gcol];
                    ((float*)Cv)[(size_t)grow*ldc + gcol] = bnv + b2f(R[(size_t)grow*ldr + gcol]);
                } else if (MODE == GM_GELU_BN){
                    float gl = gelu_exact(v);
                    v = (gl - bm_[gcol])*rsqrtf(bv[gcol]+1e-5f)*bg[gcol] + bb[gcol];
                    ((u16*)Cv)[(size_t)grow*ldc + gcol] = f2b(v);
                } else if (MODE == GM_BIAS_RELU){
                    ((u16*)Cv)[(size_t)grow*ldc + gcol] = f2b(fmaxf(v + bg[gcol], 0.f));
                } else {
                    ((u16*)Cv)[(size_t)grow*ldc + gcol] = f2b(v);
                }
            }
        }
    }
}

// ---------- gate stage 2: sigmoid(G1 @ w2 + b2) per pixel, G1 bf16 ----------
__global__ __launch_bounds__(256) void gate2_k(const u16* __restrict__ G1,
    const float* __restrict__ w2, const float* __restrict__ b2, float* __restrict__ gpix)
{
    int pix = blockIdx.x*256 + threadIdx.x;
    const short4v* g4 = (const short4v*)(G1 + (size_t)pix*96);
    const float4* w4 = (const float4*)w2;
    float s = b2[0];
    #pragma unroll
    for (int j=0;j<24;j++){
        short4v g = g4[j]; float4 w = w4[j];
        s += b2f((u16)g.x)*w.x + b2f((u16)g.y)*w.y + b2f((u16)g.z)*w.z + b2f((u16)g.w)*w.w;
    }
    gpix[pix] = 1.f/(1.f+expf(-s));
}

// ---------- deterministic mean of gpix -> dyn_k ----------
__global__ __launch_bounds__(1024) void gate_reduce_k(const float* __restrict__ gpix,
                                                      float* __restrict__ dynk)
{
    __shared__ float sm[16];
    float s = 0.f;
    for (int i=threadIdx.x; i<NPIX; i+=1024) s += gpix[i];
    #pragma unroll
    for (int off=32; off; off>>=1) s += __shfl_xor(s,off,64);
    int wid = threadIdx.x>>6, lane = threadIdx.x&63;
    if (lane==0) sm[wid]=s;
    __syncthreads();
    if (threadIdx.x==0){
        float tot=0.f; for (int i=0;i<16;i++) tot+=sm[i];
        *dynk = floorf(12.0f * (tot/(float)NPIX));
    }
}

// ---------- qkv depthwise 3x3 (288 ch), 4-col sweep, LDS weights, XCD-swizzled ----------
#define QPOS(c8) ((c8)*8 + ((c8)>>2)*4)
#define QTAPSTRIDE 324
__global__ __launch_bounds__(256) void qkv_dw_k(const u16* __restrict__ in,
    const float* __restrict__ w, u16* __restrict__ out, size_t planeStride)
{
    __shared__ float wlds[9*QTAPSTRIDE];
    int t = threadIdx.x;
    for (int i=t; i<2592; i+=256){
        int tap = i/288, cc = i%288;
        wlds[tap*QTAPSTRIDE + QPOS(cc>>3) + (cc&7)] = w[cc*9+tap];
    }
    __syncthreads();
    int bid = blockIdx.x;
    int sb = (bid & 7)*(gridDim.x >> 3) + (bid >> 3);
    int idx = sb*256 + t;
    int c8 = idx % 36; int pq = idx / 36;
    int xg = pq & 31; int hy = (pq >> 5) & 127; int img = pq >> 12;
    int x0 = xg*4;
    int c0 = c8*8;
    int wofs = QPOS(c8);
    float acc[4][8] = {{0.f}};
    #pragma unroll
    for (int ky=0; ky<3; ky++){
        int hh = hy + ky - 1; if ((unsigned)hh >= HH) continue;
        float wr[3][8];
        #pragma unroll
        for (int kx=0; kx<3; kx++){
            floatx4 wa = *(const floatx4*)&wlds[(ky*3+kx)*QTAPSTRIDE + wofs];
            floatx4 wb = *(const floatx4*)&wlds[(ky*3+kx)*QTAPSTRIDE + wofs + 4];
            #pragma unroll
            for (int j=0;j<4;j++){ wr[kx][j]=wa[j]; wr[kx][4+j]=wb[j]; }
        }
        const u16* rowp = in + ((size_t)(img*HH+hh)*WW)*288 + c0;
        #pragma unroll
        for (int cc=0; cc<6; cc++){
            int cx = x0 - 1 + cc;
            if ((unsigned)cx >= WW) continue;
            short8v v = *(const short8v*)(rowp + (size_t)cx*288);
            float vf[8];
            #pragma unroll
            for (int j=0;j<8;j++) vf[j] = b2f((u16)v[j]);
            #pragma unroll
            for (int dx=0; dx<4; dx++){
                int kx = cc - dx;
                if (kx < 0 || kx >= 3) continue;
                #pragma unroll
                for (int j=0;j<8;j++) acc[dx][j] = fmaf(wr[kx][j], vf[j], acc[dx][j]);
            }
        }
    }
    size_t pix0 = (size_t)(img*HH+hy)*WW + x0;
    int sec = c0/96, qc0 = c0 - sec*96;
    u16* outp = out + (size_t)sec*planeStride + qc0;
    #pragma unroll
    for (int dx=0; dx<4; dx++){
        short8v o;
        #pragma unroll
        for (int j=0;j<8;j++) o[j] = (short)f2b(acc[dx][j]);
        *(short8v*)(outp + (pix0+dx)*96) = o;
    }
}

// ---------- Gram partials per (img,head,slice), Q/K planes, vectorized staging ----------
__global__ __launch_bounds__(256) void gram_k(const u16* __restrict__ Qp,
    const u16* __restrict__ Kp, float* __restrict__ part)
{
    int bh = blockIdx.x;
    int slice = blockIdx.y;
    int img = bh >> 3, h = bh & 7;
    const u16* Qb = Qp + (size_t)img*HW*96 + h*12;
    const u16* Kb = Kp + (size_t)img*HW*96 + h*12;
    __shared__ float qs[64][12];
    __shared__ float ks[64][12];
    int t = threadIdx.x;
    float acc = 0.f;
    int c = (t<144) ? t/12 : (t<156 ? t-144 : t-156);
    int d = (t<144) ? t%12 : 0;
    for (int st=0; st<16; st++){
        int pix0 = slice*1024 + st*64;
        __syncthreads();
        for (int i=t; i<384; i+=256){
            int p = i/6, j = i%6;
            const u16* src = (j<3) ? (Qb + (size_t)(pix0+p)*96 + j*4)
                                   : (Kb + (size_t)(pix0+p)*96 + (j-3)*4);
            short4v v = *(const short4v*)src;
            float f0=b2f((u16)v.x), f1=b2f((u16)v.y), f2=b2f((u16)v.z), f3=b2f((u16)v.w);
            if (j<3){ int jj=j*4;     qs[p][jj]=f0; qs[p][jj+1]=f1; qs[p][jj+2]=f2; qs[p][jj+3]=f3; }
            else    { int jj=(j-3)*4; ks[p][jj]=f0; ks[p][jj+1]=f1; ks[p][jj+2]=f2; ks[p][jj+3]=f3; }
        }
        __syncthreads();
        if (t<144){        for (int p=0;p<64;p++) acc = fmaf(qs[p][c], ks[p][d], acc); }
        else if (t<156){   for (int p=0;p<64;p++) acc = fmaf(qs[p][c], qs[p][c], acc); }
        else if (t<168){   for (int p=0;p<64;p++) acc = fmaf(ks[p][c], ks[p][c], acc); }
    }
    if (t<168) part[((size_t)bh*16 + slice)*168 + t] = acc;
}

__global__ __launch_bounds__(256) void gram_combine_k(const float* __restrict__ part,
                                                      float* __restrict__ gram, int n)
{
    int i = blockIdx.x*256 + threadIdx.x;
    if (i >= n) return;
    int bh = i/168, t = i%168;
    float s = 0.f;
    for (int sl=0; sl<16; sl++) s += part[((size_t)bh*16+sl)*168 + t];
    gram[i] = s;
}

// ---------- attn 12x12: normalize, temperature, top-k mask, softmax ----------
__global__ __launch_bounds__(256) void attn_k(const float* __restrict__ gram,
    const float* __restrict__ temp, const float* __restrict__ dynk_p,
    const float* __restrict__ a1, const float* __restrict__ a2,
    const float* __restrict__ a3, const float* __restrict__ a4,
    float* __restrict__ attnW)
{
    int bh = blockIdx.x;
    int h = bh & 7;
    __shared__ float av[12][12];
    __shared__ float mv[12][12];
    __shared__ float nq[12], nk[12];
    int t = threadIdx.x;
    if (t < 12) nq[t] = fmaxf(sqrtf(gram[bh*168+144+t]), 1e-12f);
    else if (t < 24) nk[t-12] = fmaxf(sqrtf(gram[bh*168+156+(t-12)]), 1e-12f);
    __syncthreads();
    if (t < 144){
        int c=t/12, d=t%12;
        av[c][d] = gram[bh*168+t] / (nq[c]*nk[d]) * temp[h];
    }
    __syncthreads();
    float dk = *dynk_p;
    if (t < 144){
        int c=t/12, d=t%12; float v = av[c][d];
        int r = 0;
        #pragma unroll
        for (int j=0;j<12;j++){
            float o = av[c][j];
            r += (o > v) ? 1 : ((o == v && j < d) ? 1 : 0);
        }
        mv[c][d] = ((float)r < dk) ? v : -INFINITY;
    }
    __syncthreads();
    if (t < 12){
        float mx = -INFINITY;
        for (int d2=0; d2<12; d2++) mx = fmaxf(mx, mv[t][d2]);
        float e[12]; float s = 0.f;
        for (int d2=0; d2<12; d2++){ e[d2] = expf(mv[t][d2]-mx); s += e[d2]; }
        float sc = (a1[0]+a2[0]+a3[0]+a4[0]) / s;
        for (int d2=0; d2<12; d2++) attnW[(size_t)bh*144 + t*12 + d2] = e[d2]*sc;
    }
}

// ---------- attn apply -> P96 bf16 (V plane input); thread = (pixel, head) ----------
__global__ __launch_bounds__(256) void attn_apply_k(const u16* __restrict__ Vp,
    const float* __restrict__ attnW, u16* __restrict__ P)
{
    int gid = blockIdx.x*256 + threadIdx.x;
    int h = gid % 8; size_t pix = (size_t)(gid / 8);
    int img = (int)(pix >> 14);
    const u16* vp = Vp + pix*96 + h*12;
    float vf[12];
    #pragma unroll
    for (int j=0;j<3;j++){
        short4v v = *(const short4v*)(vp + j*4);
        vf[j*4+0]=b2f((u16)v.x); vf[j*4+1]=b2f((u16)v.y);
        vf[j*4+2]=b2f((u16)v.z); vf[j*4+3]=b2f((u16)v.w);
    }
    const float* awb = attnW + ((size_t)(img*8+h))*144;
    u16 o[12];
    #pragma unroll
    for (int cc=0; cc<12; cc++){
        const float4* ap = (const float4*)(awb + cc*12);
        float4 a0 = ap[0], a1 = ap[1], a2 = ap[2];
        float s = a0.x*vf[0] + a0.y*vf[1] + a0.z*vf[2] + a0.w*vf[3]
                + a1.x*vf[4] + a1.y*vf[5] + a1.z*vf[6] + a1.w*vf[7]
                + a2.x*vf[8] + a2.y*vf[9] + a2.z*vf[10]+ a2.w*vf[11];
        o[cc] = f2b(s);
    }
    u16* op = P + pix*96 + h*12;
    *(short4v*)(op)   = *(short4v*)&o[0];
    *(short4v*)(op+4) = *(short4v*)&o[4];
    *(short4v*)(op+8) = *(short4v*)&o[8];
}

// ---------- FFN multi-scale depthwise, row-sweep per scale, XCD-swizzled ----------
template<int KS>
__global__ __launch_bounds__(256) void ffn_dw_g(const u16* __restrict__ V0,
    const float* __restrict__ wsrc, const float* __restrict__ bsrc, int cbase,
    const float* __restrict__ bn2g, const float* __restrict__ bn2b,
    const float* __restrict__ bn2m, const float* __restrict__ bn2v,
    u16* __restrict__ U)
{
    constexpr int PAD = KS/2;
    __shared__ float wlds[KS*KS*64];
    __shared__ float bng[64], bnb[64], bnm[64], bnvr[64];
    int t = threadIdx.x;
    for (int i=t; i<KS*KS*64; i+=256){
        int tap = i >> 6, cc = i & 63;
        wlds[tap*64 + cc] = wsrc[cc*KS*KS + tap];
    }
    if (t < 64){
        bng[t] = bn2g[cbase+t]; bnb[t] = bn2b[cbase+t];
        bnm[t] = bn2m[cbase+t]; bnvr[t] = rsqrtf(bn2v[cbase+t]+1e-5f);
    }
    __syncthreads();
    int ci = t & 7, seg = t >> 3;
    int bid = blockIdx.x;
    int rowid = (bid & 7)*(gridDim.x >> 3) + (bid >> 3);
    int img = rowid >> 7, hy = rowid & 127;
    int c0r = ci*8;
    int c0 = cbase + c0r;
    int x0 = seg*4;
    float acc[4][8];
    {
        floatx4 b0 = *(const floatx4*)(bsrc + c0r);
        floatx4 b1 = *(const floatx4*)(bsrc + c0r + 4);
        #pragma unroll
        for (int dx=0;dx<4;dx++){
            #pragma unroll
            for (int j=0;j<4;j++){ acc[dx][j]=b0[j]; acc[dx][4+j]=b1[j]; }
        }
    }
    #pragma unroll
    for (int ky=0; ky<KS; ky++){
        int hh = hy + ky - PAD;
        if ((unsigned)hh >= HH) continue;
        float wr[KS][8];
        #pragma unroll
        for (int kx=0; kx<KS; kx++){
            floatx4 wa = *(const floatx4*)&wlds[(ky*KS+kx)*64 + c0r];
            floatx4 wb = *(const floatx4*)&wlds[(ky*KS+kx)*64 + c0r + 4];
            #pragma unroll
            for (int j=0;j<4;j++){ wr[kx][j]=wa[j]; wr[kx][4+j]=wb[j]; }
        }
        const u16* rowp = V0 + ((size_t)(img*HH+hh)*WW)*256 + c0;
        #pragma unroll
        for (int cc=0; cc<4+2*PAD; cc++){
            int cx = x0 - PAD + cc;
            if ((unsigned)cx >= WW) continue;
            short8v v = *(const short8v*)(rowp + (size_t)cx*256);
            float vf[8];
            #pragma unroll
            for (int j=0;j<8;j++) vf[j] = b2f((u16)v[j]);
            #pragma unroll
            for (int dx=0; dx<4; dx++){
                int kx = cc - dx;
                if (kx < 0 || kx >= KS) continue;
                #pragma unroll
                for (int j=0;j<8;j++) acc[dx][j] = fmaf(wr[kx][j], vf[j], acc[dx][j]);
            }
        }
    }
    size_t rbase = (size_t)(img*HH+hy)*WW;
    #pragma unroll
    for (int dx=0; dx<4; dx++){
        size_t pix = rbase + x0 + dx;
        short8v vc = *(const short8v*)(V0 + pix*256 + c0);
        short8v o;
        #pragma unroll
        for (int j=0;j<8;j++){
            float v0c = b2f((u16)vc[j]);
            float u1 = acc[dx][j] + v0c;
            float gl = gelu_exact(u1);
            float bn = (gl - bnm[c0r+j])*bnvr[c0r+j]*bng[c0r+j] + bnb[c0r+j];
            o[j] = (short)f2b(bn*v0c);
        }
        *(short8v*)(U + pix*256 + c0) = o;
    }
}

extern "C" void kernel_launch(void* const* d_in, const int* in_sizes, int n_in,
                              void* d_out, int out_size, void* d_ws, size_t ws_size,
                              hipStream_t stream)
{
    const float* x     = (const float*)d_in[0];
    const float* pos_w = (const float*)d_in[1];
    const float* pos_b = (const float*)d_in[2];
    const float* ln1g  = (const float*)d_in[3];
    const float* ln1b  = (const float*)d_in[4];
    const float* temp  = (const float*)d_in[5];
    const float* qkvw  = (const float*)d_in[6];
    const float* qkvdw = (const float*)d_in[7];
    const float* projw = (const float*)d_in[8];
    const float* gw1   = (const float*)d_in[9];
    const float* gb1   = (const float*)d_in[10];
    const float* gw2   = (const float*)d_in[11];
    const float* gb2   = (const float*)d_in[12];
    const float* a1    = (const float*)d_in[13];
    const float* a2    = (const float*)d_in[14];
    const float* a3    = (const float*)d_in[15];
    const float* a4    = (const float*)d_in[16];
    const float* ln2g  = (const float*)d_in[17];
    const float* ln2b  = (const float*)d_in[18];
    const float* fc1w  = (const float*)d_in[19];
    const float* bn1g  = (const float*)d_in[20];
    const float* bn1b  = (const float*)d_in[21];
    const float* bn1m  = (const float*)d_in[22];
    const float* bn1v  = (const float*)d_in[23];
    const float* bn2g  = (const float*)d_in[24];
    const float* bn2b  = (const float*)d_in[25];
    const float* bn2m  = (const float*)d_in[26];
    const float* bn2v  = (const float*)d_in[27];
    const float* fc2w  = (const float*)d_in[28];
    const float* bn3g  = (const float*)d_in[29];
    const float* bn3b  = (const float*)d_in[30];
    const float* bn3m  = (const float*)d_in[31];
    const float* bn3v  = (const float*)d_in[32];
    const float* dw0w  = (const float*)d_in[33];
    const float* dw0b  = (const float*)d_in[34];
    const float* dw1w  = (const float*)d_in[35];
    const float* dw1b  = (const float*)d_in[36];
    const float* dw2w  = (const float*)d_in[37];
    const float* dw2b  = (const float*)d_in[38];
    const float* dw3w  = (const float*)d_in[39];
    const float* dw3b  = (const float*)d_in[40];

    float* OUT = (float*)d_out;      // final fp32 output (written once by fc2)

    // ---- fixed small buffers + bf16 residual stream A ----
    char* p = (char*)d_ws;
    float* gpix  = (float*)p;                 p += (size_t)NPIX*4;
    float* dynk  = (float*)p;                 p += 256;
    float* gpart = (float*)p;                 p += 64*16*168*4;
    float* gram  = (float*)p;                 p += 64*168*4;
    float* attnW = (float*)p;                 p += 64*144*4;
    float* wposT = (float*)p;                 p += 1728*4;
    u16*   wbf   = (u16*)p;                   p += (size_t)WTOT*2;
    u16*   Abf   = (u16*)p;                   p += (size_t)NPIX*192*2;   // 50.3 MB
    size_t fixedB = (size_t)(p - (char*)d_ws);

    // ---- choose chunk size from ws_size: per-image = Y(192)+B1(288)+B2(288) bf16 ----
    size_t perImg = (size_t)HW*2*(192+288+288);   // 25,165,824
    int CBr = 2;
    if (ws_size >= fixedB + 8*perImg) CBr = 8;
    else if (ws_size >= fixedB + 4*perImg) CBr = 4;
    int NCHUNKr = BB/CBr;
    size_t CHWr = (size_t)CBr*HW;

    u16* Ybf = (u16*)p;                   p += CHWr*192*2;
    u16* B1  = (u16*)p;                   p += CHWr*288*2;
    u16* B2  = (u16*)p;
    u16* qkvwb = wbf;
    u16* projwb= wbf + WQ;
    u16* gw1b  = wbf + WQ + WP;
    u16* fc1b  = wbf + WQ + WP + WG;
    u16* fc2b  = wbf + WQ + WP + WG + WF1;
    u16* G1bf  = B1;     // gate phase
    u16* QKVbf = B1;     // qkv out (288 interleaved)
    u16* QKVdbf= B2;     // qkv_dw out: Q|K|V planes of CHWr*96 each
    u16* P96   = B1;     // attn out (QKV dead)
    u16* Zbf   = B2;     // LN2 out (QKVd dead)
    u16* V0bf  = B1;     // fc1 out (P96 dead)
    u16* Ubf   = B2;     // ffn out (Z dead)

    wprep_k<<<(WTOT+255)/256, 256, 0, stream>>>(qkvw, projw, gw1, fc1w, fc2w,
                                                pos_w, wbf, wposT);
    pos_conv_k<<<NPIX/4, 192, 0, stream>>>(x, wposT, pos_b, Abf);

    // gate phase
    for (int c=0; c<NCHUNKr; c++){
        const u16* Ab = Abf + (size_t)c*CHWr*192;
        ln_k<<<CHWr/4, 256, 0, stream>>>(Ab, ln1g, ln1b, Ybf);
        dim3 g(CHWr/256, 2);
        gemm_bf16_k<GM_BIAS_RELU,192><<<g, 256, 0, stream>>>(Ybf, 192, nullptr, 0,
            gw1b, G1bf, 96, nullptr, 0, gb1, nullptr, nullptr, nullptr, 96);
        gate2_k<<<CHWr/256, 256, 0, stream>>>(G1bf, gw2, gb2, gpix + (size_t)c*CHWr);
    }
    gate_reduce_k<<<1, 1024, 0, stream>>>(gpix, dynk);

    // main phase
    for (int c=0; c<NCHUNKr; c++){
        u16* Ab = Abf + (size_t)c*CHWr*192;
        if (NCHUNKr > 1)   // single-chunk mode: Ybf from gate phase is still valid
            ln_k<<<CHWr/4, 256, 0, stream>>>(Ab, ln1g, ln1b, Ybf);
        {
            dim3 g(CHWr/256, 5);
            gemm_bf16_k<GM_NONE,96><<<g, 256, 0, stream>>>(Ybf, 192, nullptr, 0,
                qkvwb, QKVbf, 288, nullptr, 0, nullptr,nullptr,nullptr,nullptr, 288);
        }
        size_t pstr = CHWr*96;
        qkv_dw_k<<<CHWr/4*36/256, 256, 0, stream>>>(QKVbf, qkvdw, QKVdbf, pstr);
        { dim3 g(CBr*8, 16); gram_k<<<g, 256, 0, stream>>>(QKVdbf, QKVdbf + pstr, gpart); }
        gram_combine_k<<<(CBr*8*168+255)/256, 256, 0, stream>>>(gpart, gram, CBr*8*168);
        attn_k<<<CBr*8, 256, 0, stream>>>(gram, temp, dynk, a1,a2,a3,a4, attnW);
        attn_apply_k<<<CHWr*8/256, 256, 0, stream>>>(QKVdbf + 2*pstr, attnW, P96);
        {   // proj + residual: A += [P96 | Y[:,96:]] @ projw^T  (bf16 in-place)
            dim3 g(CHWr/256, 3);
            gemm_bf16_k<GM_RES,192,true><<<g, 256, 0, stream>>>(P96, 96, Ybf+96, 192,
                projwb, Ab, 192, Ab, 192, nullptr,nullptr,nullptr,nullptr, 192);
        }
        ln_k<<<CHWr/4, 256, 0, stream>>>(Ab, ln2g, ln2b, Zbf);
        {
            dim3 g(CHWr/256, 4);
            gemm_bf16_k<GM_GELU_BN,192><<<g, 256, 0, stream>>>(Zbf, 192, nullptr, 0,
                fc1b, V0bf, 256, nullptr, 0, bn1g,bn1b,bn1m,bn1v, 256);
        }
        int rows = (int)(CHWr/WW);
        ffn_dw_g<1><<<rows, 256, 0, stream>>>(V0bf, dw0w, dw0b, 0,
            bn2g,bn2b,bn2m,bn2v, Ubf);
        ffn_dw_g<3><<<rows, 256, 0, stream>>>(V0bf, dw1w, dw1b, 64,
            bn2g,bn2b,bn2m,bn2v, Ubf);
        ffn_dw_g<5><<<rows, 256, 0, stream>>>(V0bf, dw2w, dw2b, 128,
            bn2g,bn2b,bn2m,bn2v, Ubf);
        ffn_dw_g<7><<<rows, 256, 0, stream>>>(V0bf, dw3w, dw3b, 192,
            bn2g,bn2b,bn2m,bn2v, Ubf);
        {   // fc2 + bn3 + residual -> fp32 OUT
            dim3 g(CHWr/256, 3);
            gemm_bf16_k<GM_BN_RES,256><<<g, 256, 0, stream>>>(Ubf, 256, nullptr, 0,
                fc2b, OUT + (size_t)c*CHWr*192, 192, Ab, 192, bn3g,bn3b,bn3m,bn3v, 192);
        }
    }
}

// Round 17
// 624.717 us; speedup vs baseline: 1.0497x; 1.0161x over previous
//
#include <hip/hip_runtime.h>
#include <hip/hip_bf16.h>
#include <math.h>

#define BB 8
#define HH 128
#define WW 128
#define HW (HH*WW)          // 16384
#define NPIX (BB*HW)        // 131072

typedef unsigned short u16;
typedef __attribute__((ext_vector_type(4))) float  floatx4;
typedef __attribute__((ext_vector_type(4))) short  short4v;
typedef __attribute__((ext_vector_type(8))) short  short8v;

static __device__ __forceinline__ float gelu_exact(float x){
    return 0.5f*x*(1.0f+erff(x*0.70710678118654752440f));
}
static __device__ __forceinline__ float b2f(u16 v){
    union { unsigned u; float f; } x; x.u = ((unsigned)v)<<16; return x.f;
}
static __device__ __forceinline__ u16 f2b(float f){
    __hip_bfloat16 h = __float2bfloat16(f);
    return *(u16*)&h;
}

// ---------- weight prep: fp32 -> bf16 GEMM weights + transposed pos weights ----------
#define WQ 27648
#define WP 36864
#define WG 18432
#define WF1 49152
#define WF2 49152
#define WTOT (WQ+WP+WG+WF1+WF2)   // 181248
__global__ __launch_bounds__(256) void wprep_k(const float* __restrict__ a,
    const float* __restrict__ b, const float* __restrict__ c,
    const float* __restrict__ d, const float* __restrict__ e,
    const float* __restrict__ posw, u16* __restrict__ o, float* __restrict__ wT)
{
    int i = blockIdx.x*256 + threadIdx.x;
    if (i < 1728){   // wT[tap][192]: wT[tap*192+c] = posw[c*9+tap]
        wT[i] = posw[(i%192)*9 + (i/192)];
    }
    if (i >= WTOT) return;
    float v;
    if (i < WQ) v = a[i];
    else if (i < WQ+WP) v = b[i-WQ];
    else if (i < WQ+WP+WG) v = c[i-WQ-WP];
    else if (i < WQ+WP+WG+WF1) v = d[i-WQ-WP-WG];
    else v = e[i-WQ-WP-WG-WF1];
    o[i] = f2b(v);
}

// ---------- pos depthwise 3x3 + bias + residual -> bf16 A; LDS halo, 2 px/thread ----------
// block = 192 thr = 8 consecutive pixels x 48 c4; stage 3x10x192ch halo in LDS (22.5 KB)
__global__ __launch_bounds__(192) void pos_conv_k(const float* __restrict__ x,
    const float* __restrict__ wT, const float* __restrict__ bias, u16* __restrict__ out)
{
    __shared__ float4 lds[3][10][48];
    int bid = blockIdx.x;
    int sb = (bid & 7)*(gridDim.x >> 3) + (bid >> 3);   // XCD image-slice swizzle
    int t = threadIdx.x;
    int unit = sb;                       // over NPIX/8 column-octets
    int x0 = (unit & 15)*8;
    int hy = (unit >> 4) & 127;
    int b  = unit >> 11;

    const float4* x4 = (const float4*)x;
    float4 z4 = make_float4(0.f,0.f,0.f,0.f);
    // stage 30 (row,col) positions x 48 c4 groups = 1440 float4 slots
    for (int i = t; i < 1440; i += 192){
        int c4s = i % 48;
        int rc  = i / 48;
        int r   = rc / 10;
        int cp  = rc % 10;
        int hh  = hy + r - 1;
        int cx  = x0 + cp - 1;
        float4 v = z4;
        if ((unsigned)hh < HH && (unsigned)cx < WW)
            v = x4[((size_t)(b*HH+hh)*WW + cx)*48 + c4s];
        lds[r][cp][c4s] = v;
    }
    __syncthreads();

    int c4 = t % 48;
    int p0 = (t / 48)*2;        // this thread's two pixels: p0, p0+1 (cols x0+p0..)
    int c0 = c4*4;
    floatx4 wv[9];
    #pragma unroll
    for (int tap=0; tap<9; tap++)
        wv[tap] = *(const floatx4*)&wT[tap*192 + c0];

    // load 3 rows x 4 cols window covering both pixels
    float4 xv[3][4];
    #pragma unroll
    for (int i=0;i<3;i++)
        #pragma unroll
        for (int k=0;k<4;k++)
            xv[i][k] = lds[i][p0+k][c4];

    float4 bias4 = *(const float4*)(bias + c0);
    float4 acc0 = bias4, acc1 = bias4;
    #pragma unroll
    for (int i=0;i<3;i++){
        #pragma unroll
        for (int k=0;k<3;k++){
            floatx4 w = wv[i*3+k];
            float4 a = xv[i][k];
            float4 bqq = xv[i][k+1];
            acc0.x = fmaf(w[0], a.x, acc0.x);
            acc0.y = fmaf(w[1], a.y, acc0.y);
            acc0.z = fmaf(w[2], a.z, acc0.z);
            acc0.w = fmaf(w[3], a.w, acc0.w);
            acc1.x = fmaf(w[0], bqq.x, acc1.x);
            acc1.y = fmaf(w[1], bqq.y, acc1.y);
            acc1.z = fmaf(w[2], bqq.z, acc1.z);
            acc1.w = fmaf(w[3], bqq.w, acc1.w);
        }
    }
    float4 xc0 = xv[1][1];   // original x at output pixels (always in range)
    float4 xc1 = xv[1][2];
    acc0.x += xc0.x; acc0.y += xc0.y; acc0.z += xc0.z; acc0.w += xc0.w;
    acc1.x += xc1.x; acc1.y += xc1.y; acc1.z += xc1.z; acc1.w += xc1.w;

    size_t pix0 = (size_t)(b*HH + hy)*WW + x0 + p0;
    short4v o0, o1;
    o0.x=(short)f2b(acc0.x); o0.y=(short)f2b(acc0.y);
    o0.z=(short)f2b(acc0.z); o0.w=(short)f2b(acc0.w);
    o1.x=(short)f2b(acc1.x); o1.y=(short)f2b(acc1.y);
    o1.z=(short)f2b(acc1.z); o1.w=(short)f2b(acc1.w);
    *(short4v*)(out + pix0*192 + c0) = o0;
    *(short4v*)(out + (pix0+1)*192 + c0) = o1;
}

// ---------- LayerNorm over C=192, bf16 in -> bf16 out, wave per pixel ----------
__global__ __launch_bounds__(256) void ln_k(const u16* __restrict__ in,
    const float* __restrict__ g, const float* __restrict__ bta, u16* __restrict__ out)
{
    int wid = threadIdx.x >> 6, lane = threadIdx.x & 63;
    size_t pix = (size_t)blockIdx.x*4 + wid;
    const u16* row = in + pix*192;
    float x0 = b2f(row[lane]), x1 = b2f(row[lane+64]), x2 = b2f(row[lane+128]);
    float s = x0+x1+x2;
    float q = x0*x0 + x1*x1 + x2*x2;
    #pragma unroll
    for (int off=32; off; off>>=1){ s += __shfl_xor(s,off,64); q += __shfl_xor(q,off,64); }
    float mean = s*(1.f/192.f);
    float var  = q*(1.f/192.f) - mean*mean;
    float inv  = rsqrtf(var + 1e-6f);
    u16* orow = out + pix*192;
    orow[lane]     = f2b((x0-mean)*inv*g[lane]     + bta[lane]);
    orow[lane+64]  = f2b((x1-mean)*inv*g[lane+64]  + bta[lane+64]);
    orow[lane+128] = f2b((x2-mean)*inv*g[lane+128] + bta[lane+128]);
}

// ---------- bf16 MFMA GEMM: W-in-LDS once, A streamed; grid=(m,n) for XCD A-locality ----------
#define GM_NONE 0
#define GM_RES 1
#define GM_GELU_BN 2
#define GM_BN_RES 3
#define GM_BIAS_RELU 4
#define WSTR 264   // LDS row stride in shorts: 528B = 132 dw; 132%32=4 -> 2-way only

template<int MODE, int K, bool SPLIT=false>
__global__ __launch_bounds__(256) void gemm_bf16_k(
    const u16* __restrict__ A, int lda,
    const u16* __restrict__ A2, int lda2,
    const u16* __restrict__ W,
    void* __restrict__ Cv, int ldc,
    const u16* __restrict__ R, int ldr,
    const float* __restrict__ bg, const float* __restrict__ bb,
    const float* __restrict__ bm_, const float* __restrict__ bv,
    int N)
{
    __shared__ u16 Ws[64*WSTR];
    int t = threadIdx.x;
    int bn = blockIdx.y * 64;
    int bm = blockIdx.x * 256;
    {
        constexpr int KQ = K/4;
        int brow = t >> 2, bq = t & 3;
        int n = bn + brow;
        bool nv = n < N;
        const u16* src = W + (size_t)n*K + bq*KQ;
        #pragma unroll
        for (int j=0; j<KQ; j+=8){
            short8v v = {};
            if (nv) v = *(const short8v*)(src + j);
            *(short8v*)&Ws[brow*WSTR + bq*KQ + j] = v;
        }
    }
    __syncthreads();
    int wave = t >> 6, lane = t & 63;
    int wm = wave*64;
    int lr = lane & 15, lk = lane >> 4;
    const u16* arow  = A + (size_t)(bm + wm + lr)*lda + lk*8;
    const u16* arow2 = SPLIT ? (A2 + (size_t)(bm + wm + lr)*lda2 + lk*8) : nullptr;
    floatx4 acc[4][4] = {};
    #pragma unroll
    for (int k0 = 0; k0 < K; k0 += 32){
        short8v afr[4];
        if (SPLIT && k0 >= 96){
            #pragma unroll
            for (int m=0;m<4;m++)
                afr[m] = *(const short8v*)(arow2 + (size_t)(m*16)*lda2 + (k0-96));
        } else {
            #pragma unroll
            for (int m=0;m<4;m++)
                afr[m] = *(const short8v*)(arow + (size_t)(m*16)*lda + k0);
        }
        #pragma unroll
        for (int n2=0;n2<4;n2++){
            short8v bfr = *(const short8v*)&Ws[(n2*16+lr)*WSTR + k0 + lk*8];
            #pragma unroll
            for (int m=0;m<4;m++)
                acc[m][n2] = __builtin_amdgcn_mfma_f32_16x16x32_bf16(afr[m], bfr, acc[m][n2], 0,0,0);
        }
    }
    #pragma unroll
    for (int m=0;m<4;m++){
        #pragma unroll
        for (int n2=0;n2<4;n2++){
            int gcol = bn + n2*16 + lr;
            if (gcol >= N) continue;
            #pragma unroll
            for (int rg=0; rg<4; rg++){
                int grow = bm + wm + m*16 + lk*4 + rg;
                float v = acc[m][n2][rg];
                if (MODE == GM_RES){
                    v += b2f(R[(size_t)grow*ldr + gcol]);
                    ((u16*)Cv)[(size_t)grow*ldc + gcol] = f2b(v);
                } else if (MODE == GM_BN_RES){
                    float bnv = (v - bm_[gcol])*rsqrtf(bv[gcol]+1e-5f)*bg[gcol] + bb[gcol];
                    ((float*)Cv)[(size_t)grow*ldc + gcol] = bnv + b2f(R[(size_t)grow*ldr + gcol]);
                } else if (MODE == GM_GELU_BN){
                    float gl = gelu_exact(v);
                    v = (gl - bm_[gcol])*rsqrtf(bv[gcol]+1e-5f)*bg[gcol] + bb[gcol];
                    ((u16*)Cv)[(size_t)grow*ldc + gcol] = f2b(v);
                } else if (MODE == GM_BIAS_RELU){
                    ((u16*)Cv)[(size_t)grow*ldc + gcol] = f2b(fmaxf(v + bg[gcol], 0.f));
                } else {
                    ((u16*)Cv)[(size_t)grow*ldc + gcol] = f2b(v);
                }
            }
        }
    }
}

// ---------- gate stage 2: sigmoid(G1 @ w2 + b2) per pixel, G1 bf16 ----------
__global__ __launch_bounds__(256) void gate2_k(const u16* __restrict__ G1,
    const float* __restrict__ w2, const float* __restrict__ b2, float* __restrict__ gpix)
{
    int pix = blockIdx.x*256 + threadIdx.x;
    const short4v* g4 = (const short4v*)(G1 + (size_t)pix*96);
    const float4* w4 = (const float4*)w2;
    float s = b2[0];
    #pragma unroll
    for (int j=0;j<24;j++){
        short4v g = g4[j]; float4 w = w4[j];
        s += b2f((u16)g.x)*w.x + b2f((u16)g.y)*w.y + b2f((u16)g.z)*w.z + b2f((u16)g.w)*w.w;
    }
    gpix[pix] = 1.f/(1.f+expf(-s));
}

// ---------- deterministic mean of gpix -> dyn_k ----------
__global__ __launch_bounds__(1024) void gate_reduce_k(const float* __restrict__ gpix,
                                                      float* __restrict__ dynk)
{
    __shared__ float sm[16];
    float s = 0.f;
    for (int i=threadIdx.x; i<NPIX; i+=1024) s += gpix[i];
    #pragma unroll
    for (int off=32; off; off>>=1) s += __shfl_xor(s,off,64);
    int wid = threadIdx.x>>6, lane = threadIdx.x&63;
    if (lane==0) sm[wid]=s;
    __syncthreads();
    if (threadIdx.x==0){
        float tot=0.f; for (int i=0;i<16;i++) tot+=sm[i];
        *dynk = floorf(12.0f * (tot/(float)NPIX));
    }
}

// ---------- qkv depthwise 3x3 (288 ch), 4-col sweep, LDS weights, XCD-swizzled ----------
#define QPOS(c8) ((c8)*8 + ((c8)>>2)*4)
#define QTAPSTRIDE 324
__global__ __launch_bounds__(256) void qkv_dw_k(const u16* __restrict__ in,
    const float* __restrict__ w, u16* __restrict__ out, size_t planeStride)
{
    __shared__ float wlds[9*QTAPSTRIDE];
    int t = threadIdx.x;
    for (int i=t; i<2592; i+=256){
        int tap = i/288, cc = i%288;
        wlds[tap*QTAPSTRIDE + QPOS(cc>>3) + (cc&7)] = w[cc*9+tap];
    }
    __syncthreads();
    int bid = blockIdx.x;
    int sb = (bid & 7)*(gridDim.x >> 3) + (bid >> 3);
    int idx = sb*256 + t;
    int c8 = idx % 36; int pq = idx / 36;
    int xg = pq & 31; int hy = (pq >> 5) & 127; int img = pq >> 12;
    int x0 = xg*4;
    int c0 = c8*8;
    int wofs = QPOS(c8);
    float acc[4][8] = {{0.f}};
    #pragma unroll
    for (int ky=0; ky<3; ky++){
        int hh = hy + ky - 1; if ((unsigned)hh >= HH) continue;
        float wr[3][8];
        #pragma unroll
        for (int kx=0; kx<3; kx++){
            floatx4 wa = *(const floatx4*)&wlds[(ky*3+kx)*QTAPSTRIDE + wofs];
            floatx4 wb = *(const floatx4*)&wlds[(ky*3+kx)*QTAPSTRIDE + wofs + 4];
            #pragma unroll
            for (int j=0;j<4;j++){ wr[kx][j]=wa[j]; wr[kx][4+j]=wb[j]; }
        }
        const u16* rowp = in + ((size_t)(img*HH+hh)*WW)*288 + c0;
        #pragma unroll
        for (int cc=0; cc<6; cc++){
            int cx = x0 - 1 + cc;
            if ((unsigned)cx >= WW) continue;
            short8v v = *(const short8v*)(rowp + (size_t)cx*288);
            float vf[8];
            #pragma unroll
            for (int j=0;j<8;j++) vf[j] = b2f((u16)v[j]);
            #pragma unroll
            for (int dx=0; dx<4; dx++){
                int kx = cc - dx;
                if (kx < 0 || kx >= 3) continue;
                #pragma unroll
                for (int j=0;j<8;j++) acc[dx][j] = fmaf(wr[kx][j], vf[j], acc[dx][j]);
            }
        }
    }
    size_t pix0 = (size_t)(img*HH+hy)*WW + x0;
    int sec = c0/96, qc0 = c0 - sec*96;
    u16* outp = out + (size_t)sec*planeStride + qc0;
    #pragma unroll
    for (int dx=0; dx<4; dx++){
        short8v o;
        #pragma unroll
        for (int j=0;j<8;j++) o[j] = (short)f2b(acc[dx][j]);
        *(short8v*)(outp + (pix0+dx)*96) = o;
    }
}

// ---------- Gram partials per (img,head,slice), Q/K planes, vectorized staging ----------
__global__ __launch_bounds__(256) void gram_k(const u16* __restrict__ Qp,
    const u16* __restrict__ Kp, float* __restrict__ part)
{
    int bh = blockIdx.x;
    int slice = blockIdx.y;
    int img = bh >> 3, h = bh & 7;
    const u16* Qb = Qp + (size_t)img*HW*96 + h*12;
    const u16* Kb = Kp + (size_t)img*HW*96 + h*12;
    __shared__ float qs[64][12];
    __shared__ float ks[64][12];
    int t = threadIdx.x;
    float acc = 0.f;
    int c = (t<144) ? t/12 : (t<156 ? t-144 : t-156);
    int d = (t<144) ? t%12 : 0;
    for (int st=0; st<16; st++){
        int pix0 = slice*1024 + st*64;
        __syncthreads();
        for (int i=t; i<384; i+=256){
            int p = i/6, j = i%6;
            const u16* src = (j<3) ? (Qb + (size_t)(pix0+p)*96 + j*4)
                                   : (Kb + (size_t)(pix0+p)*96 + (j-3)*4);
            short4v v = *(const short4v*)src;
            float f0=b2f((u16)v.x), f1=b2f((u16)v.y), f2=b2f((u16)v.z), f3=b2f((u16)v.w);
            if (j<3){ int jj=j*4;     qs[p][jj]=f0; qs[p][jj+1]=f1; qs[p][jj+2]=f2; qs[p][jj+3]=f3; }
            else    { int jj=(j-3)*4; ks[p][jj]=f0; ks[p][jj+1]=f1; ks[p][jj+2]=f2; ks[p][jj+3]=f3; }
        }
        __syncthreads();
        if (t<144){        for (int p=0;p<64;p++) acc = fmaf(qs[p][c], ks[p][d], acc); }
        else if (t<156){   for (int p=0;p<64;p++) acc = fmaf(qs[p][c], qs[p][c], acc); }
        else if (t<168){   for (int p=0;p<64;p++) acc = fmaf(ks[p][c], ks[p][c], acc); }
    }
    if (t<168) part[((size_t)bh*16 + slice)*168 + t] = acc;
}

__global__ __launch_bounds__(256) void gram_combine_k(const float* __restrict__ part,
                                                      float* __restrict__ gram, int n)
{
    int i = blockIdx.x*256 + threadIdx.x;
    if (i >= n) return;
    int bh = i/168, t = i%168;
    float s = 0.f;
    for (int sl=0; sl<16; sl++) s += part[((size_t)bh*16+sl)*168 + t];
    gram[i] = s;
}

// ---------- attn 12x12: normalize, temperature, top-k mask, softmax ----------
__global__ __launch_bounds__(256) void attn_k(const float* __restrict__ gram,
    const float* __restrict__ temp, const float* __restrict__ dynk_p,
    const float* __restrict__ a1, const float* __restrict__ a2,
    const float* __restrict__ a3, const float* __restrict__ a4,
    float* __restrict__ attnW)
{
    int bh = blockIdx.x;
    int h = bh & 7;
    __shared__ float av[12][12];
    __shared__ float mv[12][12];
    __shared__ float nq[12], nk[12];
    int t = threadIdx.x;
    if (t < 12) nq[t] = fmaxf(sqrtf(gram[bh*168+144+t]), 1e-12f);
    else if (t < 24) nk[t-12] = fmaxf(sqrtf(gram[bh*168+156+(t-12)]), 1e-12f);
    __syncthreads();
    if (t < 144){
        int c=t/12, d=t%12;
        av[c][d] = gram[bh*168+t] / (nq[c]*nk[d]) * temp[h];
    }
    __syncthreads();
    float dk = *dynk_p;
    if (t < 144){
        int c=t/12, d=t%12; float v = av[c][d];
        int r = 0;
        #pragma unroll
        for (int j=0;j<12;j++){
            float o = av[c][j];
            r += (o > v) ? 1 : ((o == v && j < d) ? 1 : 0);
        }
        mv[c][d] = ((float)r < dk) ? v : -INFINITY;
    }
    __syncthreads();
    if (t < 12){
        float mx = -INFINITY;
        for (int d2=0; d2<12; d2++) mx = fmaxf(mx, mv[t][d2]);
        float e[12]; float s = 0.f;
        for (int d2=0; d2<12; d2++){ e[d2] = expf(mv[t][d2]-mx); s += e[d2]; }
        float sc = (a1[0]+a2[0]+a3[0]+a4[0]) / s;
        for (int d2=0; d2<12; d2++) attnW[(size_t)bh*144 + t*12 + d2] = e[d2]*sc;
    }
}

// ---------- attn apply -> P96 bf16 (V plane input); thread = (pixel, head) ----------
__global__ __launch_bounds__(256) void attn_apply_k(const u16* __restrict__ Vp,
    const float* __restrict__ attnW, u16* __restrict__ P)
{
    int gid = blockIdx.x*256 + threadIdx.x;
    int h = gid % 8; size_t pix = (size_t)(gid / 8);
    int img = (int)(pix >> 14);
    const u16* vp = Vp + pix*96 + h*12;
    float vf[12];
    #pragma unroll
    for (int j=0;j<3;j++){
        short4v v = *(const short4v*)(vp + j*4);
        vf[j*4+0]=b2f((u16)v.x); vf[j*4+1]=b2f((u16)v.y);
        vf[j*4+2]=b2f((u16)v.z); vf[j*4+3]=b2f((u16)v.w);
    }
    const float* awb = attnW + ((size_t)(img*8+h))*144;
    u16 o[12];
    #pragma unroll
    for (int cc=0; cc<12; cc++){
        const float4* ap = (const float4*)(awb + cc*12);
        float4 a0 = ap[0], a1 = ap[1], a2 = ap[2];
        float s = a0.x*vf[0] + a0.y*vf[1] + a0.z*vf[2] + a0.w*vf[3]
                + a1.x*vf[4] + a1.y*vf[5] + a1.z*vf[6] + a1.w*vf[7]
                + a2.x*vf[8] + a2.y*vf[9] + a2.z*vf[10]+ a2.w*vf[11];
        o[cc] = f2b(s);
    }
    u16* op = P + pix*96 + h*12;
    *(short4v*)(op)   = *(short4v*)&o[0];
    *(short4v*)(op+4) = *(short4v*)&o[4];
    *(short4v*)(op+8) = *(short4v*)&o[8];
}

// ---------- FFN multi-scale depthwise, row-sweep per scale, XCD-swizzled ----------
template<int KS>
__global__ __launch_bounds__(256) void ffn_dw_g(const u16* __restrict__ V0,
    const float* __restrict__ wsrc, const float* __restrict__ bsrc, int cbase,
    const float* __restrict__ bn2g, const float* __restrict__ bn2b,
    const float* __restrict__ bn2m, const float* __restrict__ bn2v,
    u16* __restrict__ U)
{
    constexpr int PAD = KS/2;
    __shared__ float wlds[KS*KS*64];
    __shared__ float bng[64], bnb[64], bnm[64], bnvr[64];
    int t = threadIdx.x;
    for (int i=t; i<KS*KS*64; i+=256){
        int tap = i >> 6, cc = i & 63;
        wlds[tap*64 + cc] = wsrc[cc*KS*KS + tap];
    }
    if (t < 64){
        bng[t] = bn2g[cbase+t]; bnb[t] = bn2b[cbase+t];
        bnm[t] = bn2m[cbase+t]; bnvr[t] = rsqrtf(bn2v[cbase+t]+1e-5f);
    }
    __syncthreads();
    int ci = t & 7, seg = t >> 3;
    int bid = blockIdx.x;
    int rowid = (bid & 7)*(gridDim.x >> 3) + (bid >> 3);
    int img = rowid >> 7, hy = rowid & 127;
    int c0r = ci*8;
    int c0 = cbase + c0r;
    int x0 = seg*4;
    float acc[4][8];
    {
        floatx4 b0 = *(const floatx4*)(bsrc + c0r);
        floatx4 b1 = *(const floatx4*)(bsrc + c0r + 4);
        #pragma unroll
        for (int dx=0;dx<4;dx++){
            #pragma unroll
            for (int j=0;j<4;j++){ acc[dx][j]=b0[j]; acc[dx][4+j]=b1[j]; }
        }
    }
    #pragma unroll
    for (int ky=0; ky<KS; ky++){
        int hh = hy + ky - PAD;
        if ((unsigned)hh >= HH) continue;
        float wr[KS][8];
        #pragma unroll
        for (int kx=0; kx<KS; kx++){
            floatx4 wa = *(const floatx4*)&wlds[(ky*KS+kx)*64 + c0r];
            floatx4 wb = *(const floatx4*)&wlds[(ky*KS+kx)*64 + c0r + 4];
            #pragma unroll
            for (int j=0;j<4;j++){ wr[kx][j]=wa[j]; wr[kx][4+j]=wb[j]; }
        }
        const u16* rowp = V0 + ((size_t)(img*HH+hh)*WW)*256 + c0;
        #pragma unroll
        for (int cc=0; cc<4+2*PAD; cc++){
            int cx = x0 - PAD + cc;
            if ((unsigned)cx >= WW) continue;
            short8v v = *(const short8v*)(rowp + (size_t)cx*256);
            float vf[8];
            #pragma unroll
            for (int j=0;j<8;j++) vf[j] = b2f((u16)v[j]);
            #pragma unroll
            for (int dx=0; dx<4; dx++){
                int kx = cc - dx;
                if (kx < 0 || kx >= KS) continue;
                #pragma unroll
                for (int j=0;j<8;j++) acc[dx][j] = fmaf(wr[kx][j], vf[j], acc[dx][j]);
            }
        }
    }
    size_t rbase = (size_t)(img*HH+hy)*WW;
    #pragma unroll
    for (int dx=0; dx<4; dx++){
        size_t pix = rbase + x0 + dx;
        short8v vc = *(const short8v*)(V0 + pix*256 + c0);
        short8v o;
        #pragma unroll
        for (int j=0;j<8;j++){
            float v0c = b2f((u16)vc[j]);
            float u1 = acc[dx][j] + v0c;
            float gl = gelu_exact(u1);
            float bn = (gl - bnm[c0r+j])*bnvr[c0r+j]*bng[c0r+j] + bnb[c0r+j];
            o[j] = (short)f2b(bn*v0c);
        }
        *(short8v*)(U + pix*256 + c0) = o;
    }
}

extern "C" void kernel_launch(void* const* d_in, const int* in_sizes, int n_in,
                              void* d_out, int out_size, void* d_ws, size_t ws_size,
                              hipStream_t stream)
{
    const float* x     = (const float*)d_in[0];
    const float* pos_w = (const float*)d_in[1];
    const float* pos_b = (const float*)d_in[2];
    const float* ln1g  = (const float*)d_in[3];
    const float* ln1b  = (const float*)d_in[4];
    const float* temp  = (const float*)d_in[5];
    const float* qkvw  = (const float*)d_in[6];
    const float* qkvdw = (const float*)d_in[7];
    const float* projw = (const float*)d_in[8];
    const float* gw1   = (const float*)d_in[9];
    const float* gb1   = (const float*)d_in[10];
    const float* gw2   = (const float*)d_in[11];
    const float* gb2   = (const float*)d_in[12];
    const float* a1    = (const float*)d_in[13];
    const float* a2    = (const float*)d_in[14];
    const float* a3    = (const float*)d_in[15];
    const float* a4    = (const float*)d_in[16];
    const float* ln2g  = (const float*)d_in[17];
    const float* ln2b  = (const float*)d_in[18];
    const float* fc1w  = (const float*)d_in[19];
    const float* bn1g  = (const float*)d_in[20];
    const float* bn1b  = (const float*)d_in[21];
    const float* bn1m  = (const float*)d_in[22];
    const float* bn1v  = (const float*)d_in[23];
    const float* bn2g  = (const float*)d_in[24];
    const float* bn2b  = (const float*)d_in[25];
    const float* bn2m  = (const float*)d_in[26];
    const float* bn2v  = (const float*)d_in[27];
    const float* fc2w  = (const float*)d_in[28];
    const float* bn3g  = (const float*)d_in[29];
    const float* bn3b  = (const float*)d_in[30];
    const float* bn3m  = (const float*)d_in[31];
    const float* bn3v  = (const float*)d_in[32];
    const float* dw0w  = (const float*)d_in[33];
    const float* dw0b  = (const float*)d_in[34];
    const float* dw1w  = (const float*)d_in[35];
    const float* dw1b  = (const float*)d_in[36];
    const float* dw2w  = (const float*)d_in[37];
    const float* dw2b  = (const float*)d_in[38];
    const float* dw3w  = (const float*)d_in[39];
    const float* dw3b  = (const float*)d_in[40];

    float* OUT = (float*)d_out;      // final fp32 output (written once by fc2)

    // ---- fixed small buffers + bf16 residual stream A ----
    char* p = (char*)d_ws;
    float* gpix  = (float*)p;                 p += (size_t)NPIX*4;
    float* dynk  = (float*)p;                 p += 256;
    float* gpart = (float*)p;                 p += 64*16*168*4;
    float* gram  = (float*)p;                 p += 64*168*4;
    float* attnW = (float*)p;                 p += 64*144*4;
    float* wposT = (float*)p;                 p += 1728*4;
    u16*   wbf   = (u16*)p;                   p += (size_t)WTOT*2;
    u16*   Abf   = (u16*)p;                   p += (size_t)NPIX*192*2;   // 50.3 MB
    size_t fixedB = (size_t)(p - (char*)d_ws);

    // ---- choose chunk size from ws_size: per-image = Y(192)+B1(288)+B2(288) bf16 ----
    size_t perImg = (size_t)HW*2*(192+288+288);   // 25,165,824
    int CBr = 2;
    if (ws_size >= fixedB + 8*perImg) CBr = 8;
    else if (ws_size >= fixedB + 4*perImg) CBr = 4;
    int NCHUNKr = BB/CBr;
    size_t CHWr = (size_t)CBr*HW;

    u16* Ybf = (u16*)p;                   p += CHWr*192*2;
    u16* B1  = (u16*)p;                   p += CHWr*288*2;
    u16* B2  = (u16*)p;
    u16* qkvwb = wbf;
    u16* projwb= wbf + WQ;
    u16* gw1b  = wbf + WQ + WP;
    u16* fc1b  = wbf + WQ + WP + WG;
    u16* fc2b  = wbf + WQ + WP + WG + WF1;
    u16* G1bf  = B1;     // gate phase
    u16* QKVbf = B1;     // qkv out (288 interleaved)
    u16* QKVdbf= B2;     // qkv_dw out: Q|K|V planes of CHWr*96 each
    u16* P96   = B1;     // attn out (QKV dead)
    u16* Zbf   = B2;     // LN2 out (QKVd dead)
    u16* V0bf  = B1;     // fc1 out (P96 dead)
    u16* Ubf   = B2;     // ffn out (Z dead)

    wprep_k<<<(WTOT+255)/256, 256, 0, stream>>>(qkvw, projw, gw1, fc1w, fc2w,
                                                pos_w, wbf, wposT);
    pos_conv_k<<<NPIX/8, 192, 0, stream>>>(x, wposT, pos_b, Abf);

    // gate phase
    for (int c=0; c<NCHUNKr; c++){
        const u16* Ab = Abf + (size_t)c*CHWr*192;
        ln_k<<<CHWr/4, 256, 0, stream>>>(Ab, ln1g, ln1b, Ybf);
        dim3 g(CHWr/256, 2);
        gemm_bf16_k<GM_BIAS_RELU,192><<<g, 256, 0, stream>>>(Ybf, 192, nullptr, 0,
            gw1b, G1bf, 96, nullptr, 0, gb1, nullptr, nullptr, nullptr, 96);
        gate2_k<<<CHWr/256, 256, 0, stream>>>(G1bf, gw2, gb2, gpix + (size_t)c*CHWr);
    }
    gate_reduce_k<<<1, 1024, 0, stream>>>(gpix, dynk);

    // main phase
    for (int c=0; c<NCHUNKr; c++){
        u16* Ab = Abf + (size_t)c*CHWr*192;
        if (NCHUNKr > 1)   // single-chunk mode: Ybf from gate phase is still valid
            ln_k<<<CHWr/4, 256, 0, stream>>>(Ab, ln1g, ln1b, Ybf);
        {
            dim3 g(CHWr/256, 5);
            gemm_bf16_k<GM_NONE,96><<<g, 256, 0, stream>>>(Ybf, 192, nullptr, 0,
                qkvwb, QKVbf, 288, nullptr, 0, nullptr,nullptr,nullptr,nullptr, 288);
        }
        size_t pstr = CHWr*96;
        qkv_dw_k<<<CHWr/4*36/256, 256, 0, stream>>>(QKVbf, qkvdw, QKVdbf, pstr);
        { dim3 g(CBr*8, 16); gram_k<<<g, 256, 0, stream>>>(QKVdbf, QKVdbf + pstr, gpart); }
        gram_combine_k<<<(CBr*8*168+255)/256, 256, 0, stream>>>(gpart, gram, CBr*8*168);
        attn_k<<<CBr*8, 256, 0, stream>>>(gram, temp, dynk, a1,a2,a3,a4, attnW);
        attn_apply_k<<<CHWr*8/256, 256, 0, stream>>>(QKVdbf + 2*pstr, attnW, P96);
        {   // proj + residual: A += [P96 | Y[:,96:]] @ projw^T  (bf16 in-place)
            dim3 g(CHWr/256, 3);
            gemm_bf16_k<GM_RES,192,true><<<g, 256, 0, stream>>>(P96, 96, Ybf+96, 192,
                projwb, Ab, 192, Ab, 192, nullptr,nullptr,nullptr,nullptr, 192);
        }
        ln_k<<<CHWr/4, 256, 0, stream>>>(Ab, ln2g, ln2b, Zbf);
        {
            dim3 g(CHWr/256, 4);
            gemm_bf16_k<GM_GELU_BN,192><<<g, 256, 0, stream>>>(Zbf, 192, nullptr, 0,
                fc1b, V0bf, 256, nullptr, 0, bn1g,bn1b,bn1m,bn1v, 256);
        }
        int rows = (int)(CHWr/WW);
        ffn_dw_g<1><<<rows, 256, 0, stream>>>(V0bf, dw0w, dw0b, 0,
            bn2g,bn2b,bn2m,bn2v, Ubf);
        ffn_dw_g<3><<<rows, 256, 0, stream>>>(V0bf, dw1w, dw1b, 64,
            bn2g,bn2b,bn2m,bn2v, Ubf);
        ffn_dw_g<5><<<rows, 256, 0, stream>>>(V0bf, dw2w, dw2b, 128,
            bn2g,bn2b,bn2m,bn2v, Ubf);
        ffn_dw_g<7><<<rows, 256, 0, stream>>>(V0bf, dw3w, dw3b, 192,
            bn2g,bn2b,bn2m,bn2v, Ubf);
        {   // fc2 + bn3 + residual -> fp32 OUT
            dim3 g(CHWr/256, 3);
            gemm_bf16_k<GM_BN_RES,256><<<g, 256, 0, stream>>>(Ubf, 256, nullptr, 0,
                fc2b, OUT + (size_t)c*CHWr*192, 192, Ab, 192, bn3g,bn3b,bn3m,bn3v, 192);
        }
    }
}

// Round 18
// 613.210 us; speedup vs baseline: 1.0694x; 1.0188x over previous
//
#include <hip/hip_runtime.h>
#include <hip/hip_bf16.h>
#include <math.h>

#define BB 8
#define HH 128
#define WW 128
#define HW (HH*WW)          // 16384
#define NPIX (BB*HW)        // 131072

typedef unsigned short u16;
typedef __attribute__((ext_vector_type(4))) float  floatx4;
typedef __attribute__((ext_vector_type(4))) short  short4v;
typedef __attribute__((ext_vector_type(8))) short  short8v;

static __device__ __forceinline__ float gelu_exact(float x){
    return 0.5f*x*(1.0f+erff(x*0.70710678118654752440f));
}
static __device__ __forceinline__ float b2f(u16 v){
    union { unsigned u; float f; } x; x.u = ((unsigned)v)<<16; return x.f;
}
static __device__ __forceinline__ u16 f2b(float f){
    __hip_bfloat16 h = __float2bfloat16(f);
    return *(u16*)&h;
}

// ---------- weight prep: fp32 -> bf16 GEMM weights + transposed pos weights ----------
#define WQ 27648
#define WP 36864
#define WG 18432
#define WF1 49152
#define WF2 49152
#define WTOT (WQ+WP+WG+WF1+WF2)   // 181248
__global__ __launch_bounds__(256) void wprep_k(const float* __restrict__ a,
    const float* __restrict__ b, const float* __restrict__ c,
    const float* __restrict__ d, const float* __restrict__ e,
    const float* __restrict__ posw, u16* __restrict__ o, float* __restrict__ wT)
{
    int i = blockIdx.x*256 + threadIdx.x;
    if (i < 1728){   // wT[tap][192]: wT[tap*192+c] = posw[c*9+tap]
        wT[i] = posw[(i%192)*9 + (i/192)];
    }
    if (i >= WTOT) return;
    float v;
    if (i < WQ) v = a[i];
    else if (i < WQ+WP) v = b[i-WQ];
    else if (i < WQ+WP+WG) v = c[i-WQ-WP];
    else if (i < WQ+WP+WG+WF1) v = d[i-WQ-WP-WG];
    else v = e[i-WQ-WP-WG-WF1];
    o[i] = f2b(v);
}

// ---------- pos depthwise 3x3 + bias + residual -> bf16 A; LDS halo, 2 px/thread ----------
__global__ __launch_bounds__(192) void pos_conv_k(const float* __restrict__ x,
    const float* __restrict__ wT, const float* __restrict__ bias, u16* __restrict__ out)
{
    __shared__ float4 lds[3][10][48];
    int bid = blockIdx.x;
    int sb = (bid & 7)*(gridDim.x >> 3) + (bid >> 3);   // XCD image-slice swizzle
    int t = threadIdx.x;
    int unit = sb;                       // over NPIX/8 column-octets
    int x0 = (unit & 15)*8;
    int hy = (unit >> 4) & 127;
    int b  = unit >> 11;

    const float4* x4 = (const float4*)x;
    float4 z4 = make_float4(0.f,0.f,0.f,0.f);
    for (int i = t; i < 1440; i += 192){
        int c4s = i % 48;
        int rc  = i / 48;
        int r   = rc / 10;
        int cp  = rc % 10;
        int hh  = hy + r - 1;
        int cx  = x0 + cp - 1;
        float4 v = z4;
        if ((unsigned)hh < HH && (unsigned)cx < WW)
            v = x4[((size_t)(b*HH+hh)*WW + cx)*48 + c4s];
        lds[r][cp][c4s] = v;
    }
    __syncthreads();

    int c4 = t % 48;
    int p0 = (t / 48)*2;
    int c0 = c4*4;
    floatx4 wv[9];
    #pragma unroll
    for (int tap=0; tap<9; tap++)
        wv[tap] = *(const floatx4*)&wT[tap*192 + c0];

    float4 xv[3][4];
    #pragma unroll
    for (int i=0;i<3;i++)
        #pragma unroll
        for (int k=0;k<4;k++)
            xv[i][k] = lds[i][p0+k][c4];

    float4 bias4 = *(const float4*)(bias + c0);
    float4 acc0 = bias4, acc1 = bias4;
    #pragma unroll
    for (int i=0;i<3;i++){
        #pragma unroll
        for (int k=0;k<3;k++){
            floatx4 w = wv[i*3+k];
            float4 a = xv[i][k];
            float4 bqq = xv[i][k+1];
            acc0.x = fmaf(w[0], a.x, acc0.x);
            acc0.y = fmaf(w[1], a.y, acc0.y);
            acc0.z = fmaf(w[2], a.z, acc0.z);
            acc0.w = fmaf(w[3], a.w, acc0.w);
            acc1.x = fmaf(w[0], bqq.x, acc1.x);
            acc1.y = fmaf(w[1], bqq.y, acc1.y);
            acc1.z = fmaf(w[2], bqq.z, acc1.z);
            acc1.w = fmaf(w[3], bqq.w, acc1.w);
        }
    }
    float4 xc0 = xv[1][1];
    float4 xc1 = xv[1][2];
    acc0.x += xc0.x; acc0.y += xc0.y; acc0.z += xc0.z; acc0.w += xc0.w;
    acc1.x += xc1.x; acc1.y += xc1.y; acc1.z += xc1.z; acc1.w += xc1.w;

    size_t pix0 = (size_t)(b*HH + hy)*WW + x0 + p0;
    short4v o0, o1;
    o0.x=(short)f2b(acc0.x); o0.y=(short)f2b(acc0.y);
    o0.z=(short)f2b(acc0.z); o0.w=(short)f2b(acc0.w);
    o1.x=(short)f2b(acc1.x); o1.y=(short)f2b(acc1.y);
    o1.z=(short)f2b(acc1.z); o1.w=(short)f2b(acc1.w);
    *(short4v*)(out + pix0*192 + c0) = o0;
    *(short4v*)(out + (pix0+1)*192 + c0) = o1;
}

// ---------- LayerNorm over C=192, bf16 in -> bf16 out, wave per pixel ----------
__global__ __launch_bounds__(256) void ln_k(const u16* __restrict__ in,
    const float* __restrict__ g, const float* __restrict__ bta, u16* __restrict__ out)
{
    int wid = threadIdx.x >> 6, lane = threadIdx.x & 63;
    size_t pix = (size_t)blockIdx.x*4 + wid;
    const u16* row = in + pix*192;
    float x0 = b2f(row[lane]), x1 = b2f(row[lane+64]), x2 = b2f(row[lane+128]);
    float s = x0+x1+x2;
    float q = x0*x0 + x1*x1 + x2*x2;
    #pragma unroll
    for (int off=32; off; off>>=1){ s += __shfl_xor(s,off,64); q += __shfl_xor(q,off,64); }
    float mean = s*(1.f/192.f);
    float var  = q*(1.f/192.f) - mean*mean;
    float inv  = rsqrtf(var + 1e-6f);
    u16* orow = out + pix*192;
    orow[lane]     = f2b((x0-mean)*inv*g[lane]     + bta[lane]);
    orow[lane+64]  = f2b((x1-mean)*inv*g[lane+64]  + bta[lane+64]);
    orow[lane+128] = f2b((x2-mean)*inv*g[lane+128] + bta[lane+128]);
}

// ---------- bf16 MFMA GEMM: W-in-LDS once, A streamed; grid=(m,n) for XCD A-locality ----------
#define GM_NONE 0
#define GM_RES 1
#define GM_GELU_BN 2
#define GM_BN_RES 3
#define WSTR 264   // LDS row stride in shorts: 528B = 132 dw; 132%32=4 -> 2-way only

template<int MODE, int K, bool SPLIT=false>
__global__ __launch_bounds__(256) void gemm_bf16_k(
    const u16* __restrict__ A, int lda,
    const u16* __restrict__ A2, int lda2,
    const u16* __restrict__ W,
    void* __restrict__ Cv, int ldc,
    const u16* __restrict__ R, int ldr,
    const float* __restrict__ bg, const float* __restrict__ bb,
    const float* __restrict__ bm_, const float* __restrict__ bv,
    int N)
{
    __shared__ u16 Ws[64*WSTR];
    int t = threadIdx.x;
    int bn = blockIdx.y * 64;
    int bm = blockIdx.x * 256;
    {
        constexpr int KQ = K/4;
        int brow = t >> 2, bq = t & 3;
        int n = bn + brow;
        bool nv = n < N;
        const u16* src = W + (size_t)n*K + bq*KQ;
        #pragma unroll
        for (int j=0; j<KQ; j+=8){
            short8v v = {};
            if (nv) v = *(const short8v*)(src + j);
            *(short8v*)&Ws[brow*WSTR + bq*KQ + j] = v;
        }
    }
    __syncthreads();
    int wave = t >> 6, lane = t & 63;
    int wm = wave*64;
    int lr = lane & 15, lk = lane >> 4;
    const u16* arow  = A + (size_t)(bm + wm + lr)*lda + lk*8;
    const u16* arow2 = SPLIT ? (A2 + (size_t)(bm + wm + lr)*lda2 + lk*8) : nullptr;
    floatx4 acc[4][4] = {};
    #pragma unroll
    for (int k0 = 0; k0 < K; k0 += 32){
        short8v afr[4];
        if (SPLIT && k0 >= 96){
            #pragma unroll
            for (int m=0;m<4;m++)
                afr[m] = *(const short8v*)(arow2 + (size_t)(m*16)*lda2 + (k0-96));
        } else {
            #pragma unroll
            for (int m=0;m<4;m++)
                afr[m] = *(const short8v*)(arow + (size_t)(m*16)*lda + k0);
        }
        #pragma unroll
        for (int n2=0;n2<4;n2++){
            short8v bfr = *(const short8v*)&Ws[(n2*16+lr)*WSTR + k0 + lk*8];
            #pragma unroll
            for (int m=0;m<4;m++)
                acc[m][n2] = __builtin_amdgcn_mfma_f32_16x16x32_bf16(afr[m], bfr, acc[m][n2], 0,0,0);
        }
    }
    #pragma unroll
    for (int m=0;m<4;m++){
        #pragma unroll
        for (int n2=0;n2<4;n2++){
            int gcol = bn + n2*16 + lr;
            if (gcol >= N) continue;
            #pragma unroll
            for (int rg=0; rg<4; rg++){
                int grow = bm + wm + m*16 + lk*4 + rg;
                float v = acc[m][n2][rg];
                if (MODE == GM_RES){
                    v += b2f(R[(size_t)grow*ldr + gcol]);
                    ((u16*)Cv)[(size_t)grow*ldc + gcol] = f2b(v);
                } else if (MODE == GM_BN_RES){
                    float bnv = (v - bm_[gcol])*rsqrtf(bv[gcol]+1e-5f)*bg[gcol] + bb[gcol];
                    ((float*)Cv)[(size_t)grow*ldc + gcol] = bnv + b2f(R[(size_t)grow*ldr + gcol]);
                } else if (MODE == GM_GELU_BN){
                    float gl = gelu_exact(v);
                    v = (gl - bm_[gcol])*rsqrtf(bv[gcol]+1e-5f)*bg[gcol] + bb[gcol];
                    ((u16*)Cv)[(size_t)grow*ldc + gcol] = f2b(v);
                } else {
                    ((u16*)Cv)[(size_t)grow*ldc + gcol] = f2b(v);
                }
            }
        }
    }
}

// ---------- fused gate GEMM: gpix = sigmoid( relu(Y@gw1^T + gb1) . w2 + b2 ) ----------
// tile 256x96, K=192; acc[4][6]; epilogue dot over N=96 via 16-lane shfl tree
#define GSTR 200   // LDS row stride shorts (400B = 100dw; 100%32=4 -> 2-way only)
__global__ __launch_bounds__(256) void gate_gemm_k(
    const u16* __restrict__ A,          // Y bf16, lda=192
    const u16* __restrict__ W,          // gw1 bf16 [96][192]
    const float* __restrict__ gb1, const float* __restrict__ w2,
    const float* __restrict__ b2, float* __restrict__ gpix)
{
    __shared__ u16 Ws[96*GSTR];
    int t = threadIdx.x;
    int bm = blockIdx.x * 256;
    for (int i = t; i < 96*24; i += 256){
        int row = i/24, j = (i%24)*8;
        *(short8v*)&Ws[row*GSTR + j] = *(const short8v*)(W + (size_t)row*192 + j);
    }
    __syncthreads();
    int wave = t >> 6, lane = t & 63;
    int wm = wave*64;
    int lr = lane & 15, lk = lane >> 4;
    const u16* arow = A + (size_t)(bm + wm + lr)*192 + lk*8;
    floatx4 acc[4][6] = {};
    #pragma unroll
    for (int k0 = 0; k0 < 192; k0 += 32){
        short8v afr[4];
        #pragma unroll
        for (int m=0;m<4;m++)
            afr[m] = *(const short8v*)(arow + (size_t)(m*16)*192 + k0);
        #pragma unroll
        for (int n2=0;n2<6;n2++){
            short8v bfr = *(const short8v*)&Ws[(n2*16+lr)*GSTR + k0 + lk*8];
            #pragma unroll
            for (int m=0;m<4;m++)
                acc[m][n2] = __builtin_amdgcn_mfma_f32_16x16x32_bf16(afr[m], bfr, acc[m][n2], 0,0,0);
        }
    }
    // epilogue: per row, dot over 96 cols (6 n-tiles x 16 lr-lanes)
    float gbv[6], w2v[6];
    #pragma unroll
    for (int n2=0;n2<6;n2++){ int col = n2*16 + lr; gbv[n2] = gb1[col]; w2v[n2] = w2[col]; }
    float b2s = b2[0];
    #pragma unroll
    for (int m=0;m<4;m++){
        #pragma unroll
        for (int rg=0;rg<4;rg++){
            float part = 0.f;
            #pragma unroll
            for (int n2=0;n2<6;n2++){
                float v = fmaxf(acc[m][n2][rg] + gbv[n2], 0.f);
                part = fmaf(v, w2v[n2], part);
            }
            #pragma unroll
            for (int off=1; off<16; off<<=1) part += __shfl_xor(part, off, 64);
            if (lr == 0){
                int row = bm + wm + m*16 + lk*4 + rg;
                gpix[row] = 1.f/(1.f+expf(-(part + b2s)));
            }
        }
    }
}

// ---------- deterministic mean of gpix -> dyn_k ----------
__global__ __launch_bounds__(1024) void gate_reduce_k(const float* __restrict__ gpix,
                                                      float* __restrict__ dynk)
{
    __shared__ float sm[16];
    float s = 0.f;
    for (int i=threadIdx.x; i<NPIX; i+=1024) s += gpix[i];
    #pragma unroll
    for (int off=32; off; off>>=1) s += __shfl_xor(s,off,64);
    int wid = threadIdx.x>>6, lane = threadIdx.x&63;
    if (lane==0) sm[wid]=s;
    __syncthreads();
    if (threadIdx.x==0){
        float tot=0.f; for (int i=0;i<16;i++) tot+=sm[i];
        *dynk = floorf(12.0f * (tot/(float)NPIX));
    }
}

// ---------- qkv depthwise 3x3 (288 ch), 4-col sweep, LDS weights, XCD-swizzled ----------
#define QPOS(c8) ((c8)*8 + ((c8)>>2)*4)
#define QTAPSTRIDE 324
__global__ __launch_bounds__(256) void qkv_dw_k(const u16* __restrict__ in,
    const float* __restrict__ w, u16* __restrict__ out, size_t planeStride)
{
    __shared__ float wlds[9*QTAPSTRIDE];
    int t = threadIdx.x;
    for (int i=t; i<2592; i+=256){
        int tap = i/288, cc = i%288;
        wlds[tap*QTAPSTRIDE + QPOS(cc>>3) + (cc&7)] = w[cc*9+tap];
    }
    __syncthreads();
    int bid = blockIdx.x;
    int sb = (bid & 7)*(gridDim.x >> 3) + (bid >> 3);
    int idx = sb*256 + t;
    int c8 = idx % 36; int pq = idx / 36;
    int xg = pq & 31; int hy = (pq >> 5) & 127; int img = pq >> 12;
    int x0 = xg*4;
    int c0 = c8*8;
    int wofs = QPOS(c8);
    float acc[4][8] = {{0.f}};
    #pragma unroll
    for (int ky=0; ky<3; ky++){
        int hh = hy + ky - 1; if ((unsigned)hh >= HH) continue;
        float wr[3][8];
        #pragma unroll
        for (int kx=0; kx<3; kx++){
            floatx4 wa = *(const floatx4*)&wlds[(ky*3+kx)*QTAPSTRIDE + wofs];
            floatx4 wb = *(const floatx4*)&wlds[(ky*3+kx)*QTAPSTRIDE + wofs + 4];
            #pragma unroll
            for (int j=0;j<4;j++){ wr[kx][j]=wa[j]; wr[kx][4+j]=wb[j]; }
        }
        const u16* rowp = in + ((size_t)(img*HH+hh)*WW)*288 + c0;
        #pragma unroll
        for (int cc=0; cc<6; cc++){
            int cx = x0 - 1 + cc;
            if ((unsigned)cx >= WW) continue;
            short8v v = *(const short8v*)(rowp + (size_t)cx*288);
            float vf[8];
            #pragma unroll
            for (int j=0;j<8;j++) vf[j] = b2f((u16)v[j]);
            #pragma unroll
            for (int dx=0; dx<4; dx++){
                int kx = cc - dx;
                if (kx < 0 || kx >= 3) continue;
                #pragma unroll
                for (int j=0;j<8;j++) acc[dx][j] = fmaf(wr[kx][j], vf[j], acc[dx][j]);
            }
        }
    }
    size_t pix0 = (size_t)(img*HH+hy)*WW + x0;
    int sec = c0/96, qc0 = c0 - sec*96;
    u16* outp = out + (size_t)sec*planeStride + qc0;
    #pragma unroll
    for (int dx=0; dx<4; dx++){
        short8v o;
        #pragma unroll
        for (int j=0;j<8;j++) o[j] = (short)f2b(acc[dx][j]);
        *(short8v*)(outp + (pix0+dx)*96) = o;
    }
}

// ---------- Gram partials per (img,head,slice), Q/K planes, vectorized staging ----------
__global__ __launch_bounds__(256) void gram_k(const u16* __restrict__ Qp,
    const u16* __restrict__ Kp, float* __restrict__ part)
{
    int bh = blockIdx.x;
    int slice = blockIdx.y;
    int img = bh >> 3, h = bh & 7;
    const u16* Qb = Qp + (size_t)img*HW*96 + h*12;
    const u16* Kb = Kp + (size_t)img*HW*96 + h*12;
    __shared__ float qs[64][12];
    __shared__ float ks[64][12];
    int t = threadIdx.x;
    float acc = 0.f;
    int c = (t<144) ? t/12 : (t<156 ? t-144 : t-156);
    int d = (t<144) ? t%12 : 0;
    for (int st=0; st<16; st++){
        int pix0 = slice*1024 + st*64;
        __syncthreads();
        for (int i=t; i<384; i+=256){
            int p = i/6, j = i%6;
            const u16* src = (j<3) ? (Qb + (size_t)(pix0+p)*96 + j*4)
                                   : (Kb + (size_t)(pix0+p)*96 + (j-3)*4);
            short4v v = *(const short4v*)src;
            float f0=b2f((u16)v.x), f1=b2f((u16)v.y), f2=b2f((u16)v.z), f3=b2f((u16)v.w);
            if (j<3){ int jj=j*4;     qs[p][jj]=f0; qs[p][jj+1]=f1; qs[p][jj+2]=f2; qs[p][jj+3]=f3; }
            else    { int jj=(j-3)*4; ks[p][jj]=f0; ks[p][jj+1]=f1; ks[p][jj+2]=f2; ks[p][jj+3]=f3; }
        }
        __syncthreads();
        if (t<144){        for (int p=0;p<64;p++) acc = fmaf(qs[p][c], ks[p][d], acc); }
        else if (t<156){   for (int p=0;p<64;p++) acc = fmaf(qs[p][c], qs[p][c], acc); }
        else if (t<168){   for (int p=0;p<64;p++) acc = fmaf(ks[p][c], ks[p][c], acc); }
    }
    if (t<168) part[((size_t)bh*16 + slice)*168 + t] = acc;
}

__global__ __launch_bounds__(256) void gram_combine_k(const float* __restrict__ part,
                                                      float* __restrict__ gram, int n)
{
    int i = blockIdx.x*256 + threadIdx.x;
    if (i >= n) return;
    int bh = i/168, t = i%168;
    float s = 0.f;
    for (int sl=0; sl<16; sl++) s += part[((size_t)bh*16+sl)*168 + t];
    gram[i] = s;
}

// ---------- attn 12x12: normalize, temperature, top-k mask, softmax ----------
__global__ __launch_bounds__(256) void attn_k(const float* __restrict__ gram,
    const float* __restrict__ temp, const float* __restrict__ dynk_p,
    const float* __restrict__ a1, const float* __restrict__ a2,
    const float* __restrict__ a3, const float* __restrict__ a4,
    float* __restrict__ attnW)
{
    int bh = blockIdx.x;
    int h = bh & 7;
    __shared__ float av[12][12];
    __shared__ float mv[12][12];
    __shared__ float nq[12], nk[12];
    int t = threadIdx.x;
    if (t < 12) nq[t] = fmaxf(sqrtf(gram[bh*168+144+t]), 1e-12f);
    else if (t < 24) nk[t-12] = fmaxf(sqrtf(gram[bh*168+156+(t-12)]), 1e-12f);
    __syncthreads();
    if (t < 144){
        int c=t/12, d=t%12;
        av[c][d] = gram[bh*168+t] / (nq[c]*nk[d]) * temp[h];
    }
    __syncthreads();
    float dk = *dynk_p;
    if (t < 144){
        int c=t/12, d=t%12; float v = av[c][d];
        int r = 0;
        #pragma unroll
        for (int j=0;j<12;j++){
            float o = av[c][j];
            r += (o > v) ? 1 : ((o == v && j < d) ? 1 : 0);
        }
        mv[c][d] = ((float)r < dk) ? v : -INFINITY;
    }
    __syncthreads();
    if (t < 12){
        float mx = -INFINITY;
        for (int d2=0; d2<12; d2++) mx = fmaxf(mx, mv[t][d2]);
        float e[12]; float s = 0.f;
        for (int d2=0; d2<12; d2++){ e[d2] = expf(mv[t][d2]-mx); s += e[d2]; }
        float sc = (a1[0]+a2[0]+a3[0]+a4[0]) / s;
        for (int d2=0; d2<12; d2++) attnW[(size_t)bh*144 + t*12 + d2] = e[d2]*sc;
    }
}

// ---------- attn apply -> P96 bf16 (V plane input); thread = (pixel, head) ----------
__global__ __launch_bounds__(256) void attn_apply_k(const u16* __restrict__ Vp,
    const float* __restrict__ attnW, u16* __restrict__ P)
{
    int gid = blockIdx.x*256 + threadIdx.x;
    int h = gid % 8; size_t pix = (size_t)(gid / 8);
    int img = (int)(pix >> 14);
    const u16* vp = Vp + pix*96 + h*12;
    float vf[12];
    #pragma unroll
    for (int j=0;j<3;j++){
        short4v v = *(const short4v*)(vp + j*4);
        vf[j*4+0]=b2f((u16)v.x); vf[j*4+1]=b2f((u16)v.y);
        vf[j*4+2]=b2f((u16)v.z); vf[j*4+3]=b2f((u16)v.w);
    }
    const float* awb = attnW + ((size_t)(img*8+h))*144;
    u16 o[12];
    #pragma unroll
    for (int cc=0; cc<12; cc++){
        const float4* ap = (const float4*)(awb + cc*12);
        float4 a0 = ap[0], a1 = ap[1], a2 = ap[2];
        float s = a0.x*vf[0] + a0.y*vf[1] + a0.z*vf[2] + a0.w*vf[3]
                + a1.x*vf[4] + a1.y*vf[5] + a1.z*vf[6] + a1.w*vf[7]
                + a2.x*vf[8] + a2.y*vf[9] + a2.z*vf[10]+ a2.w*vf[11];
        o[cc] = f2b(s);
    }
    u16* op = P + pix*96 + h*12;
    *(short4v*)(op)   = *(short4v*)&o[0];
    *(short4v*)(op+4) = *(short4v*)&o[4];
    *(short4v*)(op+8) = *(short4v*)&o[8];
}

// ---------- FFN multi-scale depthwise, row-sweep per scale, XCD-swizzled ----------
template<int KS>
__global__ __launch_bounds__(256) void ffn_dw_g(const u16* __restrict__ V0,
    const float* __restrict__ wsrc, const float* __restrict__ bsrc, int cbase,
    const float* __restrict__ bn2g, const float* __restrict__ bn2b,
    const float* __restrict__ bn2m, const float* __restrict__ bn2v,
    u16* __restrict__ U)
{
    constexpr int PAD = KS/2;
    __shared__ float wlds[KS*KS*64];
    __shared__ float bng[64], bnb[64], bnm[64], bnvr[64];
    int t = threadIdx.x;
    for (int i=t; i<KS*KS*64; i+=256){
        int tap = i >> 6, cc = i & 63;
        wlds[tap*64 + cc] = wsrc[cc*KS*KS + tap];
    }
    if (t < 64){
        bng[t] = bn2g[cbase+t]; bnb[t] = bn2b[cbase+t];
        bnm[t] = bn2m[cbase+t]; bnvr[t] = rsqrtf(bn2v[cbase+t]+1e-5f);
    }
    __syncthreads();
    int ci = t & 7, seg = t >> 3;
    int bid = blockIdx.x;
    int rowid = (bid & 7)*(gridDim.x >> 3) + (bid >> 3);
    int img = rowid >> 7, hy = rowid & 127;
    int c0r = ci*8;
    int c0 = cbase + c0r;
    int x0 = seg*4;
    float acc[4][8];
    {
        floatx4 b0 = *(const floatx4*)(bsrc + c0r);
        floatx4 b1 = *(const floatx4*)(bsrc + c0r + 4);
        #pragma unroll
        for (int dx=0;dx<4;dx++){
            #pragma unroll
            for (int j=0;j<4;j++){ acc[dx][j]=b0[j]; acc[dx][4+j]=b1[j]; }
        }
    }
    #pragma unroll
    for (int ky=0; ky<KS; ky++){
        int hh = hy + ky - PAD;
        if ((unsigned)hh >= HH) continue;
        float wr[KS][8];
        #pragma unroll
        for (int kx=0; kx<KS; kx++){
            floatx4 wa = *(const floatx4*)&wlds[(ky*KS+kx)*64 + c0r];
            floatx4 wb = *(const floatx4*)&wlds[(ky*KS+kx)*64 + c0r + 4];
            #pragma unroll
            for (int j=0;j<4;j++){ wr[kx][j]=wa[j]; wr[kx][4+j]=wb[j]; }
        }
        const u16* rowp = V0 + ((size_t)(img*HH+hh)*WW)*256 + c0;
        #pragma unroll
        for (int cc=0; cc<4+2*PAD; cc++){
            int cx = x0 - PAD + cc;
            if ((unsigned)cx >= WW) continue;
            short8v v = *(const short8v*)(rowp + (size_t)cx*256);
            float vf[8];
            #pragma unroll
            for (int j=0;j<8;j++) vf[j] = b2f((u16)v[j]);
            #pragma unroll
            for (int dx=0; dx<4; dx++){
                int kx = cc - dx;
                if (kx < 0 || kx >= KS) continue;
                #pragma unroll
                for (int j=0;j<8;j++) acc[dx][j] = fmaf(wr[kx][j], vf[j], acc[dx][j]);
            }
        }
    }
    size_t rbase = (size_t)(img*HH+hy)*WW;
    #pragma unroll
    for (int dx=0; dx<4; dx++){
        size_t pix = rbase + x0 + dx;
        short8v vc = *(const short8v*)(V0 + pix*256 + c0);
        short8v o;
        #pragma unroll
        for (int j=0;j<8;j++){
            float v0c = b2f((u16)vc[j]);
            float u1 = acc[dx][j] + v0c;
            float gl = gelu_exact(u1);
            float bn = (gl - bnm[c0r+j])*bnvr[c0r+j]*bng[c0r+j] + bnb[c0r+j];
            o[j] = (short)f2b(bn*v0c);
        }
        *(short8v*)(U + pix*256 + c0) = o;
    }
}

extern "C" void kernel_launch(void* const* d_in, const int* in_sizes, int n_in,
                              void* d_out, int out_size, void* d_ws, size_t ws_size,
                              hipStream_t stream)
{
    const float* x     = (const float*)d_in[0];
    const float* pos_w = (const float*)d_in[1];
    const float* pos_b = (const float*)d_in[2];
    const float* ln1g  = (const float*)d_in[3];
    const float* ln1b  = (const float*)d_in[4];
    const float* temp  = (const float*)d_in[5];
    const float* qkvw  = (const float*)d_in[6];
    const float* qkvdw = (const float*)d_in[7];
    const float* projw = (const float*)d_in[8];
    const float* gw1   = (const float*)d_in[9];
    const float* gb1   = (const float*)d_in[10];
    const float* gw2   = (const float*)d_in[11];
    const float* gb2   = (const float*)d_in[12];
    const float* a1    = (const float*)d_in[13];
    const float* a2    = (const float*)d_in[14];
    const float* a3    = (const float*)d_in[15];
    const float* a4    = (const float*)d_in[16];
    const float* ln2g  = (const float*)d_in[17];
    const float* ln2b  = (const float*)d_in[18];
    const float* fc1w  = (const float*)d_in[19];
    const float* bn1g  = (const float*)d_in[20];
    const float* bn1b  = (const float*)d_in[21];
    const float* bn1m  = (const float*)d_in[22];
    const float* bn1v  = (const float*)d_in[23];
    const float* bn2g  = (const float*)d_in[24];
    const float* bn2b  = (const float*)d_in[25];
    const float* bn2m  = (const float*)d_in[26];
    const float* bn2v  = (const float*)d_in[27];
    const float* fc2w  = (const float*)d_in[28];
    const float* bn3g  = (const float*)d_in[29];
    const float* bn3b  = (const float*)d_in[30];
    const float* bn3m  = (const float*)d_in[31];
    const float* bn3v  = (const float*)d_in[32];
    const float* dw0w  = (const float*)d_in[33];
    const float* dw0b  = (const float*)d_in[34];
    const float* dw1w  = (const float*)d_in[35];
    const float* dw1b  = (const float*)d_in[36];
    const float* dw2w  = (const float*)d_in[37];
    const float* dw2b  = (const float*)d_in[38];
    const float* dw3w  = (const float*)d_in[39];
    const float* dw3b  = (const float*)d_in[40];

    float* OUT = (float*)d_out;      // final fp32 output (written once by fc2)

    // ---- fixed small buffers + bf16 residual stream A ----
    char* p = (char*)d_ws;
    float* gpix  = (float*)p;                 p += (size_t)NPIX*4;
    float* dynk  = (float*)p;                 p += 256;
    float* gpart = (float*)p;                 p += 64*16*168*4;
    float* gram  = (float*)p;                 p += 64*168*4;
    float* attnW = (float*)p;                 p += 64*144*4;
    float* wposT = (float*)p;                 p += 1728*4;
    u16*   wbf   = (u16*)p;                   p += (size_t)WTOT*2;
    u16*   Abf   = (u16*)p;                   p += (size_t)NPIX*192*2;   // 50.3 MB
    size_t fixedB = (size_t)(p - (char*)d_ws);

    // ---- choose chunk size from ws_size: per-image = Y(192)+B1(288)+B2(288) bf16 ----
    size_t perImg = (size_t)HW*2*(192+288+288);   // 25,165,824
    int CBr = 2;
    if (ws_size >= fixedB + 8*perImg) CBr = 8;
    else if (ws_size >= fixedB + 4*perImg) CBr = 4;
    int NCHUNKr = BB/CBr;
    size_t CHWr = (size_t)CBr*HW;

    u16* Ybf = (u16*)p;                   p += CHWr*192*2;
    u16* B1  = (u16*)p;                   p += CHWr*288*2;
    u16* B2  = (u16*)p;
    u16* qkvwb = wbf;
    u16* projwb= wbf + WQ;
    u16* gw1b  = wbf + WQ + WP;
    u16* fc1b  = wbf + WQ + WP + WG;
    u16* fc2b  = wbf + WQ + WP + WG + WF1;
    u16* QKVbf = B1;     // qkv out (288 interleaved)
    u16* QKVdbf= B2;     // qkv_dw out: Q|K|V planes of CHWr*96 each
    u16* P96   = B1;     // attn out (QKV dead)
    u16* Zbf   = B2;     // LN2 out (QKVd dead)
    u16* V0bf  = B1;     // fc1 out (P96 dead)
    u16* Ubf   = B2;     // ffn out (Z dead)

    wprep_k<<<(WTOT+255)/256, 256, 0, stream>>>(qkvw, projw, gw1, fc1w, fc2w,
                                                pos_w, wbf, wposT);
    pos_conv_k<<<NPIX/8, 192, 0, stream>>>(x, wposT, pos_b, Abf);

    // gate phase: LN1 -> fused gate GEMM -> gpix
    for (int c=0; c<NCHUNKr; c++){
        const u16* Ab = Abf + (size_t)c*CHWr*192;
        ln_k<<<CHWr/4, 256, 0, stream>>>(Ab, ln1g, ln1b, Ybf);
        gate_gemm_k<<<CHWr/256, 256, 0, stream>>>(Ybf, gw1b, gb1, gw2, gb2,
                                                  gpix + (size_t)c*CHWr);
    }
    gate_reduce_k<<<1, 1024, 0, stream>>>(gpix, dynk);

    // main phase
    for (int c=0; c<NCHUNKr; c++){
        u16* Ab = Abf + (size_t)c*CHWr*192;
        if (NCHUNKr > 1)   // single-chunk mode: Ybf from gate phase is still valid
            ln_k<<<CHWr/4, 256, 0, stream>>>(Ab, ln1g, ln1b, Ybf);
        {
            dim3 g(CHWr/256, 5);
            gemm_bf16_k<GM_NONE,96><<<g, 256, 0, stream>>>(Ybf, 192, nullptr, 0,
                qkvwb, QKVbf, 288, nullptr, 0, nullptr,nullptr,nullptr,nullptr, 288);
        }
        size_t pstr = CHWr*96;
        qkv_dw_k<<<CHWr/4*36/256, 256, 0, stream>>>(QKVbf, qkvdw, QKVdbf, pstr);
        { dim3 g(CBr*8, 16); gram_k<<<g, 256, 0, stream>>>(QKVdbf, QKVdbf + pstr, gpart); }
        gram_combine_k<<<(CBr*8*168+255)/256, 256, 0, stream>>>(gpart, gram, CBr*8*168);
        attn_k<<<CBr*8, 256, 0, stream>>>(gram, temp, dynk, a1,a2,a3,a4, attnW);
        attn_apply_k<<<CHWr*8/256, 256, 0, stream>>>(QKVdbf + 2*pstr, attnW, P96);
        {   // proj + residual: A += [P96 | Y[:,96:]] @ projw^T  (bf16 in-place)
            dim3 g(CHWr/256, 3);
            gemm_bf16_k<GM_RES,192,true><<<g, 256, 0, stream>>>(P96, 96, Ybf+96, 192,
                projwb, Ab, 192, Ab, 192, nullptr,nullptr,nullptr,nullptr, 192);
        }
        ln_k<<<CHWr/4, 256, 0, stream>>>(Ab, ln2g, ln2b, Zbf);
        {
            dim3 g(CHWr/256, 4);
            gemm_bf16_k<GM_GELU_BN,192><<<g, 256, 0, stream>>>(Zbf, 192, nullptr, 0,
                fc1b, V0bf, 256, nullptr, 0, bn1g,bn1b,bn1m,bn1v, 256);
        }
        int rows = (int)(CHWr/WW);
        ffn_dw_g<1><<<rows, 256, 0, stream>>>(V0bf, dw0w, dw0b, 0,
            bn2g,bn2b,bn2m,bn2v, Ubf);
        ffn_dw_g<3><<<rows, 256, 0, stream>>>(V0bf, dw1w, dw1b, 64,
            bn2g,bn2b,bn2m,bn2v, Ubf);
        ffn_dw_g<5><<<rows, 256, 0, stream>>>(V0bf, dw2w, dw2b, 128,
            bn2g,bn2b,bn2m,bn2v, Ubf);
        ffn_dw_g<7><<<rows, 256, 0, stream>>>(V0bf, dw3w, dw3b, 192,
            bn2g,bn2b,bn2m,bn2v, Ubf);
        {   // fc2 + bn3 + residual -> fp32 OUT
            dim3 g(CHWr/256, 3);
            gemm_bf16_k<GM_BN_RES,256><<<g, 256, 0, stream>>>(Ubf, 256, nullptr, 0,
                fc2b, OUT + (size_t)c*CHWr*192, 192, Ab, 192, bn3g,bn3b,bn3m,bn3v, 192);
        }
    }
}

// Round 19
// 609.353 us; speedup vs baseline: 1.0762x; 1.0063x over previous
//
#include <hip/hip_runtime.h>
#include <hip/hip_bf16.h>
#include <math.h>

#define BB 8
#define HH 128
#define WW 128
#define HW (HH*WW)          // 16384
#define NPIX (BB*HW)        // 131072

typedef unsigned short u16;
typedef __attribute__((ext_vector_type(4))) float  floatx4;
typedef __attribute__((ext_vector_type(4))) short  short4v;
typedef __attribute__((ext_vector_type(8))) short  short8v;

static __device__ __forceinline__ float gelu_exact(float x){
    return 0.5f*x*(1.0f+erff(x*0.70710678118654752440f));
}
static __device__ __forceinline__ float b2f(u16 v){
    union { unsigned u; float f; } x; x.u = ((unsigned)v)<<16; return x.f;
}
static __device__ __forceinline__ u16 f2b(float f){
    __hip_bfloat16 h = __float2bfloat16(f);
    return *(u16*)&h;
}

// ---------- weight prep: fp32 -> bf16 GEMM weights + transposed pos weights ----------
#define WQ 27648
#define WP 36864
#define WG 18432
#define WF1 49152
#define WF2 49152
#define WTOT (WQ+WP+WG+WF1+WF2)   // 181248
__global__ __launch_bounds__(256) void wprep_k(const float* __restrict__ a,
    const float* __restrict__ b, const float* __restrict__ c,
    const float* __restrict__ d, const float* __restrict__ e,
    const float* __restrict__ posw, u16* __restrict__ o, float* __restrict__ wT)
{
    int i = blockIdx.x*256 + threadIdx.x;
    if (i < 1728){   // wT[tap][192]: wT[tap*192+c] = posw[c*9+tap]
        wT[i] = posw[(i%192)*9 + (i/192)];
    }
    if (i >= WTOT) return;
    float v;
    if (i < WQ) v = a[i];
    else if (i < WQ+WP) v = b[i-WQ];
    else if (i < WQ+WP+WG) v = c[i-WQ-WP];
    else if (i < WQ+WP+WG+WF1) v = d[i-WQ-WP-WG];
    else v = e[i-WQ-WP-WG-WF1];
    o[i] = f2b(v);
}

// ---------- pos depthwise 3x3 + bias + residual -> bf16 A; LDS halo, 2 px/thread ----------
__global__ __launch_bounds__(192) void pos_conv_k(const float* __restrict__ x,
    const float* __restrict__ wT, const float* __restrict__ bias, u16* __restrict__ out)
{
    __shared__ float4 lds[3][10][48];
    int bid = blockIdx.x;
    int sb = (bid & 7)*(gridDim.x >> 3) + (bid >> 3);   // XCD image-slice swizzle
    int t = threadIdx.x;
    int unit = sb;                       // over NPIX/8 column-octets
    int x0 = (unit & 15)*8;
    int hy = (unit >> 4) & 127;
    int b  = unit >> 11;

    const float4* x4 = (const float4*)x;
    float4 z4 = make_float4(0.f,0.f,0.f,0.f);
    for (int i = t; i < 1440; i += 192){
        int c4s = i % 48;
        int rc  = i / 48;
        int r   = rc / 10;
        int cp  = rc % 10;
        int hh  = hy + r - 1;
        int cx  = x0 + cp - 1;
        float4 v = z4;
        if ((unsigned)hh < HH && (unsigned)cx < WW)
            v = x4[((size_t)(b*HH+hh)*WW + cx)*48 + c4s];
        lds[r][cp][c4s] = v;
    }
    __syncthreads();

    int c4 = t % 48;
    int p0 = (t / 48)*2;
    int c0 = c4*4;
    floatx4 wv[9];
    #pragma unroll
    for (int tap=0; tap<9; tap++)
        wv[tap] = *(const floatx4*)&wT[tap*192 + c0];

    float4 xv[3][4];
    #pragma unroll
    for (int i=0;i<3;i++)
        #pragma unroll
        for (int k=0;k<4;k++)
            xv[i][k] = lds[i][p0+k][c4];

    float4 bias4 = *(const float4*)(bias + c0);
    float4 acc0 = bias4, acc1 = bias4;
    #pragma unroll
    for (int i=0;i<3;i++){
        #pragma unroll
        for (int k=0;k<3;k++){
            floatx4 w = wv[i*3+k];
            float4 a = xv[i][k];
            float4 bqq = xv[i][k+1];
            acc0.x = fmaf(w[0], a.x, acc0.x);
            acc0.y = fmaf(w[1], a.y, acc0.y);
            acc0.z = fmaf(w[2], a.z, acc0.z);
            acc0.w = fmaf(w[3], a.w, acc0.w);
            acc1.x = fmaf(w[0], bqq.x, acc1.x);
            acc1.y = fmaf(w[1], bqq.y, acc1.y);
            acc1.z = fmaf(w[2], bqq.z, acc1.z);
            acc1.w = fmaf(w[3], bqq.w, acc1.w);
        }
    }
    float4 xc0 = xv[1][1];
    float4 xc1 = xv[1][2];
    acc0.x += xc0.x; acc0.y += xc0.y; acc0.z += xc0.z; acc0.w += xc0.w;
    acc1.x += xc1.x; acc1.y += xc1.y; acc1.z += xc1.z; acc1.w += xc1.w;

    size_t pix0 = (size_t)(b*HH + hy)*WW + x0 + p0;
    short4v o0, o1;
    o0.x=(short)f2b(acc0.x); o0.y=(short)f2b(acc0.y);
    o0.z=(short)f2b(acc0.z); o0.w=(short)f2b(acc0.w);
    o1.x=(short)f2b(acc1.x); o1.y=(short)f2b(acc1.y);
    o1.z=(short)f2b(acc1.z); o1.w=(short)f2b(acc1.w);
    *(short4v*)(out + pix0*192 + c0) = o0;
    *(short4v*)(out + (pix0+1)*192 + c0) = o1;
}

// ---------- LayerNorm over C=192, bf16 in -> bf16 out, wave per pixel ----------
__global__ __launch_bounds__(256) void ln_k(const u16* __restrict__ in,
    const float* __restrict__ g, const float* __restrict__ bta, u16* __restrict__ out)
{
    int wid = threadIdx.x >> 6, lane = threadIdx.x & 63;
    size_t pix = (size_t)blockIdx.x*4 + wid;
    const u16* row = in + pix*192;
    float x0 = b2f(row[lane]), x1 = b2f(row[lane+64]), x2 = b2f(row[lane+128]);
    float s = x0+x1+x2;
    float q = x0*x0 + x1*x1 + x2*x2;
    #pragma unroll
    for (int off=32; off; off>>=1){ s += __shfl_xor(s,off,64); q += __shfl_xor(q,off,64); }
    float mean = s*(1.f/192.f);
    float var  = q*(1.f/192.f) - mean*mean;
    float inv  = rsqrtf(var + 1e-6f);
    u16* orow = out + pix*192;
    orow[lane]     = f2b((x0-mean)*inv*g[lane]     + bta[lane]);
    orow[lane+64]  = f2b((x1-mean)*inv*g[lane+64]  + bta[lane+64]);
    orow[lane+128] = f2b((x2-mean)*inv*g[lane+128] + bta[lane+128]);
}

// ---------- bf16 MFMA GEMM: W-in-LDS once, A streamed; templated N-tile ----------
#define GM_NONE 0
#define GM_RES 1
#define GM_GELU_BN 2
#define GM_BN_RES 3

template<int MODE, int K, int NT, bool SPLIT=false>
__global__ __launch_bounds__(256) void gemm_bf16_k(
    const u16* __restrict__ A, int lda,
    const u16* __restrict__ A2, int lda2,
    const u16* __restrict__ W,
    void* __restrict__ Cv, int ldc,
    const u16* __restrict__ R, int ldr,
    const float* __restrict__ bg, const float* __restrict__ bb,
    const float* __restrict__ bm_, const float* __restrict__ bv,
    int N)
{
    constexpr int LSTR = (K==96) ? 104 : ((K==192) ? 200 : 264);  // stride%32dw==4 -> 2-way
    constexpr int NF = NT/16;
    __shared__ u16 Ws[NT*LSTR];
    int t = threadIdx.x;
    int bn = blockIdx.y * NT;
    int bm = blockIdx.x * 256;
    {
        constexpr int K8 = K/8;
        for (int i = t; i < NT*K8; i += 256){
            int row = i / K8, j = (i % K8)*8;
            int n = bn + row;
            short8v v = {};
            if (n < N) v = *(const short8v*)(W + (size_t)n*K + j);
            *(short8v*)&Ws[row*LSTR + j] = v;
        }
    }
    __syncthreads();
    int wave = t >> 6, lane = t & 63;
    int wm = wave*64;
    int lr = lane & 15, lk = lane >> 4;
    const u16* arow  = A + (size_t)(bm + wm + lr)*lda + lk*8;
    const u16* arow2 = SPLIT ? (A2 + (size_t)(bm + wm + lr)*lda2 + lk*8) : nullptr;
    floatx4 acc[4][NF] = {};
    #pragma unroll
    for (int k0 = 0; k0 < K; k0 += 32){
        short8v afr[4];
        if (SPLIT && k0 >= 96){
            #pragma unroll
            for (int m=0;m<4;m++)
                afr[m] = *(const short8v*)(arow2 + (size_t)(m*16)*lda2 + (k0-96));
        } else {
            #pragma unroll
            for (int m=0;m<4;m++)
                afr[m] = *(const short8v*)(arow + (size_t)(m*16)*lda + k0);
        }
        #pragma unroll
        for (int n2=0;n2<NF;n2++){
            short8v bfr = *(const short8v*)&Ws[(n2*16+lr)*LSTR + k0 + lk*8];
            #pragma unroll
            for (int m=0;m<4;m++)
                acc[m][n2] = __builtin_amdgcn_mfma_f32_16x16x32_bf16(afr[m], bfr, acc[m][n2], 0,0,0);
        }
    }
    #pragma unroll
    for (int m=0;m<4;m++){
        #pragma unroll
        for (int n2=0;n2<NF;n2++){
            int gcol = bn + n2*16 + lr;
            if (gcol >= N) continue;
            #pragma unroll
            for (int rg=0; rg<4; rg++){
                int grow = bm + wm + m*16 + lk*4 + rg;
                float v = acc[m][n2][rg];
                if (MODE == GM_RES){
                    v += b2f(R[(size_t)grow*ldr + gcol]);
                    ((u16*)Cv)[(size_t)grow*ldc + gcol] = f2b(v);
                } else if (MODE == GM_BN_RES){
                    float bnv = (v - bm_[gcol])*rsqrtf(bv[gcol]+1e-5f)*bg[gcol] + bb[gcol];
                    ((float*)Cv)[(size_t)grow*ldc + gcol] = bnv + b2f(R[(size_t)grow*ldr + gcol]);
                } else if (MODE == GM_GELU_BN){
                    float gl = gelu_exact(v);
                    v = (gl - bm_[gcol])*rsqrtf(bv[gcol]+1e-5f)*bg[gcol] + bb[gcol];
                    ((u16*)Cv)[(size_t)grow*ldc + gcol] = f2b(v);
                } else {
                    ((u16*)Cv)[(size_t)grow*ldc + gcol] = f2b(v);
                }
            }
        }
    }
}

// ---------- fused gate GEMM: gpix = sigmoid( relu(Y@gw1^T + gb1) . w2 + b2 ) ----------
#define GSTR 200
__global__ __launch_bounds__(256) void gate_gemm_k(
    const u16* __restrict__ A,
    const u16* __restrict__ W,
    const float* __restrict__ gb1, const float* __restrict__ w2,
    const float* __restrict__ b2, float* __restrict__ gpix)
{
    __shared__ u16 Ws[96*GSTR];
    int t = threadIdx.x;
    int bm = blockIdx.x * 256;
    for (int i = t; i < 96*24; i += 256){
        int row = i/24, j = (i%24)*8;
        *(short8v*)&Ws[row*GSTR + j] = *(const short8v*)(W + (size_t)row*192 + j);
    }
    __syncthreads();
    int wave = t >> 6, lane = t & 63;
    int wm = wave*64;
    int lr = lane & 15, lk = lane >> 4;
    const u16* arow = A + (size_t)(bm + wm + lr)*192 + lk*8;
    floatx4 acc[4][6] = {};
    #pragma unroll
    for (int k0 = 0; k0 < 192; k0 += 32){
        short8v afr[4];
        #pragma unroll
        for (int m=0;m<4;m++)
            afr[m] = *(const short8v*)(arow + (size_t)(m*16)*192 + k0);
        #pragma unroll
        for (int n2=0;n2<6;n2++){
            short8v bfr = *(const short8v*)&Ws[(n2*16+lr)*GSTR + k0 + lk*8];
            #pragma unroll
            for (int m=0;m<4;m++)
                acc[m][n2] = __builtin_amdgcn_mfma_f32_16x16x32_bf16(afr[m], bfr, acc[m][n2], 0,0,0);
        }
    }
    float gbv[6], w2v[6];
    #pragma unroll
    for (int n2=0;n2<6;n2++){ int col = n2*16 + lr; gbv[n2] = gb1[col]; w2v[n2] = w2[col]; }
    float b2s = b2[0];
    #pragma unroll
    for (int m=0;m<4;m++){
        #pragma unroll
        for (int rg=0;rg<4;rg++){
            float part = 0.f;
            #pragma unroll
            for (int n2=0;n2<6;n2++){
                float v = fmaxf(acc[m][n2][rg] + gbv[n2], 0.f);
                part = fmaf(v, w2v[n2], part);
            }
            #pragma unroll
            for (int off=1; off<16; off<<=1) part += __shfl_xor(part, off, 64);
            if (lr == 0){
                int row = bm + wm + m*16 + lk*4 + rg;
                gpix[row] = 1.f/(1.f+expf(-(part + b2s)));
            }
        }
    }
}

// ---------- deterministic mean of gpix -> dyn_k ----------
__global__ __launch_bounds__(1024) void gate_reduce_k(const float* __restrict__ gpix,
                                                      float* __restrict__ dynk)
{
    __shared__ float sm[16];
    float s = 0.f;
    for (int i=threadIdx.x; i<NPIX; i+=1024) s += gpix[i];
    #pragma unroll
    for (int off=32; off; off>>=1) s += __shfl_xor(s,off,64);
    int wid = threadIdx.x>>6, lane = threadIdx.x&63;
    if (lane==0) sm[wid]=s;
    __syncthreads();
    if (threadIdx.x==0){
        float tot=0.f; for (int i=0;i<16;i++) tot+=sm[i];
        *dynk = floorf(12.0f * (tot/(float)NPIX));
    }
}

// ---------- qkv depthwise 3x3 (288 ch), 4-col sweep, LDS weights, XCD-swizzled ----------
#define QPOS(c8) ((c8)*8 + ((c8)>>2)*4)
#define QTAPSTRIDE 324
__global__ __launch_bounds__(256) void qkv_dw_k(const u16* __restrict__ in,
    const float* __restrict__ w, u16* __restrict__ out, size_t planeStride)
{
    __shared__ float wlds[9*QTAPSTRIDE];
    int t = threadIdx.x;
    for (int i=t; i<2592; i+=256){
        int tap = i/288, cc = i%288;
        wlds[tap*QTAPSTRIDE + QPOS(cc>>3) + (cc&7)] = w[cc*9+tap];
    }
    __syncthreads();
    int bid = blockIdx.x;
    int sb = (bid & 7)*(gridDim.x >> 3) + (bid >> 3);
    int idx = sb*256 + t;
    int c8 = idx % 36; int pq = idx / 36;
    int xg = pq & 31; int hy = (pq >> 5) & 127; int img = pq >> 12;
    int x0 = xg*4;
    int c0 = c8*8;
    int wofs = QPOS(c8);
    float acc[4][8] = {{0.f}};
    #pragma unroll
    for (int ky=0; ky<3; ky++){
        int hh = hy + ky - 1; if ((unsigned)hh >= HH) continue;
        float wr[3][8];
        #pragma unroll
        for (int kx=0; kx<3; kx++){
            floatx4 wa = *(const floatx4*)&wlds[(ky*3+kx)*QTAPSTRIDE + wofs];
            floatx4 wb = *(const floatx4*)&wlds[(ky*3+kx)*QTAPSTRIDE + wofs + 4];
            #pragma unroll
            for (int j=0;j<4;j++){ wr[kx][j]=wa[j]; wr[kx][4+j]=wb[j]; }
        }
        const u16* rowp = in + ((size_t)(img*HH+hh)*WW)*288 + c0;
        #pragma unroll
        for (int cc=0; cc<6; cc++){
            int cx = x0 - 1 + cc;
            if ((unsigned)cx >= WW) continue;
            short8v v = *(const short8v*)(rowp + (size_t)cx*288);
            float vf[8];
            #pragma unroll
            for (int j=0;j<8;j++) vf[j] = b2f((u16)v[j]);
            #pragma unroll
            for (int dx=0; dx<4; dx++){
                int kx = cc - dx;
                if (kx < 0 || kx >= 3) continue;
                #pragma unroll
                for (int j=0;j<8;j++) acc[dx][j] = fmaf(wr[kx][j], vf[j], acc[dx][j]);
            }
        }
    }
    size_t pix0 = (size_t)(img*HH+hy)*WW + x0;
    int sec = c0/96, qc0 = c0 - sec*96;
    u16* outp = out + (size_t)sec*planeStride + qc0;
    #pragma unroll
    for (int dx=0; dx<4; dx++){
        short8v o;
        #pragma unroll
        for (int j=0;j<8;j++) o[j] = (short)f2b(acc[dx][j]);
        *(short8v*)(outp + (pix0+dx)*96) = o;
    }
}

// ---------- Gram partials per (img,head,slice), Q/K planes, vectorized staging ----------
__global__ __launch_bounds__(256) void gram_k(const u16* __restrict__ Qp,
    const u16* __restrict__ Kp, float* __restrict__ part)
{
    int bh = blockIdx.x;
    int slice = blockIdx.y;
    int img = bh >> 3, h = bh & 7;
    const u16* Qb = Qp + (size_t)img*HW*96 + h*12;
    const u16* Kb = Kp + (size_t)img*HW*96 + h*12;
    __shared__ float qs[64][12];
    __shared__ float ks[64][12];
    int t = threadIdx.x;
    float acc = 0.f;
    int c = (t<144) ? t/12 : (t<156 ? t-144 : t-156);
    int d = (t<144) ? t%12 : 0;
    for (int st=0; st<16; st++){
        int pix0 = slice*1024 + st*64;
        __syncthreads();
        for (int i=t; i<384; i+=256){
            int p = i/6, j = i%6;
            const u16* src = (j<3) ? (Qb + (size_t)(pix0+p)*96 + j*4)
                                   : (Kb + (size_t)(pix0+p)*96 + (j-3)*4);
            short4v v = *(const short4v*)src;
            float f0=b2f((u16)v.x), f1=b2f((u16)v.y), f2=b2f((u16)v.z), f3=b2f((u16)v.w);
            if (j<3){ int jj=j*4;     qs[p][jj]=f0; qs[p][jj+1]=f1; qs[p][jj+2]=f2; qs[p][jj+3]=f3; }
            else    { int jj=(j-3)*4; ks[p][jj]=f0; ks[p][jj+1]=f1; ks[p][jj+2]=f2; ks[p][jj+3]=f3; }
        }
        __syncthreads();
        if (t<144){        for (int p=0;p<64;p++) acc = fmaf(qs[p][c], ks[p][d], acc); }
        else if (t<156){   for (int p=0;p<64;p++) acc = fmaf(qs[p][c], qs[p][c], acc); }
        else if (t<168){   for (int p=0;p<64;p++) acc = fmaf(ks[p][c], ks[p][c], acc); }
    }
    if (t<168) part[((size_t)bh*16 + slice)*168 + t] = acc;
}

__global__ __launch_bounds__(256) void gram_combine_k(const float* __restrict__ part,
                                                      float* __restrict__ gram, int n)
{
    int i = blockIdx.x*256 + threadIdx.x;
    if (i >= n) return;
    int bh = i/168, t = i%168;
    float s = 0.f;
    for (int sl=0; sl<16; sl++) s += part[((size_t)bh*16+sl)*168 + t];
    gram[i] = s;
}

// ---------- attn 12x12: normalize, temperature, top-k mask, softmax ----------
__global__ __launch_bounds__(256) void attn_k(const float* __restrict__ gram,
    const float* __restrict__ temp, const float* __restrict__ dynk_p,
    const float* __restrict__ a1, const float* __restrict__ a2,
    const float* __restrict__ a3, const float* __restrict__ a4,
    float* __restrict__ attnW)
{
    int bh = blockIdx.x;
    int h = bh & 7;
    __shared__ float av[12][12];
    __shared__ float mv[12][12];
    __shared__ float nq[12], nk[12];
    int t = threadIdx.x;
    if (t < 12) nq[t] = fmaxf(sqrtf(gram[bh*168+144+t]), 1e-12f);
    else if (t < 24) nk[t-12] = fmaxf(sqrtf(gram[bh*168+156+(t-12)]), 1e-12f);
    __syncthreads();
    if (t < 144){
        int c=t/12, d=t%12;
        av[c][d] = gram[bh*168+t] / (nq[c]*nk[d]) * temp[h];
    }
    __syncthreads();
    float dk = *dynk_p;
    if (t < 144){
        int c=t/12, d=t%12; float v = av[c][d];
        int r = 0;
        #pragma unroll
        for (int j=0;j<12;j++){
            float o = av[c][j];
            r += (o > v) ? 1 : ((o == v && j < d) ? 1 : 0);
        }
        mv[c][d] = ((float)r < dk) ? v : -INFINITY;
    }
    __syncthreads();
    if (t < 12){
        float mx = -INFINITY;
        for (int d2=0; d2<12; d2++) mx = fmaxf(mx, mv[t][d2]);
        float e[12]; float s = 0.f;
        for (int d2=0; d2<12; d2++){ e[d2] = expf(mv[t][d2]-mx); s += e[d2]; }
        float sc = (a1[0]+a2[0]+a3[0]+a4[0]) / s;
        for (int d2=0; d2<12; d2++) attnW[(size_t)bh*144 + t*12 + d2] = e[d2]*sc;
    }
}

// ---------- attn apply -> P96 bf16 (V plane input); thread = (pixel, head) ----------
__global__ __launch_bounds__(256) void attn_apply_k(const u16* __restrict__ Vp,
    const float* __restrict__ attnW, u16* __restrict__ P)
{
    int gid = blockIdx.x*256 + threadIdx.x;
    int h = gid % 8; size_t pix = (size_t)(gid / 8);
    int img = (int)(pix >> 14);
    const u16* vp = Vp + pix*96 + h*12;
    float vf[12];
    #pragma unroll
    for (int j=0;j<3;j++){
        short4v v = *(const short4v*)(vp + j*4);
        vf[j*4+0]=b2f((u16)v.x); vf[j*4+1]=b2f((u16)v.y);
        vf[j*4+2]=b2f((u16)v.z); vf[j*4+3]=b2f((u16)v.w);
    }
    const float* awb = attnW + ((size_t)(img*8+h))*144;
    u16 o[12];
    #pragma unroll
    for (int cc=0; cc<12; cc++){
        const float4* ap = (const float4*)(awb + cc*12);
        float4 a0 = ap[0], a1 = ap[1], a2 = ap[2];
        float s = a0.x*vf[0] + a0.y*vf[1] + a0.z*vf[2] + a0.w*vf[3]
                + a1.x*vf[4] + a1.y*vf[5] + a1.z*vf[6] + a1.w*vf[7]
                + a2.x*vf[8] + a2.y*vf[9] + a2.z*vf[10]+ a2.w*vf[11];
        o[cc] = f2b(s);
    }
    u16* op = P + pix*96 + h*12;
    *(short4v*)(op)   = *(short4v*)&o[0];
    *(short4v*)(op+4) = *(short4v*)&o[4];
    *(short4v*)(op+8) = *(short4v*)&o[8];
}

// ---------- FFN multi-scale depthwise, row-sweep; single kernel, blockIdx.y = group ----------
template<int KS>
__device__ __forceinline__ void ffn_body(const u16* __restrict__ V0,
    const float* __restrict__ wsrc, const float* __restrict__ bsrc, int cbase,
    const float* __restrict__ bn2g, const float* __restrict__ bn2b,
    const float* __restrict__ bn2m, const float* __restrict__ bn2v,
    u16* __restrict__ U, float* wlds, float* bng, float* bnb, float* bnm, float* bnvr,
    int gridx)
{
    constexpr int PAD = KS/2;
    int t = threadIdx.x;
    for (int i=t; i<KS*KS*64; i+=256){
        int tap = i >> 6, cc = i & 63;
        wlds[tap*64 + cc] = wsrc[cc*KS*KS + tap];
    }
    if (t < 64){
        bng[t] = bn2g[cbase+t]; bnb[t] = bn2b[cbase+t];
        bnm[t] = bn2m[cbase+t]; bnvr[t] = rsqrtf(bn2v[cbase+t]+1e-5f);
    }
    __syncthreads();
    int ci = t & 7, seg = t >> 3;
    int bid = blockIdx.x;
    int rowid = (bid & 7)*(gridx >> 3) + (bid >> 3);
    int img = rowid >> 7, hy = rowid & 127;
    int c0r = ci*8;
    int c0 = cbase + c0r;
    int x0 = seg*4;
    float acc[4][8];
    {
        floatx4 b0 = *(const floatx4*)(bsrc + c0r);
        floatx4 b1 = *(const floatx4*)(bsrc + c0r + 4);
        #pragma unroll
        for (int dx=0;dx<4;dx++){
            #pragma unroll
            for (int j=0;j<4;j++){ acc[dx][j]=b0[j]; acc[dx][4+j]=b1[j]; }
        }
    }
    #pragma unroll
    for (int ky=0; ky<KS; ky++){
        int hh = hy + ky - PAD;
        if ((unsigned)hh >= HH) continue;
        float wr[KS][8];
        #pragma unroll
        for (int kx=0; kx<KS; kx++){
            floatx4 wa = *(const floatx4*)&wlds[(ky*KS+kx)*64 + c0r];
            floatx4 wb = *(const floatx4*)&wlds[(ky*KS+kx)*64 + c0r + 4];
            #pragma unroll
            for (int j=0;j<4;j++){ wr[kx][j]=wa[j]; wr[kx][4+j]=wb[j]; }
        }
        const u16* rowp = V0 + ((size_t)(img*HH+hh)*WW)*256 + c0;
        #pragma unroll
        for (int cc=0; cc<4+2*PAD; cc++){
            int cx = x0 - PAD + cc;
            if ((unsigned)cx >= WW) continue;
            short8v v = *(const short8v*)(rowp + (size_t)cx*256);
            float vf[8];
            #pragma unroll
            for (int j=0;j<8;j++) vf[j] = b2f((u16)v[j]);
            #pragma unroll
            for (int dx=0; dx<4; dx++){
                int kx = cc - dx;
                if (kx < 0 || kx >= KS) continue;
                #pragma unroll
                for (int j=0;j<8;j++) acc[dx][j] = fmaf(wr[kx][j], vf[j], acc[dx][j]);
            }
        }
    }
    size_t rbase = (size_t)(img*HH+hy)*WW;
    #pragma unroll
    for (int dx=0; dx<4; dx++){
        size_t pix = rbase + x0 + dx;
        short8v vc = *(const short8v*)(V0 + pix*256 + c0);
        short8v o;
        #pragma unroll
        for (int j=0;j<8;j++){
            float v0c = b2f((u16)vc[j]);
            float u1 = acc[dx][j] + v0c;
            float gl = gelu_exact(u1);
            float bn = (gl - bnm[c0r+j])*bnvr[c0r+j]*bng[c0r+j] + bnb[c0r+j];
            o[j] = (short)f2b(bn*v0c);
        }
        *(short8v*)(U + pix*256 + c0) = o;
    }
}

__global__ __launch_bounds__(256) void ffn_dw_all_k(const u16* __restrict__ V0,
    const float* __restrict__ w0, const float* __restrict__ bb0,
    const float* __restrict__ w1, const float* __restrict__ bb1,
    const float* __restrict__ w2, const float* __restrict__ bb2,
    const float* __restrict__ w3, const float* __restrict__ bb3,
    const float* __restrict__ bn2g, const float* __restrict__ bn2b,
    const float* __restrict__ bn2m, const float* __restrict__ bn2v,
    u16* __restrict__ U)
{
    __shared__ float wlds[49*64];
    __shared__ float bng[64], bnb[64], bnm[64], bnvr[64];
    int gx = gridDim.x;
    switch(blockIdx.y){
        case 0: ffn_body<1>(V0, w0, bb0, 0,   bn2g,bn2b,bn2m,bn2v, U, wlds,bng,bnb,bnm,bnvr, gx); break;
        case 1: ffn_body<3>(V0, w1, bb1, 64,  bn2g,bn2b,bn2m,bn2v, U, wlds,bng,bnb,bnm,bnvr, gx); break;
        case 2: ffn_body<5>(V0, w2, bb2, 128, bn2g,bn2b,bn2m,bn2v, U, wlds,bng,bnb,bnm,bnvr, gx); break;
        default: ffn_body<7>(V0, w3, bb3, 192, bn2g,bn2b,bn2m,bn2v, U, wlds,bng,bnb,bnm,bnvr, gx); break;
    }
}

extern "C" void kernel_launch(void* const* d_in, const int* in_sizes, int n_in,
                              void* d_out, int out_size, void* d_ws, size_t ws_size,
                              hipStream_t stream)
{
    const float* x     = (const float*)d_in[0];
    const float* pos_w = (const float*)d_in[1];
    const float* pos_b = (const float*)d_in[2];
    const float* ln1g  = (const float*)d_in[3];
    const float* ln1b  = (const float*)d_in[4];
    const float* temp  = (const float*)d_in[5];
    const float* qkvw  = (const float*)d_in[6];
    const float* qkvdw = (const float*)d_in[7];
    const float* projw = (const float*)d_in[8];
    const float* gw1   = (const float*)d_in[9];
    const float* gb1   = (const float*)d_in[10];
    const float* gw2   = (const float*)d_in[11];
    const float* gb2   = (const float*)d_in[12];
    const float* a1    = (const float*)d_in[13];
    const float* a2    = (const float*)d_in[14];
    const float* a3    = (const float*)d_in[15];
    const float* a4    = (const float*)d_in[16];
    const float* ln2g  = (const float*)d_in[17];
    const float* ln2b  = (const float*)d_in[18];
    const float* fc1w  = (const float*)d_in[19];
    const float* bn1g  = (const float*)d_in[20];
    const float* bn1b  = (const float*)d_in[21];
    const float* bn1m  = (const float*)d_in[22];
    const float* bn1v  = (const float*)d_in[23];
    const float* bn2g  = (const float*)d_in[24];
    const float* bn2b  = (const float*)d_in[25];
    const float* bn2m  = (const float*)d_in[26];
    const float* bn2v  = (const float*)d_in[27];
    const float* fc2w  = (const float*)d_in[28];
    const float* bn3g  = (const float*)d_in[29];
    const float* bn3b  = (const float*)d_in[30];
    const float* bn3m  = (const float*)d_in[31];
    const float* bn3v  = (const float*)d_in[32];
    const float* dw0w  = (const float*)d_in[33];
    const float* dw0b  = (const float*)d_in[34];
    const float* dw1w  = (const float*)d_in[35];
    const float* dw1b  = (const float*)d_in[36];
    const float* dw2w  = (const float*)d_in[37];
    const float* dw2b  = (const float*)d_in[38];
    const float* dw3w  = (const float*)d_in[39];
    const float* dw3b  = (const float*)d_in[40];

    float* OUT = (float*)d_out;      // final fp32 output (written once by fc2)

    // ---- fixed small buffers + bf16 residual stream A ----
    char* p = (char*)d_ws;
    float* gpix  = (float*)p;                 p += (size_t)NPIX*4;
    float* dynk  = (float*)p;                 p += 256;
    float* gpart = (float*)p;                 p += 64*16*168*4;
    float* gram  = (float*)p;                 p += 64*168*4;
    float* attnW = (float*)p;                 p += 64*144*4;
    float* wposT = (float*)p;                 p += 1728*4;
    u16*   wbf   = (u16*)p;                   p += (size_t)WTOT*2;
    u16*   Abf   = (u16*)p;                   p += (size_t)NPIX*192*2;   // 50.3 MB
    size_t fixedB = (size_t)(p - (char*)d_ws);

    // ---- choose chunk size from ws_size: per-image = Y(192)+B1(288)+B2(288) bf16 ----
    size_t perImg = (size_t)HW*2*(192+288+288);   // 25,165,824
    int CBr = 2;
    if (ws_size >= fixedB + 8*perImg) CBr = 8;
    else if (ws_size >= fixedB + 4*perImg) CBr = 4;
    int NCHUNKr = BB/CBr;
    size_t CHWr = (size_t)CBr*HW;

    u16* Ybf = (u16*)p;                   p += CHWr*192*2;
    u16* B1  = (u16*)p;                   p += CHWr*288*2;
    u16* B2  = (u16*)p;
    u16* qkvwb = wbf;
    u16* projwb= wbf + WQ;
    u16* gw1b  = wbf + WQ + WP;
    u16* fc1b  = wbf + WQ + WP + WG;
    u16* fc2b  = wbf + WQ + WP + WG + WF1;
    u16* QKVbf = B1;     // qkv out (288 interleaved)
    u16* QKVdbf= B2;     // qkv_dw out: Q|K|V planes of CHWr*96 each
    u16* P96   = B1;     // attn out (QKV dead)
    u16* Zbf   = B2;     // LN2 out (QKVd dead)
    u16* V0bf  = B1;     // fc1 out (P96 dead)
    u16* Ubf   = B2;     // ffn out (Z dead)

    wprep_k<<<(WTOT+255)/256, 256, 0, stream>>>(qkvw, projw, gw1, fc1w, fc2w,
                                                pos_w, wbf, wposT);
    pos_conv_k<<<NPIX/8, 192, 0, stream>>>(x, wposT, pos_b, Abf);

    // gate phase: LN1 -> fused gate GEMM -> gpix
    for (int c=0; c<NCHUNKr; c++){
        const u16* Ab = Abf + (size_t)c*CHWr*192;
        ln_k<<<CHWr/4, 256, 0, stream>>>(Ab, ln1g, ln1b, Ybf);
        gate_gemm_k<<<CHWr/256, 256, 0, stream>>>(Ybf, gw1b, gb1, gw2, gb2,
                                                  gpix + (size_t)c*CHWr);
    }
    gate_reduce_k<<<1, 1024, 0, stream>>>(gpix, dynk);

    // main phase
    for (int c=0; c<NCHUNKr; c++){
        u16* Ab = Abf + (size_t)c*CHWr*192;
        if (NCHUNKr > 1)   // single-chunk mode: Ybf from gate phase is still valid
            ln_k<<<CHWr/4, 256, 0, stream>>>(Ab, ln1g, ln1b, Ybf);
        {   // qkv 1x1: N=288 = 3 x 96-tiles
            dim3 g(CHWr/256, 3);
            gemm_bf16_k<GM_NONE,96,96><<<g, 256, 0, stream>>>(Ybf, 192, nullptr, 0,
                qkvwb, QKVbf, 288, nullptr, 0, nullptr,nullptr,nullptr,nullptr, 288);
        }
        size_t pstr = CHWr*96;
        qkv_dw_k<<<CHWr/4*36/256, 256, 0, stream>>>(QKVbf, qkvdw, QKVdbf, pstr);
        { dim3 g(CBr*8, 16); gram_k<<<g, 256, 0, stream>>>(QKVdbf, QKVdbf + pstr, gpart); }
        gram_combine_k<<<(CBr*8*168+255)/256, 256, 0, stream>>>(gpart, gram, CBr*8*168);
        attn_k<<<CBr*8, 256, 0, stream>>>(gram, temp, dynk, a1,a2,a3,a4, attnW);
        attn_apply_k<<<CHWr*8/256, 256, 0, stream>>>(QKVdbf + 2*pstr, attnW, P96);
        {   // proj + residual: N=192 = 2 x 96-tiles
            dim3 g(CHWr/256, 2);
            gemm_bf16_k<GM_RES,192,96,true><<<g, 256, 0, stream>>>(P96, 96, Ybf+96, 192,
                projwb, Ab, 192, Ab, 192, nullptr,nullptr,nullptr,nullptr, 192);
        }
        ln_k<<<CHWr/4, 256, 0, stream>>>(Ab, ln2g, ln2b, Zbf);
        {   // fc1: N=256 = 4 x 64-tiles
            dim3 g(CHWr/256, 4);
            gemm_bf16_k<GM_GELU_BN,192,64><<<g, 256, 0, stream>>>(Zbf, 192, nullptr, 0,
                fc1b, V0bf, 256, nullptr, 0, bn1g,bn1b,bn1m,bn1v, 256);
        }
        {   // multi-scale depthwise, all 4 groups in one launch
            int rows = (int)(CHWr/WW);
            dim3 g(rows, 4);
            ffn_dw_all_k<<<g, 256, 0, stream>>>(V0bf, dw0w,dw0b,dw1w,dw1b,dw2w,dw2b,
                                                dw3w,dw3b, bn2g,bn2b,bn2m,bn2v, Ubf);
        }
        {   // fc2 + bn3 + residual -> fp32 OUT: N=192 = 2 x 96-tiles
            dim3 g(CHWr/256, 2);
            gemm_bf16_k<GM_BN_RES,256,96><<<g, 256, 0, stream>>>(Ubf, 256, nullptr, 0,
                fc2b, OUT + (size_t)c*CHWr*192, 192, Ab, 192, bn3g,bn3b,bn3m,bn3v, 192);
        }
    }
}

// Round 20
// 589.926 us; speedup vs baseline: 1.1116x; 1.0329x over previous
//
#include <hip/hip_runtime.h>
#include <hip/hip_bf16.h>
#include <math.h>

#define BB 8
#define HH 128
#define WW 128
#define HW (HH*WW)          // 16384
#define NPIX (BB*HW)        // 131072

typedef unsigned short u16;
typedef __attribute__((ext_vector_type(4))) float  floatx4;
typedef __attribute__((ext_vector_type(4))) short  short4v;
typedef __attribute__((ext_vector_type(8))) short  short8v;

static __device__ __forceinline__ float gelu_fast(float x){
    // tanh-form gelu; |err| <= ~2e-3 vs exact; saturation-safe
    float u = 0.7978845608028654f*(x + 0.044715f*x*x*x);
    float e = __expf(2.f*u);
    float th = 1.f - 2.f/(e + 1.f);
    return 0.5f*x*(1.f + th);
}
static __device__ __forceinline__ float b2f(u16 v){
    union { unsigned u; float f; } x; x.u = ((unsigned)v)<<16; return x.f;
}
static __device__ __forceinline__ u16 f2b(float f){
    __hip_bfloat16 h = __float2bfloat16(f);
    return *(u16*)&h;
}

// ---------- weight prep: fp32 -> bf16 GEMM weights + transposed pos weights ----------
#define WQ 27648
#define WP 36864
#define WG 18432
#define WF1 49152
#define WF2 49152
#define WTOT (WQ+WP+WG+WF1+WF2)   // 181248
__global__ __launch_bounds__(256) void wprep_k(const float* __restrict__ a,
    const float* __restrict__ b, const float* __restrict__ c,
    const float* __restrict__ d, const float* __restrict__ e,
    const float* __restrict__ posw, u16* __restrict__ o, float* __restrict__ wT)
{
    int i = blockIdx.x*256 + threadIdx.x;
    if (i < 1728){   // wT[tap][192]: wT[tap*192+c] = posw[c*9+tap]
        wT[i] = posw[(i%192)*9 + (i/192)];
    }
    if (i >= WTOT) return;
    float v;
    if (i < WQ) v = a[i];
    else if (i < WQ+WP) v = b[i-WQ];
    else if (i < WQ+WP+WG) v = c[i-WQ-WP];
    else if (i < WQ+WP+WG+WF1) v = d[i-WQ-WP-WG];
    else v = e[i-WQ-WP-WG-WF1];
    o[i] = f2b(v);
}

// ---------- pos depthwise 3x3 + bias + residual -> bf16 A; LDS halo, 2 px/thread ----------
__global__ __launch_bounds__(192) void pos_conv_k(const float* __restrict__ x,
    const float* __restrict__ wT, const float* __restrict__ bias, u16* __restrict__ out)
{
    __shared__ float4 lds[3][10][48];
    int bid = blockIdx.x;
    int sb = (bid & 7)*(gridDim.x >> 3) + (bid >> 3);   // XCD image-slice swizzle
    int t = threadIdx.x;
    int unit = sb;                       // over NPIX/8 column-octets
    int x0 = (unit & 15)*8;
    int hy = (unit >> 4) & 127;
    int b  = unit >> 11;

    const float4* x4 = (const float4*)x;
    float4 z4 = make_float4(0.f,0.f,0.f,0.f);
    for (int i = t; i < 1440; i += 192){
        int c4s = i % 48;
        int rc  = i / 48;
        int r   = rc / 10;
        int cp  = rc % 10;
        int hh  = hy + r - 1;
        int cx  = x0 + cp - 1;
        float4 v = z4;
        if ((unsigned)hh < HH && (unsigned)cx < WW)
            v = x4[((size_t)(b*HH+hh)*WW + cx)*48 + c4s];
        lds[r][cp][c4s] = v;
    }
    __syncthreads();

    int c4 = t % 48;
    int p0 = (t / 48)*2;
    int c0 = c4*4;
    floatx4 wv[9];
    #pragma unroll
    for (int tap=0; tap<9; tap++)
        wv[tap] = *(const floatx4*)&wT[tap*192 + c0];

    float4 xv[3][4];
    #pragma unroll
    for (int i=0;i<3;i++)
        #pragma unroll
        for (int k=0;k<4;k++)
            xv[i][k] = lds[i][p0+k][c4];

    float4 bias4 = *(const float4*)(bias + c0);
    float4 acc0 = bias4, acc1 = bias4;
    #pragma unroll
    for (int i=0;i<3;i++){
        #pragma unroll
        for (int k=0;k<3;k++){
            floatx4 w = wv[i*3+k];
            float4 a = xv[i][k];
            float4 bqq = xv[i][k+1];
            acc0.x = fmaf(w[0], a.x, acc0.x);
            acc0.y = fmaf(w[1], a.y, acc0.y);
            acc0.z = fmaf(w[2], a.z, acc0.z);
            acc0.w = fmaf(w[3], a.w, acc0.w);
            acc1.x = fmaf(w[0], bqq.x, acc1.x);
            acc1.y = fmaf(w[1], bqq.y, acc1.y);
            acc1.z = fmaf(w[2], bqq.z, acc1.z);
            acc1.w = fmaf(w[3], bqq.w, acc1.w);
        }
    }
    float4 xc0 = xv[1][1];
    float4 xc1 = xv[1][2];
    acc0.x += xc0.x; acc0.y += xc0.y; acc0.z += xc0.z; acc0.w += xc0.w;
    acc1.x += xc1.x; acc1.y += xc1.y; acc1.z += xc1.z; acc1.w += xc1.w;

    size_t pix0 = (size_t)(b*HH + hy)*WW + x0 + p0;
    short4v o0, o1;
    o0.x=(short)f2b(acc0.x); o0.y=(short)f2b(acc0.y);
    o0.z=(short)f2b(acc0.z); o0.w=(short)f2b(acc0.w);
    o1.x=(short)f2b(acc1.x); o1.y=(short)f2b(acc1.y);
    o1.z=(short)f2b(acc1.z); o1.w=(short)f2b(acc1.w);
    *(short4v*)(out + pix0*192 + c0) = o0;
    *(short4v*)(out + (pix0+1)*192 + c0) = o1;
}

// ---------- LayerNorm over C=192, bf16 in -> bf16 out, wave per pixel ----------
__global__ __launch_bounds__(256) void ln_k(const u16* __restrict__ in,
    const float* __restrict__ g, const float* __restrict__ bta, u16* __restrict__ out)
{
    int wid = threadIdx.x >> 6, lane = threadIdx.x & 63;
    size_t pix = (size_t)blockIdx.x*4 + wid;
    const u16* row = in + pix*192;
    float x0 = b2f(row[lane]), x1 = b2f(row[lane+64]), x2 = b2f(row[lane+128]);
    float s = x0+x1+x2;
    float q = x0*x0 + x1*x1 + x2*x2;
    #pragma unroll
    for (int off=32; off; off>>=1){ s += __shfl_xor(s,off,64); q += __shfl_xor(q,off,64); }
    float mean = s*(1.f/192.f);
    float var  = q*(1.f/192.f) - mean*mean;
    float inv  = rsqrtf(var + 1e-6f);
    u16* orow = out + pix*192;
    orow[lane]     = f2b((x0-mean)*inv*g[lane]     + bta[lane]);
    orow[lane+64]  = f2b((x1-mean)*inv*g[lane+64]  + bta[lane+64]);
    orow[lane+128] = f2b((x2-mean)*inv*g[lane+128] + bta[lane+128]);
}

// ---------- bf16 MFMA GEMM: M-tile 128 (wave=32 rows), W-in-LDS once, A streamed ----------
#define GM_NONE 0
#define GM_RES 1
#define GM_GELU_BN 2
#define GM_BN_RES 3

template<int MODE, int K, int NT, bool SPLIT=false>
__global__ __launch_bounds__(256) void gemm_bf16_k(
    const u16* __restrict__ A, int lda,
    const u16* __restrict__ A2, int lda2,
    const u16* __restrict__ W,
    void* __restrict__ Cv, int ldc,
    const u16* __restrict__ R, int ldr,
    const float* __restrict__ bg, const float* __restrict__ bb,
    const float* __restrict__ bm_, const float* __restrict__ bv,
    int N)
{
    constexpr int LSTR = (K==96) ? 104 : ((K==192) ? 200 : 264);  // stride%32dw==4
    constexpr int NF = NT/16;
    __shared__ u16 Ws[NT*LSTR];
    int t = threadIdx.x;
    int bn = blockIdx.y * NT;
    int bm = blockIdx.x * 128;
    {
        constexpr int K8 = K/8;
        for (int i = t; i < NT*K8; i += 256){
            int row = i / K8, j = (i % K8)*8;
            int n = bn + row;
            short8v v = {};
            if (n < N) v = *(const short8v*)(W + (size_t)n*K + j);
            *(short8v*)&Ws[row*LSTR + j] = v;
        }
    }
    __syncthreads();
    int wave = t >> 6, lane = t & 63;
    int wm = wave*32;
    int lr = lane & 15, lk = lane >> 4;
    const u16* arow  = A + (size_t)(bm + wm + lr)*lda + lk*8;
    const u16* arow2 = SPLIT ? (A2 + (size_t)(bm + wm + lr)*lda2 + lk*8) : nullptr;
    floatx4 acc[2][NF] = {};
    #pragma unroll
    for (int k0 = 0; k0 < K; k0 += 32){
        short8v afr[2];
        if (SPLIT && k0 >= 96){
            #pragma unroll
            for (int m=0;m<2;m++)
                afr[m] = *(const short8v*)(arow2 + (size_t)(m*16)*lda2 + (k0-96));
        } else {
            #pragma unroll
            for (int m=0;m<2;m++)
                afr[m] = *(const short8v*)(arow + (size_t)(m*16)*lda + k0);
        }
        #pragma unroll
        for (int n2=0;n2<NF;n2++){
            short8v bfr = *(const short8v*)&Ws[(n2*16+lr)*LSTR + k0 + lk*8];
            #pragma unroll
            for (int m=0;m<2;m++)
                acc[m][n2] = __builtin_amdgcn_mfma_f32_16x16x32_bf16(afr[m], bfr, acc[m][n2], 0,0,0);
        }
    }
    #pragma unroll
    for (int m=0;m<2;m++){
        #pragma unroll
        for (int n2=0;n2<NF;n2++){
            int gcol = bn + n2*16 + lr;
            if (gcol >= N) continue;
            float bscale = 0.f, bmv = 0.f, bbv = 0.f;
            if (MODE == GM_GELU_BN || MODE == GM_BN_RES){
                bscale = rsqrtf(bv[gcol]+1e-5f)*bg[gcol];
                bmv = bm_[gcol]; bbv = bb[gcol];
            }
            #pragma unroll
            for (int rg=0; rg<4; rg++){
                int grow = bm + wm + m*16 + lk*4 + rg;
                float v = acc[m][n2][rg];
                if (MODE == GM_RES){
                    v += b2f(R[(size_t)grow*ldr + gcol]);
                    ((u16*)Cv)[(size_t)grow*ldc + gcol] = f2b(v);
                } else if (MODE == GM_BN_RES){
                    float bnv = (v - bmv)*bscale + bbv;
                    ((float*)Cv)[(size_t)grow*ldc + gcol] = bnv + b2f(R[(size_t)grow*ldr + gcol]);
                } else if (MODE == GM_GELU_BN){
                    float gl = gelu_fast(v);
                    v = (gl - bmv)*bscale + bbv;
                    ((u16*)Cv)[(size_t)grow*ldc + gcol] = f2b(v);
                } else {
                    ((u16*)Cv)[(size_t)grow*ldc + gcol] = f2b(v);
                }
            }
        }
    }
}

// ---------- fused gate GEMM (M-tile 128): gpix = sigmoid( relu(Y@gw1^T+gb1).w2 + b2 ) ----------
#define GSTR 200
__global__ __launch_bounds__(256) void gate_gemm_k(
    const u16* __restrict__ A,
    const u16* __restrict__ W,
    const float* __restrict__ gb1, const float* __restrict__ w2,
    const float* __restrict__ b2, float* __restrict__ gpix)
{
    __shared__ u16 Ws[96*GSTR];
    int t = threadIdx.x;
    int bm = blockIdx.x * 128;
    for (int i = t; i < 96*24; i += 256){
        int row = i/24, j = (i%24)*8;
        *(short8v*)&Ws[row*GSTR + j] = *(const short8v*)(W + (size_t)row*192 + j);
    }
    __syncthreads();
    int wave = t >> 6, lane = t & 63;
    int wm = wave*32;
    int lr = lane & 15, lk = lane >> 4;
    const u16* arow = A + (size_t)(bm + wm + lr)*192 + lk*8;
    floatx4 acc[2][6] = {};
    #pragma unroll
    for (int k0 = 0; k0 < 192; k0 += 32){
        short8v afr[2];
        #pragma unroll
        for (int m=0;m<2;m++)
            afr[m] = *(const short8v*)(arow + (size_t)(m*16)*192 + k0);
        #pragma unroll
        for (int n2=0;n2<6;n2++){
            short8v bfr = *(const short8v*)&Ws[(n2*16+lr)*GSTR + k0 + lk*8];
            #pragma unroll
            for (int m=0;m<2;m++)
                acc[m][n2] = __builtin_amdgcn_mfma_f32_16x16x32_bf16(afr[m], bfr, acc[m][n2], 0,0,0);
        }
    }
    float gbv[6], w2v[6];
    #pragma unroll
    for (int n2=0;n2<6;n2++){ int col = n2*16 + lr; gbv[n2] = gb1[col]; w2v[n2] = w2[col]; }
    float b2s = b2[0];
    #pragma unroll
    for (int m=0;m<2;m++){
        #pragma unroll
        for (int rg=0;rg<4;rg++){
            float part = 0.f;
            #pragma unroll
            for (int n2=0;n2<6;n2++){
                float v = fmaxf(acc[m][n2][rg] + gbv[n2], 0.f);
                part = fmaf(v, w2v[n2], part);
            }
            #pragma unroll
            for (int off=1; off<16; off<<=1) part += __shfl_xor(part, off, 64);
            if (lr == 0){
                int row = bm + wm + m*16 + lk*4 + rg;
                gpix[row] = 1.f/(1.f+expf(-(part + b2s)));
            }
        }
    }
}

// ---------- deterministic mean of gpix -> dyn_k ----------
__global__ __launch_bounds__(1024) void gate_reduce_k(const float* __restrict__ gpix,
                                                      float* __restrict__ dynk)
{
    __shared__ float sm[16];
    float s = 0.f;
    for (int i=threadIdx.x; i<NPIX; i+=1024) s += gpix[i];
    #pragma unroll
    for (int off=32; off; off>>=1) s += __shfl_xor(s,off,64);
    int wid = threadIdx.x>>6, lane = threadIdx.x&63;
    if (lane==0) sm[wid]=s;
    __syncthreads();
    if (threadIdx.x==0){
        float tot=0.f; for (int i=0;i<16;i++) tot+=sm[i];
        *dynk = floorf(12.0f * (tot/(float)NPIX));
    }
}

// ---------- qkv depthwise 3x3 (288 ch), 4-col sweep, LDS weights, XCD-swizzled ----------
#define QPOS(c8) ((c8)*8 + ((c8)>>2)*4)
#define QTAPSTRIDE 324
__global__ __launch_bounds__(256) void qkv_dw_k(const u16* __restrict__ in,
    const float* __restrict__ w, u16* __restrict__ out, size_t planeStride)
{
    __shared__ float wlds[9*QTAPSTRIDE];
    int t = threadIdx.x;
    for (int i=t; i<2592; i+=256){
        int tap = i/288, cc = i%288;
        wlds[tap*QTAPSTRIDE + QPOS(cc>>3) + (cc&7)] = w[cc*9+tap];
    }
    __syncthreads();
    int bid = blockIdx.x;
    int sb = (bid & 7)*(gridDim.x >> 3) + (bid >> 3);
    int idx = sb*256 + t;
    int c8 = idx % 36; int pq = idx / 36;
    int xg = pq & 31; int hy = (pq >> 5) & 127; int img = pq >> 12;
    int x0 = xg*4;
    int c0 = c8*8;
    int wofs = QPOS(c8);
    float acc[4][8] = {{0.f}};
    #pragma unroll
    for (int ky=0; ky<3; ky++){
        int hh = hy + ky - 1; if ((unsigned)hh >= HH) continue;
        float wr[3][8];
        #pragma unroll
        for (int kx=0; kx<3; kx++){
            floatx4 wa = *(const floatx4*)&wlds[(ky*3+kx)*QTAPSTRIDE + wofs];
            floatx4 wb = *(const floatx4*)&wlds[(ky*3+kx)*QTAPSTRIDE + wofs + 4];
            #pragma unroll
            for (int j=0;j<4;j++){ wr[kx][j]=wa[j]; wr[kx][4+j]=wb[j]; }
        }
        const u16* rowp = in + ((size_t)(img*HH+hh)*WW)*288 + c0;
        #pragma unroll
        for (int cc=0; cc<6; cc++){
            int cx = x0 - 1 + cc;
            if ((unsigned)cx >= WW) continue;
            short8v v = *(const short8v*)(rowp + (size_t)cx*288);
            float vf[8];
            #pragma unroll
            for (int j=0;j<8;j++) vf[j] = b2f((u16)v[j]);
            #pragma unroll
            for (int dx=0; dx<4; dx++){
                int kx = cc - dx;
                if (kx < 0 || kx >= 3) continue;
                #pragma unroll
                for (int j=0;j<8;j++) acc[dx][j] = fmaf(wr[kx][j], vf[j], acc[dx][j]);
            }
        }
    }
    size_t pix0 = (size_t)(img*HH+hy)*WW + x0;
    int sec = c0/96, qc0 = c0 - sec*96;
    u16* outp = out + (size_t)sec*planeStride + qc0;
    #pragma unroll
    for (int dx=0; dx<4; dx++){
        short8v o;
        #pragma unroll
        for (int j=0;j<8;j++) o[j] = (short)f2b(acc[dx][j]);
        *(short8v*)(outp + (pix0+dx)*96) = o;
    }
}

// ---------- Gram partials per (img,head,slice), Q/K planes, vectorized staging ----------
__global__ __launch_bounds__(256) void gram_k(const u16* __restrict__ Qp,
    const u16* __restrict__ Kp, float* __restrict__ part)
{
    int bh = blockIdx.x;
    int slice = blockIdx.y;
    int img = bh >> 3, h = bh & 7;
    const u16* Qb = Qp + (size_t)img*HW*96 + h*12;
    const u16* Kb = Kp + (size_t)img*HW*96 + h*12;
    __shared__ float qs[64][12];
    __shared__ float ks[64][12];
    int t = threadIdx.x;
    float acc = 0.f;
    int c = (t<144) ? t/12 : (t<156 ? t-144 : t-156);
    int d = (t<144) ? t%12 : 0;
    for (int st=0; st<16; st++){
        int pix0 = slice*1024 + st*64;
        __syncthreads();
        for (int i=t; i<384; i+=256){
            int p = i/6, j = i%6;
            const u16* src = (j<3) ? (Qb + (size_t)(pix0+p)*96 + j*4)
                                   : (Kb + (size_t)(pix0+p)*96 + (j-3)*4);
            short4v v = *(const short4v*)src;
            float f0=b2f((u16)v.x), f1=b2f((u16)v.y), f2=b2f((u16)v.z), f3=b2f((u16)v.w);
            if (j<3){ int jj=j*4;     qs[p][jj]=f0; qs[p][jj+1]=f1; qs[p][jj+2]=f2; qs[p][jj+3]=f3; }
            else    { int jj=(j-3)*4; ks[p][jj]=f0; ks[p][jj+1]=f1; ks[p][jj+2]=f2; ks[p][jj+3]=f3; }
        }
        __syncthreads();
        if (t<144){        for (int p=0;p<64;p++) acc = fmaf(qs[p][c], ks[p][d], acc); }
        else if (t<156){   for (int p=0;p<64;p++) acc = fmaf(qs[p][c], qs[p][c], acc); }
        else if (t<168){   for (int p=0;p<64;p++) acc = fmaf(ks[p][c], ks[p][c], acc); }
    }
    if (t<168) part[((size_t)bh*16 + slice)*168 + t] = acc;
}

__global__ __launch_bounds__(256) void gram_combine_k(const float* __restrict__ part,
                                                      float* __restrict__ gram, int n)
{
    int i = blockIdx.x*256 + threadIdx.x;
    if (i >= n) return;
    int bh = i/168, t = i%168;
    float s = 0.f;
    for (int sl=0; sl<16; sl++) s += part[((size_t)bh*16+sl)*168 + t];
    gram[i] = s;
}

// ---------- attn 12x12: normalize, temperature, top-k mask, softmax ----------
__global__ __launch_bounds__(256) void attn_k(const float* __restrict__ gram,
    const float* __restrict__ temp, const float* __restrict__ dynk_p,
    const float* __restrict__ a1, const float* __restrict__ a2,
    const float* __restrict__ a3, const float* __restrict__ a4,
    float* __restrict__ attnW)
{
    int bh = blockIdx.x;
    int h = bh & 7;
    __shared__ float av[12][12];
    __shared__ float mv[12][12];
    __shared__ float nq[12], nk[12];
    int t = threadIdx.x;
    if (t < 12) nq[t] = fmaxf(sqrtf(gram[bh*168+144+t]), 1e-12f);
    else if (t < 24) nk[t-12] = fmaxf(sqrtf(gram[bh*168+156+(t-12)]), 1e-12f);
    __syncthreads();
    if (t < 144){
        int c=t/12, d=t%12;
        av[c][d] = gram[bh*168+t] / (nq[c]*nk[d]) * temp[h];
    }
    __syncthreads();
    float dk = *dynk_p;
    if (t < 144){
        int c=t/12, d=t%12; float v = av[c][d];
        int r = 0;
        #pragma unroll
        for (int j=0;j<12;j++){
            float o = av[c][j];
            r += (o > v) ? 1 : ((o == v && j < d) ? 1 : 0);
        }
        mv[c][d] = ((float)r < dk) ? v : -INFINITY;
    }
    __syncthreads();
    if (t < 12){
        float mx = -INFINITY;
        for (int d2=0; d2<12; d2++) mx = fmaxf(mx, mv[t][d2]);
        float e[12]; float s = 0.f;
        for (int d2=0; d2<12; d2++){ e[d2] = expf(mv[t][d2]-mx); s += e[d2]; }
        float sc = (a1[0]+a2[0]+a3[0]+a4[0]) / s;
        for (int d2=0; d2<12; d2++) attnW[(size_t)bh*144 + t*12 + d2] = e[d2]*sc;
    }
}

// ---------- attn apply -> P96 bf16 (V plane input); thread = (pixel, head) ----------
__global__ __launch_bounds__(256) void attn_apply_k(const u16* __restrict__ Vp,
    const float* __restrict__ attnW, u16* __restrict__ P)
{
    int gid = blockIdx.x*256 + threadIdx.x;
    int h = gid % 8; size_t pix = (size_t)(gid / 8);
    int img = (int)(pix >> 14);
    const u16* vp = Vp + pix*96 + h*12;
    float vf[12];
    #pragma unroll
    for (int j=0;j<3;j++){
        short4v v = *(const short4v*)(vp + j*4);
        vf[j*4+0]=b2f((u16)v.x); vf[j*4+1]=b2f((u16)v.y);
        vf[j*4+2]=b2f((u16)v.z); vf[j*4+3]=b2f((u16)v.w);
    }
    const float* awb = attnW + ((size_t)(img*8+h))*144;
    u16 o[12];
    #pragma unroll
    for (int cc=0; cc<12; cc++){
        const float4* ap = (const float4*)(awb + cc*12);
        float4 a0 = ap[0], a1 = ap[1], a2 = ap[2];
        float s = a0.x*vf[0] + a0.y*vf[1] + a0.z*vf[2] + a0.w*vf[3]
                + a1.x*vf[4] + a1.y*vf[5] + a1.z*vf[6] + a1.w*vf[7]
                + a2.x*vf[8] + a2.y*vf[9] + a2.z*vf[10]+ a2.w*vf[11];
        o[cc] = f2b(s);
    }
    u16* op = P + pix*96 + h*12;
    *(short4v*)(op)   = *(short4v*)&o[0];
    *(short4v*)(op+4) = *(short4v*)&o[4];
    *(short4v*)(op+8) = *(short4v*)&o[8];
}

// ---------- FFN multi-scale depthwise, row-sweep; single kernel, blockIdx.y = group ----------
template<int KS>
__device__ __forceinline__ void ffn_body(const u16* __restrict__ V0,
    const float* __restrict__ wsrc, const float* __restrict__ bsrc, int cbase,
    const float* __restrict__ bn2g, const float* __restrict__ bn2b,
    const float* __restrict__ bn2m, const float* __restrict__ bn2v,
    u16* __restrict__ U, float* wlds, float* bng, float* bnb, float* bnm, float* bnvr,
    int gridx)
{
    constexpr int PAD = KS/2;
    int t = threadIdx.x;
    for (int i=t; i<KS*KS*64; i+=256){
        int tap = i >> 6, cc = i & 63;
        wlds[tap*64 + cc] = wsrc[cc*KS*KS + tap];
    }
    if (t < 64){
        bng[t] = bn2g[cbase+t]; bnb[t] = bn2b[cbase+t];
        bnm[t] = bn2m[cbase+t]; bnvr[t] = rsqrtf(bn2v[cbase+t]+1e-5f);
    }
    __syncthreads();
    int ci = t & 7, seg = t >> 3;
    int bid = blockIdx.x;
    int rowid = (bid & 7)*(gridx >> 3) + (bid >> 3);
    int img = rowid >> 7, hy = rowid & 127;
    int c0r = ci*8;
    int c0 = cbase + c0r;
    int x0 = seg*4;
    float acc[4][8];
    {
        floatx4 b0 = *(const floatx4*)(bsrc + c0r);
        floatx4 b1 = *(const floatx4*)(bsrc + c0r + 4);
        #pragma unroll
        for (int dx=0;dx<4;dx++){
            #pragma unroll
            for (int j=0;j<4;j++){ acc[dx][j]=b0[j]; acc[dx][4+j]=b1[j]; }
        }
    }
    #pragma unroll
    for (int ky=0; ky<KS; ky++){
        int hh = hy + ky - PAD;
        if ((unsigned)hh >= HH) continue;
        float wr[KS][8];
        #pragma unroll
        for (int kx=0; kx<KS; kx++){
            floatx4 wa = *(const floatx4*)&wlds[(ky*KS+kx)*64 + c0r];
            floatx4 wb = *(const floatx4*)&wlds[(ky*KS+kx)*64 + c0r + 4];
            #pragma unroll
            for (int j=0;j<4;j++){ wr[kx][j]=wa[j]; wr[kx][4+j]=wb[j]; }
        }
        const u16* rowp = V0 + ((size_t)(img*HH+hh)*WW)*256 + c0;
        #pragma unroll
        for (int cc=0; cc<4+2*PAD; cc++){
            int cx = x0 - PAD + cc;
            if ((unsigned)cx >= WW) continue;
            short8v v = *(const short8v*)(rowp + (size_t)cx*256);
            float vf[8];
            #pragma unroll
            for (int j=0;j<8;j++) vf[j] = b2f((u16)v[j]);
            #pragma unroll
            for (int dx=0; dx<4; dx++){
                int kx = cc - dx;
                if (kx < 0 || kx >= KS) continue;
                #pragma unroll
                for (int j=0;j<8;j++) acc[dx][j] = fmaf(wr[kx][j], vf[j], acc[dx][j]);
            }
        }
    }
    size_t rbase = (size_t)(img*HH+hy)*WW;
    #pragma unroll
    for (int dx=0; dx<4; dx++){
        size_t pix = rbase + x0 + dx;
        short8v vc = *(const short8v*)(V0 + pix*256 + c0);
        short8v o;
        #pragma unroll
        for (int j=0;j<8;j++){
            float v0c = b2f((u16)vc[j]);
            float u1 = acc[dx][j] + v0c;
            float gl = gelu_fast(u1);
            float bn = (gl - bnm[c0r+j])*bnvr[c0r+j]*bng[c0r+j] + bnb[c0r+j];
            o[j] = (short)f2b(bn*v0c);
        }
        *(short8v*)(U + pix*256 + c0) = o;
    }
}

__global__ __launch_bounds__(256) void ffn_dw_all_k(const u16* __restrict__ V0,
    const float* __restrict__ w0, const float* __restrict__ bb0,
    const float* __restrict__ w1, const float* __restrict__ bb1,
    const float* __restrict__ w2, const float* __restrict__ bb2,
    const float* __restrict__ w3, const float* __restrict__ bb3,
    const float* __restrict__ bn2g, const float* __restrict__ bn2b,
    const float* __restrict__ bn2m, const float* __restrict__ bn2v,
    u16* __restrict__ U)
{
    __shared__ float wlds[49*64];
    __shared__ float bng[64], bnb[64], bnm[64], bnvr[64];
    int gx = gridDim.x;
    switch(blockIdx.y){
        case 0: ffn_body<1>(V0, w0, bb0, 0,   bn2g,bn2b,bn2m,bn2v, U, wlds,bng,bnb,bnm,bnvr, gx); break;
        case 1: ffn_body<3>(V0, w1, bb1, 64,  bn2g,bn2b,bn2m,bn2v, U, wlds,bng,bnb,bnm,bnvr, gx); break;
        case 2: ffn_body<5>(V0, w2, bb2, 128, bn2g,bn2b,bn2m,bn2v, U, wlds,bng,bnb,bnm,bnvr, gx); break;
        default: ffn_body<7>(V0, w3, bb3, 192, bn2g,bn2b,bn2m,bn2v, U, wlds,bng,bnb,bnm,bnvr, gx); break;
    }
}

extern "C" void kernel_launch(void* const* d_in, const int* in_sizes, int n_in,
                              void* d_out, int out_size, void* d_ws, size_t ws_size,
                              hipStream_t stream)
{
    const float* x     = (const float*)d_in[0];
    const float* pos_w = (const float*)d_in[1];
    const float* pos_b = (const float*)d_in[2];
    const float* ln1g  = (const float*)d_in[3];
    const float* ln1b  = (const float*)d_in[4];
    const float* temp  = (const float*)d_in[5];
    const float* qkvw  = (const float*)d_in[6];
    const float* qkvdw = (const float*)d_in[7];
    const float* projw = (const float*)d_in[8];
    const float* gw1   = (const float*)d_in[9];
    const float* gb1   = (const float*)d_in[10];
    const float* gw2   = (const float*)d_in[11];
    const float* gb2   = (const float*)d_in[12];
    const float* a1    = (const float*)d_in[13];
    const float* a2    = (const float*)d_in[14];
    const float* a3    = (const float*)d_in[15];
    const float* a4    = (const float*)d_in[16];
    const float* ln2g  = (const float*)d_in[17];
    const float* ln2b  = (const float*)d_in[18];
    const float* fc1w  = (const float*)d_in[19];
    const float* bn1g  = (const float*)d_in[20];
    const float* bn1b  = (const float*)d_in[21];
    const float* bn1m  = (const float*)d_in[22];
    const float* bn1v  = (const float*)d_in[23];
    const float* bn2g  = (const float*)d_in[24];
    const float* bn2b  = (const float*)d_in[25];
    const float* bn2m  = (const float*)d_in[26];
    const float* bn2v  = (const float*)d_in[27];
    const float* fc2w  = (const float*)d_in[28];
    const float* bn3g  = (const float*)d_in[29];
    const float* bn3b  = (const float*)d_in[30];
    const float* bn3m  = (const float*)d_in[31];
    const float* bn3v  = (const float*)d_in[32];
    const float* dw0w  = (const float*)d_in[33];
    const float* dw0b  = (const float*)d_in[34];
    const float* dw1w  = (const float*)d_in[35];
    const float* dw1b  = (const float*)d_in[36];
    const float* dw2w  = (const float*)d_in[37];
    const float* dw2b  = (const float*)d_in[38];
    const float* dw3w  = (const float*)d_in[39];
    const float* dw3b  = (const float*)d_in[40];

    float* OUT = (float*)d_out;      // final fp32 output (written once by fc2)

    // ---- fixed small buffers + bf16 residual stream A ----
    char* p = (char*)d_ws;
    float* gpix  = (float*)p;                 p += (size_t)NPIX*4;
    float* dynk  = (float*)p;                 p += 256;
    float* gpart = (float*)p;                 p += 64*16*168*4;
    float* gram  = (float*)p;                 p += 64*168*4;
    float* attnW = (float*)p;                 p += 64*144*4;
    float* wposT = (float*)p;                 p += 1728*4;
    u16*   wbf   = (u16*)p;                   p += (size_t)WTOT*2;
    u16*   Abf   = (u16*)p;                   p += (size_t)NPIX*192*2;   // 50.3 MB
    size_t fixedB = (size_t)(p - (char*)d_ws);

    // ---- choose chunk size from ws_size: per-image = Y(192)+B1(288)+B2(288) bf16 ----
    size_t perImg = (size_t)HW*2*(192+288+288);   // 25,165,824
    int CBr = 2;
    if (ws_size >= fixedB + 8*perImg) CBr = 8;
    else if (ws_size >= fixedB + 4*perImg) CBr = 4;
    int NCHUNKr = BB/CBr;
    size_t CHWr = (size_t)CBr*HW;

    u16* Ybf = (u16*)p;                   p += CHWr*192*2;
    u16* B1  = (u16*)p;                   p += CHWr*288*2;
    u16* B2  = (u16*)p;
    u16* qkvwb = wbf;
    u16* projwb= wbf + WQ;
    u16* gw1b  = wbf + WQ + WP;
    u16* fc1b  = wbf + WQ + WP + WG;
    u16* fc2b  = wbf + WQ + WP + WG + WF1;
    u16* QKVbf = B1;     // qkv out (288 interleaved)
    u16* QKVdbf= B2;     // qkv_dw out: Q|K|V planes of CHWr*96 each
    u16* P96   = B1;     // attn out (QKV dead)
    u16* Zbf   = B2;     // LN2 out (QKVd dead)
    u16* V0bf  = B1;     // fc1 out (P96 dead)
    u16* Ubf   = B2;     // ffn out (Z dead)

    wprep_k<<<(WTOT+255)/256, 256, 0, stream>>>(qkvw, projw, gw1, fc1w, fc2w,
                                                pos_w, wbf, wposT);
    pos_conv_k<<<NPIX/8, 192, 0, stream>>>(x, wposT, pos_b, Abf);

    // gate phase: LN1 -> fused gate GEMM -> gpix
    for (int c=0; c<NCHUNKr; c++){
        const u16* Ab = Abf + (size_t)c*CHWr*192;
        ln_k<<<CHWr/4, 256, 0, stream>>>(Ab, ln1g, ln1b, Ybf);
        gate_gemm_k<<<CHWr/128, 256, 0, stream>>>(Ybf, gw1b, gb1, gw2, gb2,
                                                  gpix + (size_t)c*CHWr);
    }
    gate_reduce_k<<<1, 1024, 0, stream>>>(gpix, dynk);

    // main phase
    for (int c=0; c<NCHUNKr; c++){
        u16* Ab = Abf + (size_t)c*CHWr*192;
        if (NCHUNKr > 1)   // single-chunk mode: Ybf from gate phase is still valid
            ln_k<<<CHWr/4, 256, 0, stream>>>(Ab, ln1g, ln1b, Ybf);
        {   // qkv 1x1: N=288 = 3 x 96-tiles
            dim3 g(CHWr/128, 3);
            gemm_bf16_k<GM_NONE,96,96><<<g, 256, 0, stream>>>(Ybf, 192, nullptr, 0,
                qkvwb, QKVbf, 288, nullptr, 0, nullptr,nullptr,nullptr,nullptr, 288);
        }
        size_t pstr = CHWr*96;
        qkv_dw_k<<<CHWr/4*36/256, 256, 0, stream>>>(QKVbf, qkvdw, QKVdbf, pstr);
        { dim3 g(CBr*8, 16); gram_k<<<g, 256, 0, stream>>>(QKVdbf, QKVdbf + pstr, gpart); }
        gram_combine_k<<<(CBr*8*168+255)/256, 256, 0, stream>>>(gpart, gram, CBr*8*168);
        attn_k<<<CBr*8, 256, 0, stream>>>(gram, temp, dynk, a1,a2,a3,a4, attnW);
        attn_apply_k<<<CHWr*8/256, 256, 0, stream>>>(QKVdbf + 2*pstr, attnW, P96);
        {   // proj + residual: N=192 = 2 x 96-tiles
            dim3 g(CHWr/128, 2);
            gemm_bf16_k<GM_RES,192,96,true><<<g, 256, 0, stream>>>(P96, 96, Ybf+96, 192,
                projwb, Ab, 192, Ab, 192, nullptr,nullptr,nullptr,nullptr, 192);
        }
        ln_k<<<CHWr/4, 256, 0, stream>>>(Ab, ln2g, ln2b, Zbf);
        {   // fc1: N=256 = 4 x 64-tiles
            dim3 g(CHWr/128, 4);
            gemm_bf16_k<GM_GELU_BN,192,64><<<g, 256, 0, stream>>>(Zbf, 192, nullptr, 0,
                fc1b, V0bf, 256, nullptr, 0, bn1g,bn1b,bn1m,bn1v, 256);
        }
        {   // multi-scale depthwise, all 4 groups in one launch
            int rows = (int)(CHWr/WW);
            dim3 g(rows, 4);
            ffn_dw_all_k<<<g, 256, 0, stream>>>(V0bf, dw0w,dw0b,dw1w,dw1b,dw2w,dw2b,
                                                dw3w,dw3b, bn2g,bn2b,bn2m,bn2v, Ubf);
        }
        {   // fc2 + bn3 + residual -> fp32 OUT: N=192 = 2 x 96-tiles
            dim3 g(CHWr/128, 2);
            gemm_bf16_k<GM_BN_RES,256,96><<<g, 256, 0, stream>>>(Ubf, 256, nullptr, 0,
                fc2b, OUT + (size_t)c*CHWr*192, 192, Ab, 192, bn3g,bn3b,bn3m,bn3v, 192);
        }
    }
}

// Round 21
// 583.094 us; speedup vs baseline: 1.1246x; 1.0117x over previous
//
#include <hip/hip_runtime.h>
#include <hip/hip_bf16.h>
#include <math.h>

#define BB 8
#define HH 128
#define WW 128
#define HW (HH*WW)          // 16384
#define NPIX (BB*HW)        // 131072

typedef unsigned short u16;
typedef __attribute__((ext_vector_type(4))) float  floatx4;
typedef __attribute__((ext_vector_type(4))) short  short4v;
typedef __attribute__((ext_vector_type(8))) short  short8v;

static __device__ __forceinline__ float gelu_fast(float x){
    float u = 0.7978845608028654f*(x + 0.044715f*x*x*x);
    float e = __expf(2.f*u);
    float th = 1.f - 2.f/(e + 1.f);
    return 0.5f*x*(1.f + th);
}
static __device__ __forceinline__ float b2f(u16 v){
    union { unsigned u; float f; } x; x.u = ((unsigned)v)<<16; return x.f;
}
static __device__ __forceinline__ u16 f2b(float f){
    __hip_bfloat16 h = __float2bfloat16(f);
    return *(u16*)&h;
}

// ---------- weight prep: fp32 -> bf16 GEMM weights + transposed pos weights ----------
#define WQ 27648
#define WP 36864
#define WG 18432
#define WF1 49152
#define WF2 49152
#define WTOT (WQ+WP+WG+WF1+WF2)   // 181248
__global__ __launch_bounds__(256) void wprep_k(const float* __restrict__ a,
    const float* __restrict__ b, const float* __restrict__ c,
    const float* __restrict__ d, const float* __restrict__ e,
    const float* __restrict__ posw, u16* __restrict__ o, float* __restrict__ wT)
{
    int i = blockIdx.x*256 + threadIdx.x;
    if (i < 1728){   // wT[tap][192]: wT[tap*192+c] = posw[c*9+tap]
        wT[i] = posw[(i%192)*9 + (i/192)];
    }
    if (i >= WTOT) return;
    float v;
    if (i < WQ) v = a[i];
    else if (i < WQ+WP) v = b[i-WQ];
    else if (i < WQ+WP+WG) v = c[i-WQ-WP];
    else if (i < WQ+WP+WG+WF1) v = d[i-WQ-WP-WG];
    else v = e[i-WQ-WP-WG-WF1];
    o[i] = f2b(v);
}

// ---------- pos depthwise 3x3 + bias + residual -> bf16 A; LDS halo, 2 px/thread ----------
__global__ __launch_bounds__(192) void pos_conv_k(const float* __restrict__ x,
    const float* __restrict__ wT, const float* __restrict__ bias, u16* __restrict__ out)
{
    __shared__ float4 lds[3][10][48];
    int bid = blockIdx.x;
    int sb = (bid & 7)*(gridDim.x >> 3) + (bid >> 3);   // XCD image-slice swizzle
    int t = threadIdx.x;
    int unit = sb;                       // over NPIX/8 column-octets
    int x0 = (unit & 15)*8;
    int hy = (unit >> 4) & 127;
    int b  = unit >> 11;

    const float4* x4 = (const float4*)x;
    float4 z4 = make_float4(0.f,0.f,0.f,0.f);
    for (int i = t; i < 1440; i += 192){
        int c4s = i % 48;
        int rc  = i / 48;
        int r   = rc / 10;
        int cp  = rc % 10;
        int hh  = hy + r - 1;
        int cx  = x0 + cp - 1;
        float4 v = z4;
        if ((unsigned)hh < HH && (unsigned)cx < WW)
            v = x4[((size_t)(b*HH+hh)*WW + cx)*48 + c4s];
        lds[r][cp][c4s] = v;
    }
    __syncthreads();

    int c4 = t % 48;
    int p0 = (t / 48)*2;
    int c0 = c4*4;
    floatx4 wv[9];
    #pragma unroll
    for (int tap=0; tap<9; tap++)
        wv[tap] = *(const floatx4*)&wT[tap*192 + c0];

    float4 xv[3][4];
    #pragma unroll
    for (int i=0;i<3;i++)
        #pragma unroll
        for (int k=0;k<4;k++)
            xv[i][k] = lds[i][p0+k][c4];

    float4 bias4 = *(const float4*)(bias + c0);
    float4 acc0 = bias4, acc1 = bias4;
    #pragma unroll
    for (int i=0;i<3;i++){
        #pragma unroll
        for (int k=0;k<3;k++){
            floatx4 w = wv[i*3+k];
            float4 a = xv[i][k];
            float4 bqq = xv[i][k+1];
            acc0.x = fmaf(w[0], a.x, acc0.x);
            acc0.y = fmaf(w[1], a.y, acc0.y);
            acc0.z = fmaf(w[2], a.z, acc0.z);
            acc0.w = fmaf(w[3], a.w, acc0.w);
            acc1.x = fmaf(w[0], bqq.x, acc1.x);
            acc1.y = fmaf(w[1], bqq.y, acc1.y);
            acc1.z = fmaf(w[2], bqq.z, acc1.z);
            acc1.w = fmaf(w[3], bqq.w, acc1.w);
        }
    }
    float4 xc0 = xv[1][1];
    float4 xc1 = xv[1][2];
    acc0.x += xc0.x; acc0.y += xc0.y; acc0.z += xc0.z; acc0.w += xc0.w;
    acc1.x += xc1.x; acc1.y += xc1.y; acc1.z += xc1.z; acc1.w += xc1.w;

    size_t pix0 = (size_t)(b*HH + hy)*WW + x0 + p0;
    short4v o0, o1;
    o0.x=(short)f2b(acc0.x); o0.y=(short)f2b(acc0.y);
    o0.z=(short)f2b(acc0.z); o0.w=(short)f2b(acc0.w);
    o1.x=(short)f2b(acc1.x); o1.y=(short)f2b(acc1.y);
    o1.z=(short)f2b(acc1.z); o1.w=(short)f2b(acc1.w);
    *(short4v*)(out + pix0*192 + c0) = o0;
    *(short4v*)(out + (pix0+1)*192 + c0) = o1;
}

// ---------- LayerNorm over C=192, bf16 in -> split Y0|Y1 planes (96 ch each) ----------
__global__ __launch_bounds__(256) void ln_split_k(const u16* __restrict__ in,
    const float* __restrict__ g, const float* __restrict__ bta,
    u16* __restrict__ y0, u16* __restrict__ y1)
{
    int wid = threadIdx.x >> 6, lane = threadIdx.x & 63;
    size_t pix = (size_t)blockIdx.x*4 + wid;
    const u16* row = in + pix*192;
    float x0 = b2f(row[lane]), x1 = b2f(row[lane+64]), x2 = b2f(row[lane+128]);
    float s = x0+x1+x2;
    float q = x0*x0 + x1*x1 + x2*x2;
    #pragma unroll
    for (int off=32; off; off>>=1){ s += __shfl_xor(s,off,64); q += __shfl_xor(q,off,64); }
    float mean = s*(1.f/192.f);
    float var  = q*(1.f/192.f) - mean*mean;
    float inv  = rsqrtf(var + 1e-6f);
    y0[pix*96 + lane] = f2b((x0-mean)*inv*g[lane] + bta[lane]);
    int c1 = lane + 64;
    u16 v1 = f2b((x1-mean)*inv*g[c1] + bta[c1]);
    if (c1 < 96) y0[pix*96 + c1] = v1;
    else         y1[pix*96 + c1 - 96] = v1;
    int c2 = lane + 128;
    y1[pix*96 + c2 - 96] = f2b((x2-mean)*inv*g[c2] + bta[c2]);
}

// ---------- LayerNorm over C=192, bf16 in -> contiguous bf16 out (LN2) ----------
__global__ __launch_bounds__(256) void ln_k(const u16* __restrict__ in,
    const float* __restrict__ g, const float* __restrict__ bta, u16* __restrict__ out)
{
    int wid = threadIdx.x >> 6, lane = threadIdx.x & 63;
    size_t pix = (size_t)blockIdx.x*4 + wid;
    const u16* row = in + pix*192;
    float x0 = b2f(row[lane]), x1 = b2f(row[lane+64]), x2 = b2f(row[lane+128]);
    float s = x0+x1+x2;
    float q = x0*x0 + x1*x1 + x2*x2;
    #pragma unroll
    for (int off=32; off; off>>=1){ s += __shfl_xor(s,off,64); q += __shfl_xor(q,off,64); }
    float mean = s*(1.f/192.f);
    float var  = q*(1.f/192.f) - mean*mean;
    float inv  = rsqrtf(var + 1e-6f);
    u16* orow = out + pix*192;
    orow[lane]     = f2b((x0-mean)*inv*g[lane]     + bta[lane]);
    orow[lane+64]  = f2b((x1-mean)*inv*g[lane+64]  + bta[lane+64]);
    orow[lane+128] = f2b((x2-mean)*inv*g[lane+128] + bta[lane+128]);
}

// ---------- bf16 MFMA GEMM: M-tile 128 (wave=32 rows), W-in-LDS once, A streamed ----------
#define GM_NONE 0
#define GM_RES 1
#define GM_GELU_BN 2
#define GM_BN_RES 3

template<int MODE, int K, int NT, bool SPLIT=false>
__global__ __launch_bounds__(256) void gemm_bf16_k(
    const u16* __restrict__ A, int lda,
    const u16* __restrict__ A2, int lda2,
    const u16* __restrict__ W,
    void* __restrict__ Cv, int ldc,
    const u16* __restrict__ R, int ldr,
    const float* __restrict__ bg, const float* __restrict__ bb,
    const float* __restrict__ bm_, const float* __restrict__ bv,
    int N)
{
    constexpr int LSTR = (K==96) ? 104 : ((K==192) ? 200 : 264);  // stride%32dw==4
    constexpr int NF = NT/16;
    __shared__ u16 Ws[NT*LSTR];
    int t = threadIdx.x;
    int bn = blockIdx.y * NT;
    int bm = blockIdx.x * 128;
    {
        constexpr int K8 = K/8;
        for (int i = t; i < NT*K8; i += 256){
            int row = i / K8, j = (i % K8)*8;
            int n = bn + row;
            short8v v = {};
            if (n < N) v = *(const short8v*)(W + (size_t)n*K + j);
            *(short8v*)&Ws[row*LSTR + j] = v;
        }
    }
    __syncthreads();
    int wave = t >> 6, lane = t & 63;
    int wm = wave*32;
    int lr = lane & 15, lk = lane >> 4;
    const u16* arow  = A + (size_t)(bm + wm + lr)*lda + lk*8;
    const u16* arow2 = SPLIT ? (A2 + (size_t)(bm + wm + lr)*lda2 + lk*8) : nullptr;
    floatx4 acc[2][NF] = {};
    #pragma unroll
    for (int k0 = 0; k0 < K; k0 += 32){
        short8v afr[2];
        if (SPLIT && k0 >= 96){
            #pragma unroll
            for (int m=0;m<2;m++)
                afr[m] = *(const short8v*)(arow2 + (size_t)(m*16)*lda2 + (k0-96));
        } else {
            #pragma unroll
            for (int m=0;m<2;m++)
                afr[m] = *(const short8v*)(arow + (size_t)(m*16)*lda + k0);
        }
        #pragma unroll
        for (int n2=0;n2<NF;n2++){
            short8v bfr = *(const short8v*)&Ws[(n2*16+lr)*LSTR + k0 + lk*8];
            #pragma unroll
            for (int m=0;m<2;m++)
                acc[m][n2] = __builtin_amdgcn_mfma_f32_16x16x32_bf16(afr[m], bfr, acc[m][n2], 0,0,0);
        }
    }
    #pragma unroll
    for (int m=0;m<2;m++){
        #pragma unroll
        for (int n2=0;n2<NF;n2++){
            int gcol = bn + n2*16 + lr;
            if (gcol >= N) continue;
            float bscale = 0.f, bmv = 0.f, bbv = 0.f;
            if (MODE == GM_GELU_BN || MODE == GM_BN_RES){
                bscale = rsqrtf(bv[gcol]+1e-5f)*bg[gcol];
                bmv = bm_[gcol]; bbv = bb[gcol];
            }
            #pragma unroll
            for (int rg=0; rg<4; rg++){
                int grow = bm + wm + m*16 + lk*4 + rg;
                float v = acc[m][n2][rg];
                if (MODE == GM_RES){
                    v += b2f(R[(size_t)grow*ldr + gcol]);
                    ((u16*)Cv)[(size_t)grow*ldc + gcol] = f2b(v);
                } else if (MODE == GM_BN_RES){
                    float bnv = (v - bmv)*bscale + bbv;
                    ((float*)Cv)[(size_t)grow*ldc + gcol] = bnv + b2f(R[(size_t)grow*ldr + gcol]);
                } else if (MODE == GM_GELU_BN){
                    float gl = gelu_fast(v);
                    v = (gl - bmv)*bscale + bbv;
                    ((u16*)Cv)[(size_t)grow*ldc + gcol] = f2b(v);
                } else {
                    ((u16*)Cv)[(size_t)grow*ldc + gcol] = f2b(v);
                }
            }
        }
    }
}

// ---------- fused gate GEMM (M-tile 128, two-panel A): gpix = sigmoid(relu(Y@gw1^T+gb1).w2+b2) ----------
#define GSTR 200
__global__ __launch_bounds__(256) void gate_gemm_k(
    const u16* __restrict__ A0, const u16* __restrict__ A1,   // Y planes, lda=96
    const u16* __restrict__ W,
    const float* __restrict__ gb1, const float* __restrict__ w2,
    const float* __restrict__ b2, float* __restrict__ gpix)
{
    __shared__ u16 Ws[96*GSTR];
    int t = threadIdx.x;
    int bm = blockIdx.x * 128;
    for (int i = t; i < 96*24; i += 256){
        int row = i/24, j = (i%24)*8;
        *(short8v*)&Ws[row*GSTR + j] = *(const short8v*)(W + (size_t)row*192 + j);
    }
    __syncthreads();
    int wave = t >> 6, lane = t & 63;
    int wm = wave*32;
    int lr = lane & 15, lk = lane >> 4;
    const u16* arow0 = A0 + (size_t)(bm + wm + lr)*96 + lk*8;
    const u16* arow1 = A1 + (size_t)(bm + wm + lr)*96 + lk*8;
    floatx4 acc[2][6] = {};
    #pragma unroll
    for (int k0 = 0; k0 < 192; k0 += 32){
        short8v afr[2];
        if (k0 >= 96){
            #pragma unroll
            for (int m=0;m<2;m++)
                afr[m] = *(const short8v*)(arow1 + (size_t)(m*16)*96 + (k0-96));
        } else {
            #pragma unroll
            for (int m=0;m<2;m++)
                afr[m] = *(const short8v*)(arow0 + (size_t)(m*16)*96 + k0);
        }
        #pragma unroll
        for (int n2=0;n2<6;n2++){
            short8v bfr = *(const short8v*)&Ws[(n2*16+lr)*GSTR + k0 + lk*8];
            #pragma unroll
            for (int m=0;m<2;m++)
                acc[m][n2] = __builtin_amdgcn_mfma_f32_16x16x32_bf16(afr[m], bfr, acc[m][n2], 0,0,0);
        }
    }
    float gbv[6], w2v[6];
    #pragma unroll
    for (int n2=0;n2<6;n2++){ int col = n2*16 + lr; gbv[n2] = gb1[col]; w2v[n2] = w2[col]; }
    float b2s = b2[0];
    #pragma unroll
    for (int m=0;m<2;m++){
        #pragma unroll
        for (int rg=0;rg<4;rg++){
            float part = 0.f;
            #pragma unroll
            for (int n2=0;n2<6;n2++){
                float v = fmaxf(acc[m][n2][rg] + gbv[n2], 0.f);
                part = fmaf(v, w2v[n2], part);
            }
            #pragma unroll
            for (int off=1; off<16; off<<=1) part += __shfl_xor(part, off, 64);
            if (lr == 0){
                int row = bm + wm + m*16 + lk*4 + rg;
                gpix[row] = 1.f/(1.f+expf(-(part + b2s)));
            }
        }
    }
}

// ---------- deterministic mean of gpix -> dyn_k ----------
__global__ __launch_bounds__(1024) void gate_reduce_k(const float* __restrict__ gpix,
                                                      float* __restrict__ dynk)
{
    __shared__ float sm[16];
    float s = 0.f;
    for (int i=threadIdx.x; i<NPIX; i+=1024) s += gpix[i];
    #pragma unroll
    for (int off=32; off; off>>=1) s += __shfl_xor(s,off,64);
    int wid = threadIdx.x>>6, lane = threadIdx.x&63;
    if (lane==0) sm[wid]=s;
    __syncthreads();
    if (threadIdx.x==0){
        float tot=0.f; for (int i=0;i<16;i++) tot+=sm[i];
        *dynk = floorf(12.0f * (tot/(float)NPIX));
    }
}

// ---------- qkv depthwise 3x3 (288 ch), 4-col sweep, LDS weights, XCD-swizzled ----------
#define QPOS(c8) ((c8)*8 + ((c8)>>2)*4)
#define QTAPSTRIDE 324
__global__ __launch_bounds__(256) void qkv_dw_k(const u16* __restrict__ in,
    const float* __restrict__ w, u16* __restrict__ out, size_t planeStride)
{
    __shared__ float wlds[9*QTAPSTRIDE];
    int t = threadIdx.x;
    for (int i=t; i<2592; i+=256){
        int tap = i/288, cc = i%288;
        wlds[tap*QTAPSTRIDE + QPOS(cc>>3) + (cc&7)] = w[cc*9+tap];
    }
    __syncthreads();
    int bid = blockIdx.x;
    int sb = (bid & 7)*(gridDim.x >> 3) + (bid >> 3);
    int idx = sb*256 + t;
    int c8 = idx % 36; int pq = idx / 36;
    int xg = pq & 31; int hy = (pq >> 5) & 127; int img = pq >> 12;
    int x0 = xg*4;
    int c0 = c8*8;
    int wofs = QPOS(c8);
    float acc[4][8] = {{0.f}};
    #pragma unroll
    for (int ky=0; ky<3; ky++){
        int hh = hy + ky - 1; if ((unsigned)hh >= HH) continue;
        float wr[3][8];
        #pragma unroll
        for (int kx=0; kx<3; kx++){
            floatx4 wa = *(const floatx4*)&wlds[(ky*3+kx)*QTAPSTRIDE + wofs];
            floatx4 wb = *(const floatx4*)&wlds[(ky*3+kx)*QTAPSTRIDE + wofs + 4];
            #pragma unroll
            for (int j=0;j<4;j++){ wr[kx][j]=wa[j]; wr[kx][4+j]=wb[j]; }
        }
        const u16* rowp = in + ((size_t)(img*HH+hh)*WW)*288 + c0;
        #pragma unroll
        for (int cc=0; cc<6; cc++){
            int cx = x0 - 1 + cc;
            if ((unsigned)cx >= WW) continue;
            short8v v = *(const short8v*)(rowp + (size_t)cx*288);
            float vf[8];
            #pragma unroll
            for (int j=0;j<8;j++) vf[j] = b2f((u16)v[j]);
            #pragma unroll
            for (int dx=0; dx<4; dx++){
                int kx = cc - dx;
                if (kx < 0 || kx >= 3) continue;
                #pragma unroll
                for (int j=0;j<8;j++) acc[dx][j] = fmaf(wr[kx][j], vf[j], acc[dx][j]);
            }
        }
    }
    size_t pix0 = (size_t)(img*HH+hy)*WW + x0;
    int sec = c0/96, qc0 = c0 - sec*96;
    u16* outp = out + (size_t)sec*planeStride + qc0;
    #pragma unroll
    for (int dx=0; dx<4; dx++){
        short8v o;
        #pragma unroll
        for (int j=0;j<8;j++) o[j] = (short)f2b(acc[dx][j]);
        *(short8v*)(outp + (pix0+dx)*96) = o;
    }
}

// ---------- Gram partials per (img,head,slice), Q/K planes, vectorized staging ----------
__global__ __launch_bounds__(256) void gram_k(const u16* __restrict__ Qp,
    const u16* __restrict__ Kp, float* __restrict__ part)
{
    int bh = blockIdx.x;
    int slice = blockIdx.y;
    int img = bh >> 3, h = bh & 7;
    const u16* Qb = Qp + (size_t)img*HW*96 + h*12;
    const u16* Kb = Kp + (size_t)img*HW*96 + h*12;
    __shared__ float qs[64][12];
    __shared__ float ks[64][12];
    int t = threadIdx.x;
    float acc = 0.f;
    int c = (t<144) ? t/12 : (t<156 ? t-144 : t-156);
    int d = (t<144) ? t%12 : 0;
    for (int st=0; st<16; st++){
        int pix0 = slice*1024 + st*64;
        __syncthreads();
        for (int i=t; i<384; i+=256){
            int p = i/6, j = i%6;
            const u16* src = (j<3) ? (Qb + (size_t)(pix0+p)*96 + j*4)
                                   : (Kb + (size_t)(pix0+p)*96 + (j-3)*4);
            short4v v = *(const short4v*)src;
            float f0=b2f((u16)v.x), f1=b2f((u16)v.y), f2=b2f((u16)v.z), f3=b2f((u16)v.w);
            if (j<3){ int jj=j*4;     qs[p][jj]=f0; qs[p][jj+1]=f1; qs[p][jj+2]=f2; qs[p][jj+3]=f3; }
            else    { int jj=(j-3)*4; ks[p][jj]=f0; ks[p][jj+1]=f1; ks[p][jj+2]=f2; ks[p][jj+3]=f3; }
        }
        __syncthreads();
        if (t<144){        for (int p=0;p<64;p++) acc = fmaf(qs[p][c], ks[p][d], acc); }
        else if (t<156){   for (int p=0;p<64;p++) acc = fmaf(qs[p][c], qs[p][c], acc); }
        else if (t<168){   for (int p=0;p<64;p++) acc = fmaf(ks[p][c], ks[p][c], acc); }
    }
    if (t<168) part[((size_t)bh*16 + slice)*168 + t] = acc;
}

__global__ __launch_bounds__(256) void gram_combine_k(const float* __restrict__ part,
                                                      float* __restrict__ gram, int n)
{
    int i = blockIdx.x*256 + threadIdx.x;
    if (i >= n) return;
    int bh = i/168, t = i%168;
    float s = 0.f;
    for (int sl=0; sl<16; sl++) s += part[((size_t)bh*16+sl)*168 + t];
    gram[i] = s;
}

// ---------- attn 12x12: normalize, temperature, top-k mask, softmax ----------
__global__ __launch_bounds__(256) void attn_k(const float* __restrict__ gram,
    const float* __restrict__ temp, const float* __restrict__ dynk_p,
    const float* __restrict__ a1, const float* __restrict__ a2,
    const float* __restrict__ a3, const float* __restrict__ a4,
    float* __restrict__ attnW)
{
    int bh = blockIdx.x;
    int h = bh & 7;
    __shared__ float av[12][12];
    __shared__ float mv[12][12];
    __shared__ float nq[12], nk[12];
    int t = threadIdx.x;
    if (t < 12) nq[t] = fmaxf(sqrtf(gram[bh*168+144+t]), 1e-12f);
    else if (t < 24) nk[t-12] = fmaxf(sqrtf(gram[bh*168+156+(t-12)]), 1e-12f);
    __syncthreads();
    if (t < 144){
        int c=t/12, d=t%12;
        av[c][d] = gram[bh*168+t] / (nq[c]*nk[d]) * temp[h];
    }
    __syncthreads();
    float dk = *dynk_p;
    if (t < 144){
        int c=t/12, d=t%12; float v = av[c][d];
        int r = 0;
        #pragma unroll
        for (int j=0;j<12;j++){
            float o = av[c][j];
            r += (o > v) ? 1 : ((o == v && j < d) ? 1 : 0);
        }
        mv[c][d] = ((float)r < dk) ? v : -INFINITY;
    }
    __syncthreads();
    if (t < 12){
        float mx = -INFINITY;
        for (int d2=0; d2<12; d2++) mx = fmaxf(mx, mv[t][d2]);
        float e[12]; float s = 0.f;
        for (int d2=0; d2<12; d2++){ e[d2] = expf(mv[t][d2]-mx); s += e[d2]; }
        float sc = (a1[0]+a2[0]+a3[0]+a4[0]) / s;
        for (int d2=0; d2<12; d2++) attnW[(size_t)bh*144 + t*12 + d2] = e[d2]*sc;
    }
}

// ---------- attn apply -> P96 bf16 (V plane input); thread = (pixel, head) ----------
__global__ __launch_bounds__(256) void attn_apply_k(const u16* __restrict__ Vp,
    const float* __restrict__ attnW, u16* __restrict__ P)
{
    int gid = blockIdx.x*256 + threadIdx.x;
    int h = gid % 8; size_t pix = (size_t)(gid / 8);
    int img = (int)(pix >> 14);
    const u16* vp = Vp + pix*96 + h*12;
    float vf[12];
    #pragma unroll
    for (int j=0;j<3;j++){
        short4v v = *(const short4v*)(vp + j*4);
        vf[j*4+0]=b2f((u16)v.x); vf[j*4+1]=b2f((u16)v.y);
        vf[j*4+2]=b2f((u16)v.z); vf[j*4+3]=b2f((u16)v.w);
    }
    const float* awb = attnW + ((size_t)(img*8+h))*144;
    u16 o[12];
    #pragma unroll
    for (int cc=0; cc<12; cc++){
        const float4* ap = (const float4*)(awb + cc*12);
        float4 a0 = ap[0], a1 = ap[1], a2 = ap[2];
        float s = a0.x*vf[0] + a0.y*vf[1] + a0.z*vf[2] + a0.w*vf[3]
                + a1.x*vf[4] + a1.y*vf[5] + a1.z*vf[6] + a1.w*vf[7]
                + a2.x*vf[8] + a2.y*vf[9] + a2.z*vf[10]+ a2.w*vf[11];
        o[cc] = f2b(s);
    }
    u16* op = P + pix*96 + h*12;
    *(short4v*)(op)   = *(short4v*)&o[0];
    *(short4v*)(op+4) = *(short4v*)&o[4];
    *(short4v*)(op+8) = *(short4v*)&o[8];
}

// ---------- FFN multi-scale depthwise, row-sweep; merged kernel, heaviest group FIRST ----------
template<int KS>
__device__ __forceinline__ void ffn_body(const u16* __restrict__ V0,
    const float* __restrict__ wsrc, const float* __restrict__ bsrc, int cbase,
    const float* __restrict__ bn2g, const float* __restrict__ bn2b,
    const float* __restrict__ bn2m, const float* __restrict__ bn2v,
    u16* __restrict__ U, float* wlds, float* bng, float* bnb, float* bnm, float* bnvr,
    int gridx)
{
    constexpr int PAD = KS/2;
    int t = threadIdx.x;
    for (int i=t; i<KS*KS*64; i+=256){
        int tap = i >> 6, cc = i & 63;
        wlds[tap*64 + cc] = wsrc[cc*KS*KS + tap];
    }
    if (t < 64){
        bng[t] = bn2g[cbase+t]; bnb[t] = bn2b[cbase+t];
        bnm[t] = bn2m[cbase+t]; bnvr[t] = rsqrtf(bn2v[cbase+t]+1e-5f);
    }
    __syncthreads();
    int ci = t & 7, seg = t >> 3;
    int bid = blockIdx.x;
    int rowid = (bid & 7)*(gridx >> 3) + (bid >> 3);
    int img = rowid >> 7, hy = rowid & 127;
    int c0r = ci*8;
    int c0 = cbase + c0r;
    int x0 = seg*4;
    float acc[4][8];
    {
        floatx4 b0 = *(const floatx4*)(bsrc + c0r);
        floatx4 b1 = *(const floatx4*)(bsrc + c0r + 4);
        #pragma unroll
        for (int dx=0;dx<4;dx++){
            #pragma unroll
            for (int j=0;j<4;j++){ acc[dx][j]=b0[j]; acc[dx][4+j]=b1[j]; }
        }
    }
    #pragma unroll
    for (int ky=0; ky<KS; ky++){
        int hh = hy + ky - PAD;
        if ((unsigned)hh >= HH) continue;
        float wr[KS][8];
        #pragma unroll
        for (int kx=0; kx<KS; kx++){
            floatx4 wa = *(const floatx4*)&wlds[(ky*KS+kx)*64 + c0r];
            floatx4 wb = *(const floatx4*)&wlds[(ky*KS+kx)*64 + c0r + 4];
            #pragma unroll
            for (int j=0;j<4;j++){ wr[kx][j]=wa[j]; wr[kx][4+j]=wb[j]; }
        }
        const u16* rowp = V0 + ((size_t)(img*HH+hh)*WW)*256 + c0;
        #pragma unroll
        for (int cc=0; cc<4+2*PAD; cc++){
            int cx = x0 - PAD + cc;
            if ((unsigned)cx >= WW) continue;
            short8v v = *(const short8v*)(rowp + (size_t)cx*256);
            float vf[8];
            #pragma unroll
            for (int j=0;j<8;j++) vf[j] = b2f((u16)v[j]);
            #pragma unroll
            for (int dx=0; dx<4; dx++){
                int kx = cc - dx;
                if (kx < 0 || kx >= KS) continue;
                #pragma unroll
                for (int j=0;j<8;j++) acc[dx][j] = fmaf(wr[kx][j], vf[j], acc[dx][j]);
            }
        }
    }
    size_t rbase = (size_t)(img*HH+hy)*WW;
    #pragma unroll
    for (int dx=0; dx<4; dx++){
        size_t pix = rbase + x0 + dx;
        short8v vc = *(const short8v*)(V0 + pix*256 + c0);
        short8v o;
        #pragma unroll
        for (int j=0;j<8;j++){
            float v0c = b2f((u16)vc[j]);
            float u1 = acc[dx][j] + v0c;
            float gl = gelu_fast(u1);
            float bn = (gl - bnm[c0r+j])*bnvr[c0r+j]*bng[c0r+j] + bnb[c0r+j];
            o[j] = (short)f2b(bn*v0c);
        }
        *(short8v*)(U + pix*256 + c0) = o;
    }
}

__global__ __launch_bounds__(256) void ffn_dw_all_k(const u16* __restrict__ V0,
    const float* __restrict__ w0, const float* __restrict__ bb0,
    const float* __restrict__ w1, const float* __restrict__ bb1,
    const float* __restrict__ w2, const float* __restrict__ bb2,
    const float* __restrict__ w3, const float* __restrict__ bb3,
    const float* __restrict__ bn2g, const float* __restrict__ bn2b,
    const float* __restrict__ bn2m, const float* __restrict__ bn2v,
    u16* __restrict__ U)
{
    __shared__ float wlds[49*64];
    __shared__ float bng[64], bnb[64], bnm[64], bnvr[64];
    int gx = gridDim.x;
    // heaviest group first: y=0 -> 7x7 so its blocks dispatch before the cheap groups
    switch(blockIdx.y){
        case 0: ffn_body<7>(V0, w3, bb3, 192, bn2g,bn2b,bn2m,bn2v, U, wlds,bng,bnb,bnm,bnvr, gx); break;
        case 1: ffn_body<5>(V0, w2, bb2, 128, bn2g,bn2b,bn2m,bn2v, U, wlds,bng,bnb,bnm,bnvr, gx); break;
        case 2: ffn_body<3>(V0, w1, bb1, 64,  bn2g,bn2b,bn2m,bn2v, U, wlds,bng,bnb,bnm,bnvr, gx); break;
        default: ffn_body<1>(V0, w0, bb0, 0,  bn2g,bn2b,bn2m,bn2v, U, wlds,bng,bnb,bnm,bnvr, gx); break;
    }
}

extern "C" void kernel_launch(void* const* d_in, const int* in_sizes, int n_in,
                              void* d_out, int out_size, void* d_ws, size_t ws_size,
                              hipStream_t stream)
{
    const float* x     = (const float*)d_in[0];
    const float* pos_w = (const float*)d_in[1];
    const float* pos_b = (const float*)d_in[2];
    const float* ln1g  = (const float*)d_in[3];
    const float* ln1b  = (const float*)d_in[4];
    const float* temp  = (const float*)d_in[5];
    const float* qkvw  = (const float*)d_in[6];
    const float* qkvdw = (const float*)d_in[7];
    const float* projw = (const float*)d_in[8];
    const float* gw1   = (const float*)d_in[9];
    const float* gb1   = (const float*)d_in[10];
    const float* gw2   = (const float*)d_in[11];
    const float* gb2   = (const float*)d_in[12];
    const float* a1    = (const float*)d_in[13];
    const float* a2    = (const float*)d_in[14];
    const float* a3    = (const float*)d_in[15];
    const float* a4    = (const float*)d_in[16];
    const float* ln2g  = (const float*)d_in[17];
    const float* ln2b  = (const float*)d_in[18];
    const float* fc1w  = (const float*)d_in[19];
    const float* bn1g  = (const float*)d_in[20];
    const float* bn1b  = (const float*)d_in[21];
    const float* bn1m  = (const float*)d_in[22];
    const float* bn1v  = (const float*)d_in[23];
    const float* bn2g  = (const float*)d_in[24];
    const float* bn2b  = (const float*)d_in[25];
    const float* bn2m  = (const float*)d_in[26];
    const float* bn2v  = (const float*)d_in[27];
    const float* fc2w  = (const float*)d_in[28];
    const float* bn3g  = (const float*)d_in[29];
    const float* bn3b  = (const float*)d_in[30];
    const float* bn3m  = (const float*)d_in[31];
    const float* bn3v  = (const float*)d_in[32];
    const float* dw0w  = (const float*)d_in[33];
    const float* dw0b  = (const float*)d_in[34];
    const float* dw1w  = (const float*)d_in[35];
    const float* dw1b  = (const float*)d_in[36];
    const float* dw2w  = (const float*)d_in[37];
    const float* dw2b  = (const float*)d_in[38];
    const float* dw3w  = (const float*)d_in[39];
    const float* dw3b  = (const float*)d_in[40];

    float* OUT = (float*)d_out;      // final fp32 output (written once by fc2)

    // ---- fixed small buffers + bf16 residual stream A ----
    char* p = (char*)d_ws;
    float* gpix  = (float*)p;                 p += (size_t)NPIX*4;
    float* dynk  = (float*)p;                 p += 256;
    float* gpart = (float*)p;                 p += 64*16*168*4;
    float* gram  = (float*)p;                 p += 64*168*4;
    float* attnW = (float*)p;                 p += 64*144*4;
    float* wposT = (float*)p;                 p += 1728*4;
    u16*   wbf   = (u16*)p;                   p += (size_t)WTOT*2;
    u16*   Abf   = (u16*)p;                   p += (size_t)NPIX*192*2;   // 50.3 MB
    size_t fixedB = (size_t)(p - (char*)d_ws);

    // ---- choose chunk size from ws_size: per-image = Y(192)+B1(288)+B2(288) bf16 ----
    size_t perImg = (size_t)HW*2*(192+288+288);   // 25,165,824
    int CBr = 2;
    if (ws_size >= fixedB + 8*perImg) CBr = 8;
    else if (ws_size >= fixedB + 4*perImg) CBr = 4;
    int NCHUNKr = BB/CBr;
    size_t CHWr = (size_t)CBr*HW;

    u16* Ybf = (u16*)p;                   p += CHWr*192*2;   // two 96-ch planes
    u16* B1  = (u16*)p;                   p += CHWr*288*2;
    u16* B2  = (u16*)p;
    u16* Y0  = Ybf;
    u16* Y1  = Ybf + CHWr*96;
    u16* qkvwb = wbf;
    u16* projwb= wbf + WQ;
    u16* gw1b  = wbf + WQ + WP;
    u16* fc1b  = wbf + WQ + WP + WG;
    u16* fc2b  = wbf + WQ + WP + WG + WF1;
    u16* QKVbf = B1;     // qkv out (288 interleaved)
    u16* QKVdbf= B2;     // qkv_dw out: Q|K|V planes of CHWr*96 each
    u16* P96   = B1;     // attn out (QKV dead)
    u16* Zbf   = B2;     // LN2 out (QKVd dead)
    u16* V0bf  = B1;     // fc1 out (P96 dead)
    u16* Ubf   = B2;     // ffn out (Z dead)

    wprep_k<<<(WTOT+255)/256, 256, 0, stream>>>(qkvw, projw, gw1, fc1w, fc2w,
                                                pos_w, wbf, wposT);
    pos_conv_k<<<NPIX/8, 192, 0, stream>>>(x, wposT, pos_b, Abf);

    // gate phase: LN1 (split planes) -> fused gate GEMM -> gpix
    for (int c=0; c<NCHUNKr; c++){
        const u16* Ab = Abf + (size_t)c*CHWr*192;
        ln_split_k<<<CHWr/4, 256, 0, stream>>>(Ab, ln1g, ln1b, Y0, Y1);
        gate_gemm_k<<<CHWr/128, 256, 0, stream>>>(Y0, Y1, gw1b, gb1, gw2, gb2,
                                                  gpix + (size_t)c*CHWr);
    }
    gate_reduce_k<<<1, 1024, 0, stream>>>(gpix, dynk);

    // main phase
    for (int c=0; c<NCHUNKr; c++){
        u16* Ab = Abf + (size_t)c*CHWr*192;
        if (NCHUNKr > 1)   // single-chunk mode: Y planes from gate phase still valid
            ln_split_k<<<CHWr/4, 256, 0, stream>>>(Ab, ln1g, ln1b, Y0, Y1);
        {   // qkv 1x1: A = dense Y0 plane (K=96), N=288 = 3 x 96-tiles
            dim3 g(CHWr/128, 3);
            gemm_bf16_k<GM_NONE,96,96><<<g, 256, 0, stream>>>(Y0, 96, nullptr, 0,
                qkvwb, QKVbf, 288, nullptr, 0, nullptr,nullptr,nullptr,nullptr, 288);
        }
        size_t pstr = CHWr*96;
        qkv_dw_k<<<CHWr/4*36/256, 256, 0, stream>>>(QKVbf, qkvdw, QKVdbf, pstr);
        { dim3 g(CBr*8, 16); gram_k<<<g, 256, 0, stream>>>(QKVdbf, QKVdbf + pstr, gpart); }
        gram_combine_k<<<(CBr*8*168+255)/256, 256, 0, stream>>>(gpart, gram, CBr*8*168);
        attn_k<<<CBr*8, 256, 0, stream>>>(gram, temp, dynk, a1,a2,a3,a4, attnW);
        attn_apply_k<<<CHWr*8/256, 256, 0, stream>>>(QKVdbf + 2*pstr, attnW, P96);
        {   // proj + residual: A-panels = P96 | Y1 (both dense 96-wide)
            dim3 g(CHWr/128, 2);
            gemm_bf16_k<GM_RES,192,96,true><<<g, 256, 0, stream>>>(P96, 96, Y1, 96,
                projwb, Ab, 192, Ab, 192, nullptr,nullptr,nullptr,nullptr, 192);
        }
        ln_k<<<CHWr/4, 256, 0, stream>>>(Ab, ln2g, ln2b, Zbf);
        {   // fc1: N=256 = 4 x 64-tiles
            dim3 g(CHWr/128, 4);
            gemm_bf16_k<GM_GELU_BN,192,64><<<g, 256, 0, stream>>>(Zbf, 192, nullptr, 0,
                fc1b, V0bf, 256, nullptr, 0, bn1g,bn1b,bn1m,bn1v, 256);
        }
        {   // multi-scale depthwise, heaviest-first merged launch
            int rows = (int)(CHWr/WW);
            dim3 g(rows, 4);
            ffn_dw_all_k<<<g, 256, 0, stream>>>(V0bf, dw0w,dw0b,dw1w,dw1b,dw2w,dw2b,
                                                dw3w,dw3b, bn2g,bn2b,bn2m,bn2v, Ubf);
        }
        {   // fc2 + bn3 + residual -> fp32 OUT: N=192 = 2 x 96-tiles
            dim3 g(CHWr/128, 2);
            gemm_bf16_k<GM_BN_RES,256,96><<<g, 256, 0, stream>>>(Ubf, 256, nullptr, 0,
                fc2b, OUT + (size_t)c*CHWr*192, 192, Ab, 192, bn3g,bn3b,bn3m,bn3v, 192);
        }
    }
}

// Round 22
// 577.936 us; speedup vs baseline: 1.1347x; 1.0089x over previous
//
#include <hip/hip_runtime.h>
#include <hip/hip_bf16.h>
#include <math.h>

#define BB 8
#define HH 128
#define WW 128
#define HW (HH*WW)          // 16384
#define NPIX (BB*HW)        // 131072

typedef unsigned short u16;
typedef __attribute__((ext_vector_type(4))) float  floatx4;
typedef __attribute__((ext_vector_type(4))) short  short4v;
typedef __attribute__((ext_vector_type(8))) short  short8v;

static __device__ __forceinline__ float gelu_fast(float x){
    float u = 0.7978845608028654f*(x + 0.044715f*x*x*x);
    float e = __expf(2.f*u);
    float th = 1.f - 2.f/(e + 1.f);
    return 0.5f*x*(1.f + th);
}
static __device__ __forceinline__ float b2f(u16 v){
    union { unsigned u; float f; } x; x.u = ((unsigned)v)<<16; return x.f;
}
static __device__ __forceinline__ u16 f2b(float f){
    __hip_bfloat16 h = __float2bfloat16(f);
    return *(u16*)&h;
}

// ---------- weight prep: fp32 -> bf16 GEMM weights + transposed pos weights ----------
#define WQ 27648
#define WP 36864
#define WG 18432
#define WF1 49152
#define WF2 49152
#define WTOT (WQ+WP+WG+WF1+WF2)   // 181248
__global__ __launch_bounds__(256) void wprep_k(const float* __restrict__ a,
    const float* __restrict__ b, const float* __restrict__ c,
    const float* __restrict__ d, const float* __restrict__ e,
    const float* __restrict__ posw, u16* __restrict__ o, float* __restrict__ wT)
{
    int i = blockIdx.x*256 + threadIdx.x;
    if (i < 1728){   // wT[tap][192]: wT[tap*192+c] = posw[c*9+tap]
        wT[i] = posw[(i%192)*9 + (i/192)];
    }
    if (i >= WTOT) return;
    float v;
    if (i < WQ) v = a[i];
    else if (i < WQ+WP) v = b[i-WQ];
    else if (i < WQ+WP+WG) v = c[i-WQ-WP];
    else if (i < WQ+WP+WG+WF1) v = d[i-WQ-WP-WG];
    else v = e[i-WQ-WP-WG-WF1];
    o[i] = f2b(v);
}

// ---------- pos depthwise 3x3 + bias + residual -> bf16 A; LDS halo, 2 px/thread ----------
__global__ __launch_bounds__(192) void pos_conv_k(const float* __restrict__ x,
    const float* __restrict__ wT, const float* __restrict__ bias, u16* __restrict__ out)
{
    __shared__ float4 lds[3][10][48];
    int bid = blockIdx.x;
    int sb = (bid & 7)*(gridDim.x >> 3) + (bid >> 3);   // XCD image-slice swizzle
    int t = threadIdx.x;
    int unit = sb;                       // over NPIX/8 column-octets
    int x0 = (unit & 15)*8;
    int hy = (unit >> 4) & 127;
    int b  = unit >> 11;

    const float4* x4 = (const float4*)x;
    float4 z4 = make_float4(0.f,0.f,0.f,0.f);
    for (int i = t; i < 1440; i += 192){
        int c4s = i % 48;
        int rc  = i / 48;
        int r   = rc / 10;
        int cp  = rc % 10;
        int hh  = hy + r - 1;
        int cx  = x0 + cp - 1;
        float4 v = z4;
        if ((unsigned)hh < HH && (unsigned)cx < WW)
            v = x4[((size_t)(b*HH+hh)*WW + cx)*48 + c4s];
        lds[r][cp][c4s] = v;
    }
    __syncthreads();

    int c4 = t % 48;
    int p0 = (t / 48)*2;
    int c0 = c4*4;
    floatx4 wv[9];
    #pragma unroll
    for (int tap=0; tap<9; tap++)
        wv[tap] = *(const floatx4*)&wT[tap*192 + c0];

    float4 xv[3][4];
    #pragma unroll
    for (int i=0;i<3;i++)
        #pragma unroll
        for (int k=0;k<4;k++)
            xv[i][k] = lds[i][p0+k][c4];

    float4 bias4 = *(const float4*)(bias + c0);
    float4 acc0 = bias4, acc1 = bias4;
    #pragma unroll
    for (int i=0;i<3;i++){
        #pragma unroll
        for (int k=0;k<3;k++){
            floatx4 w = wv[i*3+k];
            float4 a = xv[i][k];
            float4 bqq = xv[i][k+1];
            acc0.x = fmaf(w[0], a.x, acc0.x);
            acc0.y = fmaf(w[1], a.y, acc0.y);
            acc0.z = fmaf(w[2], a.z, acc0.z);
            acc0.w = fmaf(w[3], a.w, acc0.w);
            acc1.x = fmaf(w[0], bqq.x, acc1.x);
            acc1.y = fmaf(w[1], bqq.y, acc1.y);
            acc1.z = fmaf(w[2], bqq.z, acc1.z);
            acc1.w = fmaf(w[3], bqq.w, acc1.w);
        }
    }
    float4 xc0 = xv[1][1];
    float4 xc1 = xv[1][2];
    acc0.x += xc0.x; acc0.y += xc0.y; acc0.z += xc0.z; acc0.w += xc0.w;
    acc1.x += xc1.x; acc1.y += xc1.y; acc1.z += xc1.z; acc1.w += xc1.w;

    size_t pix0 = (size_t)(b*HH + hy)*WW + x0 + p0;
    short4v o0, o1;
    o0.x=(short)f2b(acc0.x); o0.y=(short)f2b(acc0.y);
    o0.z=(short)f2b(acc0.z); o0.w=(short)f2b(acc0.w);
    o1.x=(short)f2b(acc1.x); o1.y=(short)f2b(acc1.y);
    o1.z=(short)f2b(acc1.z); o1.w=(short)f2b(acc1.w);
    *(short4v*)(out + pix0*192 + c0) = o0;
    *(short4v*)(out + (pix0+1)*192 + c0) = o1;
}

// ---------- LayerNorm over C=192, bf16 in -> split Y0|Y1 planes (96 ch each) ----------
__global__ __launch_bounds__(256) void ln_split_k(const u16* __restrict__ in,
    const float* __restrict__ g, const float* __restrict__ bta,
    u16* __restrict__ y0, u16* __restrict__ y1)
{
    int wid = threadIdx.x >> 6, lane = threadIdx.x & 63;
    size_t pix = (size_t)blockIdx.x*4 + wid;
    const u16* row = in + pix*192;
    float x0 = b2f(row[lane]), x1 = b2f(row[lane+64]), x2 = b2f(row[lane+128]);
    float s = x0+x1+x2;
    float q = x0*x0 + x1*x1 + x2*x2;
    #pragma unroll
    for (int off=32; off; off>>=1){ s += __shfl_xor(s,off,64); q += __shfl_xor(q,off,64); }
    float mean = s*(1.f/192.f);
    float var  = q*(1.f/192.f) - mean*mean;
    float inv  = rsqrtf(var + 1e-6f);
    y0[pix*96 + lane] = f2b((x0-mean)*inv*g[lane] + bta[lane]);
    int c1 = lane + 64;
    u16 v1 = f2b((x1-mean)*inv*g[c1] + bta[c1]);
    if (c1 < 96) y0[pix*96 + c1] = v1;
    else         y1[pix*96 + c1 - 96] = v1;
    int c2 = lane + 128;
    y1[pix*96 + c2 - 96] = f2b((x2-mean)*inv*g[c2] + bta[c2]);
}

// ---------- LayerNorm over C=192, bf16 in -> contiguous bf16 out (LN2) ----------
__global__ __launch_bounds__(256) void ln_k(const u16* __restrict__ in,
    const float* __restrict__ g, const float* __restrict__ bta, u16* __restrict__ out)
{
    int wid = threadIdx.x >> 6, lane = threadIdx.x & 63;
    size_t pix = (size_t)blockIdx.x*4 + wid;
    const u16* row = in + pix*192;
    float x0 = b2f(row[lane]), x1 = b2f(row[lane+64]), x2 = b2f(row[lane+128]);
    float s = x0+x1+x2;
    float q = x0*x0 + x1*x1 + x2*x2;
    #pragma unroll
    for (int off=32; off; off>>=1){ s += __shfl_xor(s,off,64); q += __shfl_xor(q,off,64); }
    float mean = s*(1.f/192.f);
    float var  = q*(1.f/192.f) - mean*mean;
    float inv  = rsqrtf(var + 1e-6f);
    u16* orow = out + pix*192;
    orow[lane]     = f2b((x0-mean)*inv*g[lane]     + bta[lane]);
    orow[lane+64]  = f2b((x1-mean)*inv*g[lane+64]  + bta[lane+64]);
    orow[lane+128] = f2b((x2-mean)*inv*g[lane+128] + bta[lane+128]);
}

// ---------- bf16 MFMA GEMM: M-tile 128 (wave=32 rows), W-in-LDS once, A streamed ----------
#define GM_NONE 0
#define GM_RES 1
#define GM_GELU_BN 2
#define GM_BN_RES 3

template<int MODE, int K, int NT, bool SPLIT=false>
__global__ __launch_bounds__(256) void gemm_bf16_k(
    const u16* __restrict__ A, int lda,
    const u16* __restrict__ A2, int lda2,
    const u16* __restrict__ W,
    void* __restrict__ Cv, int ldc,
    const u16* __restrict__ R, int ldr,
    const float* __restrict__ bg, const float* __restrict__ bb,
    const float* __restrict__ bm_, const float* __restrict__ bv,
    int N)
{
    constexpr int LSTR = (K==96) ? 104 : ((K==192) ? 200 : 264);  // stride%32dw==4
    constexpr int NF = NT/16;
    __shared__ u16 Ws[NT*LSTR];
    int t = threadIdx.x;
    int bn = blockIdx.y * NT;
    int bm = blockIdx.x * 128;
    {
        constexpr int K8 = K/8;
        for (int i = t; i < NT*K8; i += 256){
            int row = i / K8, j = (i % K8)*8;
            int n = bn + row;
            short8v v = {};
            if (n < N) v = *(const short8v*)(W + (size_t)n*K + j);
            *(short8v*)&Ws[row*LSTR + j] = v;
        }
    }
    __syncthreads();
    int wave = t >> 6, lane = t & 63;
    int wm = wave*32;
    int lr = lane & 15, lk = lane >> 4;
    const u16* arow  = A + (size_t)(bm + wm + lr)*lda + lk*8;
    const u16* arow2 = SPLIT ? (A2 + (size_t)(bm + wm + lr)*lda2 + lk*8) : nullptr;
    floatx4 acc[2][NF] = {};
    #pragma unroll
    for (int k0 = 0; k0 < K; k0 += 32){
        short8v afr[2];
        if (SPLIT && k0 >= 96){
            #pragma unroll
            for (int m=0;m<2;m++)
                afr[m] = *(const short8v*)(arow2 + (size_t)(m*16)*lda2 + (k0-96));
        } else {
            #pragma unroll
            for (int m=0;m<2;m++)
                afr[m] = *(const short8v*)(arow + (size_t)(m*16)*lda + k0);
        }
        #pragma unroll
        for (int n2=0;n2<NF;n2++){
            short8v bfr = *(const short8v*)&Ws[(n2*16+lr)*LSTR + k0 + lk*8];
            #pragma unroll
            for (int m=0;m<2;m++)
                acc[m][n2] = __builtin_amdgcn_mfma_f32_16x16x32_bf16(afr[m], bfr, acc[m][n2], 0,0,0);
        }
    }
    #pragma unroll
    for (int m=0;m<2;m++){
        #pragma unroll
        for (int n2=0;n2<NF;n2++){
            int gcol = bn + n2*16 + lr;
            if (gcol >= N) continue;
            float bscale = 0.f, bmv = 0.f, bbv = 0.f;
            if (MODE == GM_GELU_BN || MODE == GM_BN_RES){
                bscale = rsqrtf(bv[gcol]+1e-5f)*bg[gcol];
                bmv = bm_[gcol]; bbv = bb[gcol];
            }
            #pragma unroll
            for (int rg=0; rg<4; rg++){
                int grow = bm + wm + m*16 + lk*4 + rg;
                float v = acc[m][n2][rg];
                if (MODE == GM_RES){
                    v += b2f(R[(size_t)grow*ldr + gcol]);
                    ((u16*)Cv)[(size_t)grow*ldc + gcol] = f2b(v);
                } else if (MODE == GM_BN_RES){
                    float bnv = (v - bmv)*bscale + bbv;
                    ((float*)Cv)[(size_t)grow*ldc + gcol] = bnv + b2f(R[(size_t)grow*ldr + gcol]);
                } else if (MODE == GM_GELU_BN){
                    float gl = gelu_fast(v);
                    v = (gl - bmv)*bscale + bbv;
                    ((u16*)Cv)[(size_t)grow*ldc + gcol] = f2b(v);
                } else {
                    ((u16*)Cv)[(size_t)grow*ldc + gcol] = f2b(v);
                }
            }
        }
    }
}

// ---------- fused gate GEMM (M-tile 128, two-panel A): gpix = sigmoid(relu(Y@gw1^T+gb1).w2+b2) ----------
#define GSTR 200
__global__ __launch_bounds__(256) void gate_gemm_k(
    const u16* __restrict__ A0, const u16* __restrict__ A1,   // Y planes, lda=96
    const u16* __restrict__ W,
    const float* __restrict__ gb1, const float* __restrict__ w2,
    const float* __restrict__ b2, float* __restrict__ gpix)
{
    __shared__ u16 Ws[96*GSTR];
    int t = threadIdx.x;
    int bm = blockIdx.x * 128;
    for (int i = t; i < 96*24; i += 256){
        int row = i/24, j = (i%24)*8;
        *(short8v*)&Ws[row*GSTR + j] = *(const short8v*)(W + (size_t)row*192 + j);
    }
    __syncthreads();
    int wave = t >> 6, lane = t & 63;
    int wm = wave*32;
    int lr = lane & 15, lk = lane >> 4;
    const u16* arow0 = A0 + (size_t)(bm + wm + lr)*96 + lk*8;
    const u16* arow1 = A1 + (size_t)(bm + wm + lr)*96 + lk*8;
    floatx4 acc[2][6] = {};
    #pragma unroll
    for (int k0 = 0; k0 < 192; k0 += 32){
        short8v afr[2];
        if (k0 >= 96){
            #pragma unroll
            for (int m=0;m<2;m++)
                afr[m] = *(const short8v*)(arow1 + (size_t)(m*16)*96 + (k0-96));
        } else {
            #pragma unroll
            for (int m=0;m<2;m++)
                afr[m] = *(const short8v*)(arow0 + (size_t)(m*16)*96 + k0);
        }
        #pragma unroll
        for (int n2=0;n2<6;n2++){
            short8v bfr = *(const short8v*)&Ws[(n2*16+lr)*GSTR + k0 + lk*8];
            #pragma unroll
            for (int m=0;m<2;m++)
                acc[m][n2] = __builtin_amdgcn_mfma_f32_16x16x32_bf16(afr[m], bfr, acc[m][n2], 0,0,0);
        }
    }
    float gbv[6], w2v[6];
    #pragma unroll
    for (int n2=0;n2<6;n2++){ int col = n2*16 + lr; gbv[n2] = gb1[col]; w2v[n2] = w2[col]; }
    float b2s = b2[0];
    #pragma unroll
    for (int m=0;m<2;m++){
        #pragma unroll
        for (int rg=0;rg<4;rg++){
            float part = 0.f;
            #pragma unroll
            for (int n2=0;n2<6;n2++){
                float v = fmaxf(acc[m][n2][rg] + gbv[n2], 0.f);
                part = fmaf(v, w2v[n2], part);
            }
            #pragma unroll
            for (int off=1; off<16; off<<=1) part += __shfl_xor(part, off, 64);
            if (lr == 0){
                int row = bm + wm + m*16 + lk*4 + rg;
                gpix[row] = 1.f/(1.f+expf(-(part + b2s)));
            }
        }
    }
}

// ---------- deterministic mean of gpix -> dyn_k ----------
__global__ __launch_bounds__(1024) void gate_reduce_k(const float* __restrict__ gpix,
                                                      float* __restrict__ dynk)
{
    __shared__ float sm[16];
    float s = 0.f;
    for (int i=threadIdx.x; i<NPIX; i+=1024) s += gpix[i];
    #pragma unroll
    for (int off=32; off; off>>=1) s += __shfl_xor(s,off,64);
    int wid = threadIdx.x>>6, lane = threadIdx.x&63;
    if (lane==0) sm[wid]=s;
    __syncthreads();
    if (threadIdx.x==0){
        float tot=0.f; for (int i=0;i<16;i++) tot+=sm[i];
        *dynk = floorf(12.0f * (tot/(float)NPIX));
    }
}

// ---------- qkv depthwise 3x3 (288 ch), 4-col sweep, LDS weights, XCD-swizzled ----------
#define QPOS(c8) ((c8)*8 + ((c8)>>2)*4)
#define QTAPSTRIDE 324
__global__ __launch_bounds__(256) void qkv_dw_k(const u16* __restrict__ in,
    const float* __restrict__ w, u16* __restrict__ out, size_t planeStride)
{
    __shared__ float wlds[9*QTAPSTRIDE];
    int t = threadIdx.x;
    for (int i=t; i<2592; i+=256){
        int tap = i/288, cc = i%288;
        wlds[tap*QTAPSTRIDE + QPOS(cc>>3) + (cc&7)] = w[cc*9+tap];
    }
    __syncthreads();
    int bid = blockIdx.x;
    int sb = (bid & 7)*(gridDim.x >> 3) + (bid >> 3);
    int idx = sb*256 + t;
    int c8 = idx % 36; int pq = idx / 36;
    int xg = pq & 31; int hy = (pq >> 5) & 127; int img = pq >> 12;
    int x0 = xg*4;
    int c0 = c8*8;
    int wofs = QPOS(c8);
    float acc[4][8] = {{0.f}};
    #pragma unroll
    for (int ky=0; ky<3; ky++){
        int hh = hy + ky - 1; if ((unsigned)hh >= HH) continue;
        float wr[3][8];
        #pragma unroll
        for (int kx=0; kx<3; kx++){
            floatx4 wa = *(const floatx4*)&wlds[(ky*3+kx)*QTAPSTRIDE + wofs];
            floatx4 wb = *(const floatx4*)&wlds[(ky*3+kx)*QTAPSTRIDE + wofs + 4];
            #pragma unroll
            for (int j=0;j<4;j++){ wr[kx][j]=wa[j]; wr[kx][4+j]=wb[j]; }
        }
        const u16* rowp = in + ((size_t)(img*HH+hh)*WW)*288 + c0;
        #pragma unroll
        for (int cc=0; cc<6; cc++){
            int cx = x0 - 1 + cc;
            if ((unsigned)cx >= WW) continue;
            short8v v = *(const short8v*)(rowp + (size_t)cx*288);
            float vf[8];
            #pragma unroll
            for (int j=0;j<8;j++) vf[j] = b2f((u16)v[j]);
            #pragma unroll
            for (int dx=0; dx<4; dx++){
                int kx = cc - dx;
                if (kx < 0 || kx >= 3) continue;
                #pragma unroll
                for (int j=0;j<8;j++) acc[dx][j] = fmaf(wr[kx][j], vf[j], acc[dx][j]);
            }
        }
    }
    size_t pix0 = (size_t)(img*HH+hy)*WW + x0;
    int sec = c0/96, qc0 = c0 - sec*96;
    u16* outp = out + (size_t)sec*planeStride + qc0;
    #pragma unroll
    for (int dx=0; dx<4; dx++){
        short8v o;
        #pragma unroll
        for (int j=0;j<8;j++) o[j] = (short)f2b(acc[dx][j]);
        *(short8v*)(outp + (pix0+dx)*96) = o;
    }
}

// ---------- Gram via MFMA: Q^T K + diag(Q^T Q), diag(K^T K) per (img,head,slice) ----------
// wave0: QK, wave1: QQ (diag), wave2: KK (diag); LDS tiles [16 ch][64 px] bf16, stride 72
__global__ __launch_bounds__(256) void gram_k(const u16* __restrict__ Qp,
    const u16* __restrict__ Kp, float* __restrict__ part)
{
    int bh = blockIdx.x;
    int slice = blockIdx.y;
    int img = bh >> 3, h = bh & 7;
    const u16* Qb = Qp + (size_t)img*HW*96 + h*12;
    const u16* Kb = Kp + (size_t)img*HW*96 + h*12;
    __shared__ __align__(16) u16 qs[16][72];
    __shared__ __align__(16) u16 ks[16][72];
    int t = threadIdx.x;
    int wave = t >> 6, lane = t & 63;
    int lr = lane & 15, lk = lane >> 4;
    floatx4 acc = {};
    for (int st=0; st<16; st++){
        int pix0 = slice*1024 + st*64;
        __syncthreads();
        // stage 64 px x 12 ch of Q and K, transposed to [ch][px]
        for (int i=t; i<384; i+=256){
            int p = i/6, j = i%6;
            const u16* src = (j<3) ? (Qb + (size_t)(pix0+p)*96 + j*4)
                                   : (Kb + (size_t)(pix0+p)*96 + (j-3)*4);
            short4v v = *(const short4v*)src;
            if (j<3){
                int jj=j*4;
                qs[jj+0][p]=(u16)v.x; qs[jj+1][p]=(u16)v.y;
                qs[jj+2][p]=(u16)v.z; qs[jj+3][p]=(u16)v.w;
            } else {
                int jj=(j-3)*4;
                ks[jj+0][p]=(u16)v.x; ks[jj+1][p]=(u16)v.y;
                ks[jj+2][p]=(u16)v.z; ks[jj+3][p]=(u16)v.w;
            }
        }
        __syncthreads();
        if (wave == 0){
            short8v a0 = *(const short8v*)&qs[lr][lk*8];
            short8v b0 = *(const short8v*)&ks[lr][lk*8];
            acc = __builtin_amdgcn_mfma_f32_16x16x32_bf16(a0, b0, acc, 0,0,0);
            short8v a1 = *(const short8v*)&qs[lr][32 + lk*8];
            short8v b1 = *(const short8v*)&ks[lr][32 + lk*8];
            acc = __builtin_amdgcn_mfma_f32_16x16x32_bf16(a1, b1, acc, 0,0,0);
        } else if (wave == 1){
            short8v a0 = *(const short8v*)&qs[lr][lk*8];
            acc = __builtin_amdgcn_mfma_f32_16x16x32_bf16(a0, a0, acc, 0,0,0);
            short8v a1 = *(const short8v*)&qs[lr][32 + lk*8];
            acc = __builtin_amdgcn_mfma_f32_16x16x32_bf16(a1, a1, acc, 0,0,0);
        } else if (wave == 2){
            short8v a0 = *(const short8v*)&ks[lr][lk*8];
            acc = __builtin_amdgcn_mfma_f32_16x16x32_bf16(a0, a0, acc, 0,0,0);
            short8v a1 = *(const short8v*)&ks[lr][32 + lk*8];
            acc = __builtin_amdgcn_mfma_f32_16x16x32_bf16(a1, a1, acc, 0,0,0);
        }
    }
    float* pdst = part + ((size_t)bh*16 + slice)*168;
    if (wave == 0){
        #pragma unroll
        for (int rg=0; rg<4; rg++){
            int c = lk*4 + rg, d = lr;
            if (c < 12 && d < 12) pdst[c*12 + d] = acc[rg];
        }
    } else if (wave == 1){
        #pragma unroll
        for (int rg=0; rg<4; rg++){
            int c = lk*4 + rg;
            if (c == lr && c < 12) pdst[144 + c] = acc[rg];
        }
    } else if (wave == 2){
        #pragma unroll
        for (int rg=0; rg<4; rg++){
            int c = lk*4 + rg;
            if (c == lr && c < 12) pdst[156 + c] = acc[rg];
        }
    }
}

__global__ __launch_bounds__(256) void gram_combine_k(const float* __restrict__ part,
                                                      float* __restrict__ gram, int n)
{
    int i = blockIdx.x*256 + threadIdx.x;
    if (i >= n) return;
    int bh = i/168, t = i%168;
    float s = 0.f;
    for (int sl=0; sl<16; sl++) s += part[((size_t)bh*16+sl)*168 + t];
    gram[i] = s;
}

// ---------- attn 12x12: normalize, temperature, top-k mask, softmax ----------
__global__ __launch_bounds__(256) void attn_k(const float* __restrict__ gram,
    const float* __restrict__ temp, const float* __restrict__ dynk_p,
    const float* __restrict__ a1, const float* __restrict__ a2,
    const float* __restrict__ a3, const float* __restrict__ a4,
    float* __restrict__ attnW)
{
    int bh = blockIdx.x;
    int h = bh & 7;
    __shared__ float av[12][12];
    __shared__ float mv[12][12];
    __shared__ float nq[12], nk[12];
    int t = threadIdx.x;
    if (t < 12) nq[t] = fmaxf(sqrtf(gram[bh*168+144+t]), 1e-12f);
    else if (t < 24) nk[t-12] = fmaxf(sqrtf(gram[bh*168+156+(t-12)]), 1e-12f);
    __syncthreads();
    if (t < 144){
        int c=t/12, d=t%12;
        av[c][d] = gram[bh*168+t] / (nq[c]*nk[d]) * temp[h];
    }
    __syncthreads();
    float dk = *dynk_p;
    if (t < 144){
        int c=t/12, d=t%12; float v = av[c][d];
        int r = 0;
        #pragma unroll
        for (int j=0;j<12;j++){
            float o = av[c][j];
            r += (o > v) ? 1 : ((o == v && j < d) ? 1 : 0);
        }
        mv[c][d] = ((float)r < dk) ? v : -INFINITY;
    }
    __syncthreads();
    if (t < 12){
        float mx = -INFINITY;
        for (int d2=0; d2<12; d2++) mx = fmaxf(mx, mv[t][d2]);
        float e[12]; float s = 0.f;
        for (int d2=0; d2<12; d2++){ e[d2] = expf(mv[t][d2]-mx); s += e[d2]; }
        float sc = (a1[0]+a2[0]+a3[0]+a4[0]) / s;
        for (int d2=0; d2<12; d2++) attnW[(size_t)bh*144 + t*12 + d2] = e[d2]*sc;
    }
}

// ---------- attn apply -> P96 bf16 (V plane input); thread = (pixel, head) ----------
__global__ __launch_bounds__(256) void attn_apply_k(const u16* __restrict__ Vp,
    const float* __restrict__ attnW, u16* __restrict__ P)
{
    int gid = blockIdx.x*256 + threadIdx.x;
    int h = gid % 8; size_t pix = (size_t)(gid / 8);
    int img = (int)(pix >> 14);
    const u16* vp = Vp + pix*96 + h*12;
    float vf[12];
    #pragma unroll
    for (int j=0;j<3;j++){
        short4v v = *(const short4v*)(vp + j*4);
        vf[j*4+0]=b2f((u16)v.x); vf[j*4+1]=b2f((u16)v.y);
        vf[j*4+2]=b2f((u16)v.z); vf[j*4+3]=b2f((u16)v.w);
    }
    const float* awb = attnW + ((size_t)(img*8+h))*144;
    u16 o[12];
    #pragma unroll
    for (int cc=0; cc<12; cc++){
        const float4* ap = (const float4*)(awb + cc*12);
        float4 a0 = ap[0], a1 = ap[1], a2 = ap[2];
        float s = a0.x*vf[0] + a0.y*vf[1] + a0.z*vf[2] + a0.w*vf[3]
                + a1.x*vf[4] + a1.y*vf[5] + a1.z*vf[6] + a1.w*vf[7]
                + a2.x*vf[8] + a2.y*vf[9] + a2.z*vf[10]+ a2.w*vf[11];
        o[cc] = f2b(s);
    }
    u16* op = P + pix*96 + h*12;
    *(short4v*)(op)   = *(short4v*)&o[0];
    *(short4v*)(op+4) = *(short4v*)&o[4];
    *(short4v*)(op+8) = *(short4v*)&o[8];
}

// ---------- FFN multi-scale depthwise, row-sweep; merged kernel, heaviest group FIRST ----------
template<int KS>
__device__ __forceinline__ void ffn_body(const u16* __restrict__ V0,
    const float* __restrict__ wsrc, const float* __restrict__ bsrc, int cbase,
    const float* __restrict__ bn2g, const float* __restrict__ bn2b,
    const float* __restrict__ bn2m, const float* __restrict__ bn2v,
    u16* __restrict__ U, float* wlds, float* bng, float* bnb, float* bnm, float* bnvr,
    int gridx)
{
    constexpr int PAD = KS/2;
    int t = threadIdx.x;
    for (int i=t; i<KS*KS*64; i+=256){
        int tap = i >> 6, cc = i & 63;
        wlds[tap*64 + cc] = wsrc[cc*KS*KS + tap];
    }
    if (t < 64){
        bng[t] = bn2g[cbase+t]; bnb[t] = bn2b[cbase+t];
        bnm[t] = bn2m[cbase+t]; bnvr[t] = rsqrtf(bn2v[cbase+t]+1e-5f);
    }
    __syncthreads();
    int ci = t & 7, seg = t >> 3;
    int bid = blockIdx.x;
    int rowid = (bid & 7)*(gridx >> 3) + (bid >> 3);
    int img = rowid >> 7, hy = rowid & 127;
    int c0r = ci*8;
    int c0 = cbase + c0r;
    int x0 = seg*4;
    float acc[4][8];
    {
        floatx4 b0 = *(const floatx4*)(bsrc + c0r);
        floatx4 b1 = *(const floatx4*)(bsrc + c0r + 4);
        #pragma unroll
        for (int dx=0;dx<4;dx++){
            #pragma unroll
            for (int j=0;j<4;j++){ acc[dx][j]=b0[j]; acc[dx][4+j]=b1[j]; }
        }
    }
    #pragma unroll
    for (int ky=0; ky<KS; ky++){
        int hh = hy + ky - PAD;
        if ((unsigned)hh >= HH) continue;
        float wr[KS][8];
        #pragma unroll
        for (int kx=0; kx<KS; kx++){
            floatx4 wa = *(const floatx4*)&wlds[(ky*KS+kx)*64 + c0r];
            floatx4 wb = *(const floatx4*)&wlds[(ky*KS+kx)*64 + c0r + 4];
            #pragma unroll
            for (int j=0;j<4;j++){ wr[kx][j]=wa[j]; wr[kx][4+j]=wb[j]; }
        }
        const u16* rowp = V0 + ((size_t)(img*HH+hh)*WW)*256 + c0;
        #pragma unroll
        for (int cc=0; cc<4+2*PAD; cc++){
            int cx = x0 - PAD + cc;
            if ((unsigned)cx >= WW) continue;
            short8v v = *(const short8v*)(rowp + (size_t)cx*256);
            float vf[8];
            #pragma unroll
            for (int j=0;j<8;j++) vf[j] = b2f((u16)v[j]);
            #pragma unroll
            for (int dx=0; dx<4; dx++){
                int kx = cc - dx;
                if (kx < 0 || kx >= KS) continue;
                #pragma unroll
                for (int j=0;j<8;j++) acc[dx][j] = fmaf(wr[kx][j], vf[j], acc[dx][j]);
            }
        }
    }
    size_t rbase = (size_t)(img*HH+hy)*WW;
    #pragma unroll
    for (int dx=0; dx<4; dx++){
        size_t pix = rbase + x0 + dx;
        short8v vc = *(const short8v*)(V0 + pix*256 + c0);
        short8v o;
        #pragma unroll
        for (int j=0;j<8;j++){
            float v0c = b2f((u16)vc[j]);
            float u1 = acc[dx][j] + v0c;
            float gl = gelu_fast(u1);
            float bn = (gl - bnm[c0r+j])*bnvr[c0r+j]*bng[c0r+j] + bnb[c0r+j];
            o[j] = (short)f2b(bn*v0c);
        }
        *(short8v*)(U + pix*256 + c0) = o;
    }
}

__global__ __launch_bounds__(256) void ffn_dw_all_k(const u16* __restrict__ V0,
    const float* __restrict__ w0, const float* __restrict__ bb0,
    const float* __restrict__ w1, const float* __restrict__ bb1,
    const float* __restrict__ w2, const float* __restrict__ bb2,
    const float* __restrict__ w3, const float* __restrict__ bb3,
    const float* __restrict__ bn2g, const float* __restrict__ bn2b,
    const float* __restrict__ bn2m, const float* __restrict__ bn2v,
    u16* __restrict__ U)
{
    __shared__ float wlds[49*64];
    __shared__ float bng[64], bnb[64], bnm[64], bnvr[64];
    int gx = gridDim.x;
    switch(blockIdx.y){
        case 0: ffn_body<7>(V0, w3, bb3, 192, bn2g,bn2b,bn2m,bn2v, U, wlds,bng,bnb,bnm,bnvr, gx); break;
        case 1: ffn_body<5>(V0, w2, bb2, 128, bn2g,bn2b,bn2m,bn2v, U, wlds,bng,bnb,bnm,bnvr, gx); break;
        case 2: ffn_body<3>(V0, w1, bb1, 64,  bn2g,bn2b,bn2m,bn2v, U, wlds,bng,bnb,bnm,bnvr, gx); break;
        default: ffn_body<1>(V0, w0, bb0, 0,  bn2g,bn2b,bn2m,bn2v, U, wlds,bng,bnb,bnm,bnvr, gx); break;
    }
}

extern "C" void kernel_launch(void* const* d_in, const int* in_sizes, int n_in,
                              void* d_out, int out_size, void* d_ws, size_t ws_size,
                              hipStream_t stream)
{
    const float* x     = (const float*)d_in[0];
    const float* pos_w = (const float*)d_in[1];
    const float* pos_b = (const float*)d_in[2];
    const float* ln1g  = (const float*)d_in[3];
    const float* ln1b  = (const float*)d_in[4];
    const float* temp  = (const float*)d_in[5];
    const float* qkvw  = (const float*)d_in[6];
    const float* qkvdw = (const float*)d_in[7];
    const float* projw = (const float*)d_in[8];
    const float* gw1   = (const float*)d_in[9];
    const float* gb1   = (const float*)d_in[10];
    const float* gw2   = (const float*)d_in[11];
    const float* gb2   = (const float*)d_in[12];
    const float* a1    = (const float*)d_in[13];
    const float* a2    = (const float*)d_in[14];
    const float* a3    = (const float*)d_in[15];
    const float* a4    = (const float*)d_in[16];
    const float* ln2g  = (const float*)d_in[17];
    const float* ln2b  = (const float*)d_in[18];
    const float* fc1w  = (const float*)d_in[19];
    const float* bn1g  = (const float*)d_in[20];
    const float* bn1b  = (const float*)d_in[21];
    const float* bn1m  = (const float*)d_in[22];
    const float* bn1v  = (const float*)d_in[23];
    const float* bn2g  = (const float*)d_in[24];
    const float* bn2b  = (const float*)d_in[25];
    const float* bn2m  = (const float*)d_in[26];
    const float* bn2v  = (const float*)d_in[27];
    const float* fc2w  = (const float*)d_in[28];
    const float* bn3g  = (const float*)d_in[29];
    const float* bn3b  = (const float*)d_in[30];
    const float* bn3m  = (const float*)d_in[31];
    const float* bn3v  = (const float*)d_in[32];
    const float* dw0w  = (const float*)d_in[33];
    const float* dw0b  = (const float*)d_in[34];
    const float* dw1w  = (const float*)d_in[35];
    const float* dw1b  = (const float*)d_in[36];
    const float* dw2w  = (const float*)d_in[37];
    const float* dw2b  = (const float*)d_in[38];
    const float* dw3w  = (const float*)d_in[39];
    const float* dw3b  = (const float*)d_in[40];

    float* OUT = (float*)d_out;      // final fp32 output (written once by fc2)

    // ---- fixed small buffers + bf16 residual stream A ----
    char* p = (char*)d_ws;
    float* gpix  = (float*)p;                 p += (size_t)NPIX*4;
    float* dynk  = (float*)p;                 p += 256;
    float* gpart = (float*)p;                 p += 64*16*168*4;
    float* gram  = (float*)p;                 p += 64*168*4;
    float* attnW = (float*)p;                 p += 64*144*4;
    float* wposT = (float*)p;                 p += 1728*4;
    u16*   wbf   = (u16*)p;                   p += (size_t)WTOT*2;
    u16*   Abf   = (u16*)p;                   p += (size_t)NPIX*192*2;   // 50.3 MB
    size_t fixedB = (size_t)(p - (char*)d_ws);

    // ---- choose chunk size from ws_size: per-image = Y(192)+B1(288)+B2(288) bf16 ----
    size_t perImg = (size_t)HW*2*(192+288+288);   // 25,165,824
    int CBr = 2;
    if (ws_size >= fixedB + 8*perImg) CBr = 8;
    else if (ws_size >= fixedB + 4*perImg) CBr = 4;
    int NCHUNKr = BB/CBr;
    size_t CHWr = (size_t)CBr*HW;

    u16* Ybf = (u16*)p;                   p += CHWr*192*2;   // two 96-ch planes
    u16* B1  = (u16*)p;                   p += CHWr*288*2;
    u16* B2  = (u16*)p;
    u16* Y0  = Ybf;
    u16* Y1  = Ybf + CHWr*96;
    u16* qkvwb = wbf;
    u16* projwb= wbf + WQ;
    u16* gw1b  = wbf + WQ + WP;
    u16* fc1b  = wbf + WQ + WP + WG;
    u16* fc2b  = wbf + WQ + WP + WG + WF1;
    u16* QKVbf = B1;     // qkv out (288 interleaved)
    u16* QKVdbf= B2;     // qkv_dw out: Q|K|V planes of CHWr*96 each
    u16* P96   = B1;     // attn out (QKV dead)
    u16* Zbf   = B2;     // LN2 out (QKVd dead)
    u16* V0bf  = B1;     // fc1 out (P96 dead)
    u16* Ubf   = B2;     // ffn out (Z dead)

    wprep_k<<<(WTOT+255)/256, 256, 0, stream>>>(qkvw, projw, gw1, fc1w, fc2w,
                                                pos_w, wbf, wposT);
    pos_conv_k<<<NPIX/8, 192, 0, stream>>>(x, wposT, pos_b, Abf);

    // gate phase: LN1 (split planes) -> fused gate GEMM -> gpix
    for (int c=0; c<NCHUNKr; c++){
        const u16* Ab = Abf + (size_t)c*CHWr*192;
        ln_split_k<<<CHWr/4, 256, 0, stream>>>(Ab, ln1g, ln1b, Y0, Y1);
        gate_gemm_k<<<CHWr/128, 256, 0, stream>>>(Y0, Y1, gw1b, gb1, gw2, gb2,
                                                  gpix + (size_t)c*CHWr);
    }
    gate_reduce_k<<<1, 1024, 0, stream>>>(gpix, dynk);

    // main phase
    for (int c=0; c<NCHUNKr; c++){
        u16* Ab = Abf + (size_t)c*CHWr*192;
        if (NCHUNKr > 1)   // single-chunk mode: Y planes from gate phase still valid
            ln_split_k<<<CHWr/4, 256, 0, stream>>>(Ab, ln1g, ln1b, Y0, Y1);
        {   // qkv 1x1: A = dense Y0 plane (K=96), N=288 = 3 x 96-tiles
            dim3 g(CHWr/128, 3);
            gemm_bf16_k<GM_NONE,96,96><<<g, 256, 0, stream>>>(Y0, 96, nullptr, 0,
                qkvwb, QKVbf, 288, nullptr, 0, nullptr,nullptr,nullptr,nullptr, 288);
        }
        size_t pstr = CHWr*96;
        qkv_dw_k<<<CHWr/4*36/256, 256, 0, stream>>>(QKVbf, qkvdw, QKVdbf, pstr);
        { dim3 g(CBr*8, 16); gram_k<<<g, 256, 0, stream>>>(QKVdbf, QKVdbf + pstr, gpart); }
        gram_combine_k<<<(CBr*8*168+255)/256, 256, 0, stream>>>(gpart, gram, CBr*8*168);
        attn_k<<<CBr*8, 256, 0, stream>>>(gram, temp, dynk, a1,a2,a3,a4, attnW);
        attn_apply_k<<<CHWr*8/256, 256, 0, stream>>>(QKVdbf + 2*pstr, attnW, P96);
        {   // proj + residual: A-panels = P96 | Y1 (both dense 96-wide)
            dim3 g(CHWr/128, 2);
            gemm_bf16_k<GM_RES,192,96,true><<<g, 256, 0, stream>>>(P96, 96, Y1, 96,
                projwb, Ab, 192, Ab, 192, nullptr,nullptr,nullptr,nullptr, 192);
        }
        ln_k<<<CHWr/4, 256, 0, stream>>>(Ab, ln2g, ln2b, Zbf);
        {   // fc1: N=256 = 4 x 64-tiles
            dim3 g(CHWr/128, 4);
            gemm_bf16_k<GM_GELU_BN,192,64><<<g, 256, 0, stream>>>(Zbf, 192, nullptr, 0,
                fc1b, V0bf, 256, nullptr, 0, bn1g,bn1b,bn1m,bn1v, 256);
        }
        {   // multi-scale depthwise, heaviest-first merged launch
            int rows = (int)(CHWr/WW);
            dim3 g(rows, 4);
            ffn_dw_all_k<<<g, 256, 0, stream>>>(V0bf, dw0w,dw0b,dw1w,dw1b,dw2w,dw2b,
                                                dw3w,dw3b, bn2g,bn2b,bn2m,bn2v, Ubf);
        }
        {   // fc2 + bn3 + residual -> fp32 OUT: N=192 = 2 x 96-tiles
            dim3 g(CHWr/128, 2);
            gemm_bf16_k<GM_BN_RES,256,96><<<g, 256, 0, stream>>>(Ubf, 256, nullptr, 0,
                fc2b, OUT + (size_t)c*CHWr*192, 192, Ab, 192, bn3g,bn3b,bn3m,bn3v, 192);
        }
    }
}

// Round 23
// 571.640 us; speedup vs baseline: 1.1472x; 1.0110x over previous
//
#include <hip/hip_runtime.h>
#include <hip/hip_bf16.h>
#include <math.h>

#define BB 8
#define HH 128
#define WW 128
#define HW (HH*WW)          // 16384
#define NPIX (BB*HW)        // 131072

typedef unsigned short u16;
typedef __attribute__((ext_vector_type(4))) float  floatx4;
typedef __attribute__((ext_vector_type(4))) short  short4v;
typedef __attribute__((ext_vector_type(8))) short  short8v;

static __device__ __forceinline__ float gelu_fast(float x){
    float u = 0.7978845608028654f*(x + 0.044715f*x*x*x);
    float e = __expf(2.f*u);
    float th = 1.f - 2.f/(e + 1.f);
    return 0.5f*x*(1.f + th);
}
static __device__ __forceinline__ float b2f(u16 v){
    union { unsigned u; float f; } x; x.u = ((unsigned)v)<<16; return x.f;
}
static __device__ __forceinline__ u16 f2b(float f){
    __hip_bfloat16 h = __float2bfloat16(f);
    return *(u16*)&h;
}

// ---------- weight prep: fp32 -> bf16 GEMM weights + transposed pos weights ----------
#define WQ 27648
#define WP 36864
#define WG 18432
#define WF1 49152
#define WF2 49152
#define WTOT (WQ+WP+WG+WF1+WF2)   // 181248
__global__ __launch_bounds__(256) void wprep_k(const float* __restrict__ a,
    const float* __restrict__ b, const float* __restrict__ c,
    const float* __restrict__ d, const float* __restrict__ e,
    const float* __restrict__ posw, u16* __restrict__ o, float* __restrict__ wT)
{
    int i = blockIdx.x*256 + threadIdx.x;
    if (i < 1728){   // wT[tap][192]: wT[tap*192+c] = posw[c*9+tap]
        wT[i] = posw[(i%192)*9 + (i/192)];
    }
    if (i >= WTOT) return;
    float v;
    if (i < WQ) v = a[i];
    else if (i < WQ+WP) v = b[i-WQ];
    else if (i < WQ+WP+WG) v = c[i-WQ-WP];
    else if (i < WQ+WP+WG+WF1) v = d[i-WQ-WP-WG];
    else v = e[i-WQ-WP-WG-WF1];
    o[i] = f2b(v);
}

// ---------- pos depthwise 3x3 + bias + residual -> bf16 A; LDS halo, 2 px/thread ----------
__global__ __launch_bounds__(192) void pos_conv_k(const float* __restrict__ x,
    const float* __restrict__ wT, const float* __restrict__ bias, u16* __restrict__ out)
{
    __shared__ float4 lds[3][10][48];
    int bid = blockIdx.x;
    int sb = (bid & 7)*(gridDim.x >> 3) + (bid >> 3);   // XCD image-slice swizzle
    int t = threadIdx.x;
    int unit = sb;                       // over NPIX/8 column-octets
    int x0 = (unit & 15)*8;
    int hy = (unit >> 4) & 127;
    int b  = unit >> 11;

    const float4* x4 = (const float4*)x;
    float4 z4 = make_float4(0.f,0.f,0.f,0.f);
    for (int i = t; i < 1440; i += 192){
        int c4s = i % 48;
        int rc  = i / 48;
        int r   = rc / 10;
        int cp  = rc % 10;
        int hh  = hy + r - 1;
        int cx  = x0 + cp - 1;
        float4 v = z4;
        if ((unsigned)hh < HH && (unsigned)cx < WW)
            v = x4[((size_t)(b*HH+hh)*WW + cx)*48 + c4s];
        lds[r][cp][c4s] = v;
    }
    __syncthreads();

    int c4 = t % 48;
    int p0 = (t / 48)*2;
    int c0 = c4*4;
    floatx4 wv[9];
    #pragma unroll
    for (int tap=0; tap<9; tap++)
        wv[tap] = *(const floatx4*)&wT[tap*192 + c0];

    float4 xv[3][4];
    #pragma unroll
    for (int i=0;i<3;i++)
        #pragma unroll
        for (int k=0;k<4;k++)
            xv[i][k] = lds[i][p0+k][c4];

    float4 bias4 = *(const float4*)(bias + c0);
    float4 acc0 = bias4, acc1 = bias4;
    #pragma unroll
    for (int i=0;i<3;i++){
        #pragma unroll
        for (int k=0;k<3;k++){
            floatx4 w = wv[i*3+k];
            float4 a = xv[i][k];
            float4 bqq = xv[i][k+1];
            acc0.x = fmaf(w[0], a.x, acc0.x);
            acc0.y = fmaf(w[1], a.y, acc0.y);
            acc0.z = fmaf(w[2], a.z, acc0.z);
            acc0.w = fmaf(w[3], a.w, acc0.w);
            acc1.x = fmaf(w[0], bqq.x, acc1.x);
            acc1.y = fmaf(w[1], bqq.y, acc1.y);
            acc1.z = fmaf(w[2], bqq.z, acc1.z);
            acc1.w = fmaf(w[3], bqq.w, acc1.w);
        }
    }
    float4 xc0 = xv[1][1];
    float4 xc1 = xv[1][2];
    acc0.x += xc0.x; acc0.y += xc0.y; acc0.z += xc0.z; acc0.w += xc0.w;
    acc1.x += xc1.x; acc1.y += xc1.y; acc1.z += xc1.z; acc1.w += xc1.w;

    size_t pix0 = (size_t)(b*HH + hy)*WW + x0 + p0;
    short4v o0, o1;
    o0.x=(short)f2b(acc0.x); o0.y=(short)f2b(acc0.y);
    o0.z=(short)f2b(acc0.z); o0.w=(short)f2b(acc0.w);
    o1.x=(short)f2b(acc1.x); o1.y=(short)f2b(acc1.y);
    o1.z=(short)f2b(acc1.z); o1.w=(short)f2b(acc1.w);
    *(short4v*)(out + pix0*192 + c0) = o0;
    *(short4v*)(out + (pix0+1)*192 + c0) = o1;
}

// ---------- LayerNorm over C=192, bf16 in -> split Y0|Y1 planes (96 ch each) ----------
__global__ __launch_bounds__(256) void ln_split_k(const u16* __restrict__ in,
    const float* __restrict__ g, const float* __restrict__ bta,
    u16* __restrict__ y0, u16* __restrict__ y1)
{
    int wid = threadIdx.x >> 6, lane = threadIdx.x & 63;
    size_t pix = (size_t)blockIdx.x*4 + wid;
    const u16* row = in + pix*192;
    float x0 = b2f(row[lane]), x1 = b2f(row[lane+64]), x2 = b2f(row[lane+128]);
    float s = x0+x1+x2;
    float q = x0*x0 + x1*x1 + x2*x2;
    #pragma unroll
    for (int off=32; off; off>>=1){ s += __shfl_xor(s,off,64); q += __shfl_xor(q,off,64); }
    float mean = s*(1.f/192.f);
    float var  = q*(1.f/192.f) - mean*mean;
    float inv  = rsqrtf(var + 1e-6f);
    y0[pix*96 + lane] = f2b((x0-mean)*inv*g[lane] + bta[lane]);
    int c1 = lane + 64;
    u16 v1 = f2b((x1-mean)*inv*g[c1] + bta[c1]);
    if (c1 < 96) y0[pix*96 + c1] = v1;
    else         y1[pix*96 + c1 - 96] = v1;
    int c2 = lane + 128;
    y1[pix*96 + c2 - 96] = f2b((x2-mean)*inv*g[c2] + bta[c2]);
}

// ---------- LayerNorm over C=192, bf16 in -> contiguous bf16 out (LN2) ----------
__global__ __launch_bounds__(256) void ln_k(const u16* __restrict__ in,
    const float* __restrict__ g, const float* __restrict__ bta, u16* __restrict__ out)
{
    int wid = threadIdx.x >> 6, lane = threadIdx.x & 63;
    size_t pix = (size_t)blockIdx.x*4 + wid;
    const u16* row = in + pix*192;
    float x0 = b2f(row[lane]), x1 = b2f(row[lane+64]), x2 = b2f(row[lane+128]);
    float s = x0+x1+x2;
    float q = x0*x0 + x1*x1 + x2*x2;
    #pragma unroll
    for (int off=32; off; off>>=1){ s += __shfl_xor(s,off,64); q += __shfl_xor(q,off,64); }
    float mean = s*(1.f/192.f);
    float var  = q*(1.f/192.f) - mean*mean;
    float inv  = rsqrtf(var + 1e-6f);
    u16* orow = out + pix*192;
    orow[lane]     = f2b((x0-mean)*inv*g[lane]     + bta[lane]);
    orow[lane+64]  = f2b((x1-mean)*inv*g[lane+64]  + bta[lane+64]);
    orow[lane+128] = f2b((x2-mean)*inv*g[lane+128] + bta[lane+128]);
}

// ---------- bf16 MFMA GEMM: M-tile 128, XCD-swizzled m-blocks, W-in-LDS once ----------
#define GM_NONE 0
#define GM_RES 1
#define GM_GELU_BN 2
#define GM_BN_RES 3

template<int MODE, int K, int NT, bool SPLIT=false>
__global__ __launch_bounds__(256) void gemm_bf16_k(
    const u16* __restrict__ A, int lda,
    const u16* __restrict__ A2, int lda2,
    const u16* __restrict__ W,
    void* __restrict__ Cv, int ldc,
    const u16* __restrict__ R, int ldr,
    const float* __restrict__ bg, const float* __restrict__ bb,
    const float* __restrict__ bm_, const float* __restrict__ bv,
    int N)
{
    constexpr int LSTR = (K==96) ? 104 : ((K==192) ? 200 : 264);  // stride%32dw==4
    constexpr int NF = NT/16;
    __shared__ u16 Ws[NT*LSTR];
    int t = threadIdx.x;
    int bn = blockIdx.y * NT;
    int bidx = blockIdx.x;
    int sbm = (bidx & 7)*(gridDim.x >> 3) + (bidx >> 3);   // XCD-contiguous m-slices
    int bm = sbm * 128;
    {
        constexpr int K8 = K/8;
        for (int i = t; i < NT*K8; i += 256){
            int row = i / K8, j = (i % K8)*8;
            int n = bn + row;
            short8v v = {};
            if (n < N) v = *(const short8v*)(W + (size_t)n*K + j);
            *(short8v*)&Ws[row*LSTR + j] = v;
        }
    }
    __syncthreads();
    int wave = t >> 6, lane = t & 63;
    int wm = wave*32;
    int lr = lane & 15, lk = lane >> 4;
    const u16* arow  = A + (size_t)(bm + wm + lr)*lda + lk*8;
    const u16* arow2 = SPLIT ? (A2 + (size_t)(bm + wm + lr)*lda2 + lk*8) : nullptr;
    floatx4 acc[2][NF] = {};
    #pragma unroll
    for (int k0 = 0; k0 < K; k0 += 32){
        short8v afr[2];
        if (SPLIT && k0 >= 96){
            #pragma unroll
            for (int m=0;m<2;m++)
                afr[m] = *(const short8v*)(arow2 + (size_t)(m*16)*lda2 + (k0-96));
        } else {
            #pragma unroll
            for (int m=0;m<2;m++)
                afr[m] = *(const short8v*)(arow + (size_t)(m*16)*lda + k0);
        }
        #pragma unroll
        for (int n2=0;n2<NF;n2++){
            short8v bfr = *(const short8v*)&Ws[(n2*16+lr)*LSTR + k0 + lk*8];
            #pragma unroll
            for (int m=0;m<2;m++)
                acc[m][n2] = __builtin_amdgcn_mfma_f32_16x16x32_bf16(afr[m], bfr, acc[m][n2], 0,0,0);
        }
    }
    #pragma unroll
    for (int m=0;m<2;m++){
        #pragma unroll
        for (int n2=0;n2<NF;n2++){
            int gcol = bn + n2*16 + lr;
            if (gcol >= N) continue;
            float bscale = 0.f, bmv = 0.f, bbv = 0.f;
            if (MODE == GM_GELU_BN || MODE == GM_BN_RES){
                bscale = rsqrtf(bv[gcol]+1e-5f)*bg[gcol];
                bmv = bm_[gcol]; bbv = bb[gcol];
            }
            #pragma unroll
            for (int rg=0; rg<4; rg++){
                int grow = bm + wm + m*16 + lk*4 + rg;
                float v = acc[m][n2][rg];
                if (MODE == GM_RES){
                    v += b2f(R[(size_t)grow*ldr + gcol]);
                    ((u16*)Cv)[(size_t)grow*ldc + gcol] = f2b(v);
                } else if (MODE == GM_BN_RES){
                    float bnv = (v - bmv)*bscale + bbv;
                    ((float*)Cv)[(size_t)grow*ldc + gcol] = bnv + b2f(R[(size_t)grow*ldr + gcol]);
                } else if (MODE == GM_GELU_BN){
                    float gl = gelu_fast(v);
                    v = (gl - bmv)*bscale + bbv;
                    ((u16*)Cv)[(size_t)grow*ldc + gcol] = f2b(v);
                } else {
                    ((u16*)Cv)[(size_t)grow*ldc + gcol] = f2b(v);
                }
            }
        }
    }
}

// ---------- fused gate GEMM (M-tile 128, XCD-swizzled, two-panel A) ----------
#define GSTR 200
__global__ __launch_bounds__(256) void gate_gemm_k(
    const u16* __restrict__ A0, const u16* __restrict__ A1,   // Y planes, lda=96
    const u16* __restrict__ W,
    const float* __restrict__ gb1, const float* __restrict__ w2,
    const float* __restrict__ b2, float* __restrict__ gpix)
{
    __shared__ u16 Ws[96*GSTR];
    int t = threadIdx.x;
    int bidx = blockIdx.x;
    int sbm = (bidx & 7)*(gridDim.x >> 3) + (bidx >> 3);
    int bm = sbm * 128;
    for (int i = t; i < 96*24; i += 256){
        int row = i/24, j = (i%24)*8;
        *(short8v*)&Ws[row*GSTR + j] = *(const short8v*)(W + (size_t)row*192 + j);
    }
    __syncthreads();
    int wave = t >> 6, lane = t & 63;
    int wm = wave*32;
    int lr = lane & 15, lk = lane >> 4;
    const u16* arow0 = A0 + (size_t)(bm + wm + lr)*96 + lk*8;
    const u16* arow1 = A1 + (size_t)(bm + wm + lr)*96 + lk*8;
    floatx4 acc[2][6] = {};
    #pragma unroll
    for (int k0 = 0; k0 < 192; k0 += 32){
        short8v afr[2];
        if (k0 >= 96){
            #pragma unroll
            for (int m=0;m<2;m++)
                afr[m] = *(const short8v*)(arow1 + (size_t)(m*16)*96 + (k0-96));
        } else {
            #pragma unroll
            for (int m=0;m<2;m++)
                afr[m] = *(const short8v*)(arow0 + (size_t)(m*16)*96 + k0);
        }
        #pragma unroll
        for (int n2=0;n2<6;n2++){
            short8v bfr = *(const short8v*)&Ws[(n2*16+lr)*GSTR + k0 + lk*8];
            #pragma unroll
            for (int m=0;m<2;m++)
                acc[m][n2] = __builtin_amdgcn_mfma_f32_16x16x32_bf16(afr[m], bfr, acc[m][n2], 0,0,0);
        }
    }
    float gbv[6], w2v[6];
    #pragma unroll
    for (int n2=0;n2<6;n2++){ int col = n2*16 + lr; gbv[n2] = gb1[col]; w2v[n2] = w2[col]; }
    float b2s = b2[0];
    #pragma unroll
    for (int m=0;m<2;m++){
        #pragma unroll
        for (int rg=0;rg<4;rg++){
            float part = 0.f;
            #pragma unroll
            for (int n2=0;n2<6;n2++){
                float v = fmaxf(acc[m][n2][rg] + gbv[n2], 0.f);
                part = fmaf(v, w2v[n2], part);
            }
            #pragma unroll
            for (int off=1; off<16; off<<=1) part += __shfl_xor(part, off, 64);
            if (lr == 0){
                int row = bm + wm + m*16 + lk*4 + rg;
                gpix[row] = 1.f/(1.f+expf(-(part + b2s)));
            }
        }
    }
}

// ---------- deterministic mean of gpix -> dyn_k ----------
__global__ __launch_bounds__(1024) void gate_reduce_k(const float* __restrict__ gpix,
                                                      float* __restrict__ dynk)
{
    __shared__ float sm[16];
    float s = 0.f;
    for (int i=threadIdx.x; i<NPIX; i+=1024) s += gpix[i];
    #pragma unroll
    for (int off=32; off; off>>=1) s += __shfl_xor(s,off,64);
    int wid = threadIdx.x>>6, lane = threadIdx.x&63;
    if (lane==0) sm[wid]=s;
    __syncthreads();
    if (threadIdx.x==0){
        float tot=0.f; for (int i=0;i<16;i++) tot+=sm[i];
        *dynk = floorf(12.0f * (tot/(float)NPIX));
    }
}

// ---------- qkv depthwise 3x3 (288 ch), 4-col sweep, LDS weights, XCD-swizzled ----------
#define QPOS(c8) ((c8)*8 + ((c8)>>2)*4)
#define QTAPSTRIDE 324
__global__ __launch_bounds__(256) void qkv_dw_k(const u16* __restrict__ in,
    const float* __restrict__ w, u16* __restrict__ out, size_t planeStride)
{
    __shared__ float wlds[9*QTAPSTRIDE];
    int t = threadIdx.x;
    for (int i=t; i<2592; i+=256){
        int tap = i/288, cc = i%288;
        wlds[tap*QTAPSTRIDE + QPOS(cc>>3) + (cc&7)] = w[cc*9+tap];
    }
    __syncthreads();
    int bid = blockIdx.x;
    int sb = (bid & 7)*(gridDim.x >> 3) + (bid >> 3);
    int idx = sb*256 + t;
    int c8 = idx % 36; int pq = idx / 36;
    int xg = pq & 31; int hy = (pq >> 5) & 127; int img = pq >> 12;
    int x0 = xg*4;
    int c0 = c8*8;
    int wofs = QPOS(c8);
    float acc[4][8] = {{0.f}};
    #pragma unroll
    for (int ky=0; ky<3; ky++){
        int hh = hy + ky - 1; if ((unsigned)hh >= HH) continue;
        float wr[3][8];
        #pragma unroll
        for (int kx=0; kx<3; kx++){
            floatx4 wa = *(const floatx4*)&wlds[(ky*3+kx)*QTAPSTRIDE + wofs];
            floatx4 wb = *(const floatx4*)&wlds[(ky*3+kx)*QTAPSTRIDE + wofs + 4];
            #pragma unroll
            for (int j=0;j<4;j++){ wr[kx][j]=wa[j]; wr[kx][4+j]=wb[j]; }
        }
        const u16* rowp = in + ((size_t)(img*HH+hh)*WW)*288 + c0;
        #pragma unroll
        for (int cc=0; cc<6; cc++){
            int cx = x0 - 1 + cc;
            if ((unsigned)cx >= WW) continue;
            short8v v = *(const short8v*)(rowp + (size_t)cx*288);
            float vf[8];
            #pragma unroll
            for (int j=0;j<8;j++) vf[j] = b2f((u16)v[j]);
            #pragma unroll
            for (int dx=0; dx<4; dx++){
                int kx = cc - dx;
                if (kx < 0 || kx >= 3) continue;
                #pragma unroll
                for (int j=0;j<8;j++) acc[dx][j] = fmaf(wr[kx][j], vf[j], acc[dx][j]);
            }
        }
    }
    size_t pix0 = (size_t)(img*HH+hy)*WW + x0;
    int sec = c0/96, qc0 = c0 - sec*96;
    u16* outp = out + (size_t)sec*planeStride + qc0;
    #pragma unroll
    for (int dx=0; dx<4; dx++){
        short8v o;
        #pragma unroll
        for (int j=0;j<8;j++) o[j] = (short)f2b(acc[dx][j]);
        *(short8v*)(outp + (pix0+dx)*96) = o;
    }
}

// ---------- Gram via MFMA: Q^T K + diag(Q^T Q), diag(K^T K) per (img,head,slice) ----------
__global__ __launch_bounds__(256) void gram_k(const u16* __restrict__ Qp,
    const u16* __restrict__ Kp, float* __restrict__ part)
{
    int bh = blockIdx.x;
    int slice = blockIdx.y;
    int img = bh >> 3, h = bh & 7;
    const u16* Qb = Qp + (size_t)img*HW*96 + h*12;
    const u16* Kb = Kp + (size_t)img*HW*96 + h*12;
    __shared__ __align__(16) u16 qs[16][72];
    __shared__ __align__(16) u16 ks[16][72];
    int t = threadIdx.x;
    int wave = t >> 6, lane = t & 63;
    int lr = lane & 15, lk = lane >> 4;
    floatx4 acc = {};
    for (int st=0; st<16; st++){
        int pix0 = slice*1024 + st*64;
        __syncthreads();
        for (int i=t; i<384; i+=256){
            int p = i/6, j = i%6;
            const u16* src = (j<3) ? (Qb + (size_t)(pix0+p)*96 + j*4)
                                   : (Kb + (size_t)(pix0+p)*96 + (j-3)*4);
            short4v v = *(const short4v*)src;
            if (j<3){
                int jj=j*4;
                qs[jj+0][p]=(u16)v.x; qs[jj+1][p]=(u16)v.y;
                qs[jj+2][p]=(u16)v.z; qs[jj+3][p]=(u16)v.w;
            } else {
                int jj=(j-3)*4;
                ks[jj+0][p]=(u16)v.x; ks[jj+1][p]=(u16)v.y;
                ks[jj+2][p]=(u16)v.z; ks[jj+3][p]=(u16)v.w;
            }
        }
        __syncthreads();
        if (wave == 0){
            short8v a0 = *(const short8v*)&qs[lr][lk*8];
            short8v b0 = *(const short8v*)&ks[lr][lk*8];
            acc = __builtin_amdgcn_mfma_f32_16x16x32_bf16(a0, b0, acc, 0,0,0);
            short8v a1 = *(const short8v*)&qs[lr][32 + lk*8];
            short8v b1 = *(const short8v*)&ks[lr][32 + lk*8];
            acc = __builtin_amdgcn_mfma_f32_16x16x32_bf16(a1, b1, acc, 0,0,0);
        } else if (wave == 1){
            short8v a0 = *(const short8v*)&qs[lr][lk*8];
            acc = __builtin_amdgcn_mfma_f32_16x16x32_bf16(a0, a0, acc, 0,0,0);
            short8v a1 = *(const short8v*)&qs[lr][32 + lk*8];
            acc = __builtin_amdgcn_mfma_f32_16x16x32_bf16(a1, a1, acc, 0,0,0);
        } else if (wave == 2){
            short8v a0 = *(const short8v*)&ks[lr][lk*8];
            acc = __builtin_amdgcn_mfma_f32_16x16x32_bf16(a0, a0, acc, 0,0,0);
            short8v a1 = *(const short8v*)&ks[lr][32 + lk*8];
            acc = __builtin_amdgcn_mfma_f32_16x16x32_bf16(a1, a1, acc, 0,0,0);
        }
    }
    float* pdst = part + ((size_t)bh*16 + slice)*168;
    if (wave == 0){
        #pragma unroll
        for (int rg=0; rg<4; rg++){
            int c = lk*4 + rg, d = lr;
            if (c < 12 && d < 12) pdst[c*12 + d] = acc[rg];
        }
    } else if (wave == 1){
        #pragma unroll
        for (int rg=0; rg<4; rg++){
            int c = lk*4 + rg;
            if (c == lr && c < 12) pdst[144 + c] = acc[rg];
        }
    } else if (wave == 2){
        #pragma unroll
        for (int rg=0; rg<4; rg++){
            int c = lk*4 + rg;
            if (c == lr && c < 12) pdst[156 + c] = acc[rg];
        }
    }
}

__global__ __launch_bounds__(256) void gram_combine_k(const float* __restrict__ part,
                                                      float* __restrict__ gram, int n)
{
    int i = blockIdx.x*256 + threadIdx.x;
    if (i >= n) return;
    int bh = i/168, t = i%168;
    float s = 0.f;
    for (int sl=0; sl<16; sl++) s += part[((size_t)bh*16+sl)*168 + t];
    gram[i] = s;
}

// ---------- attn 12x12: normalize, temperature, top-k mask, softmax ----------
__global__ __launch_bounds__(256) void attn_k(const float* __restrict__ gram,
    const float* __restrict__ temp, const float* __restrict__ dynk_p,
    const float* __restrict__ a1, const float* __restrict__ a2,
    const float* __restrict__ a3, const float* __restrict__ a4,
    float* __restrict__ attnW)
{
    int bh = blockIdx.x;
    int h = bh & 7;
    __shared__ float av[12][12];
    __shared__ float mv[12][12];
    __shared__ float nq[12], nk[12];
    int t = threadIdx.x;
    if (t < 12) nq[t] = fmaxf(sqrtf(gram[bh*168+144+t]), 1e-12f);
    else if (t < 24) nk[t-12] = fmaxf(sqrtf(gram[bh*168+156+(t-12)]), 1e-12f);
    __syncthreads();
    if (t < 144){
        int c=t/12, d=t%12;
        av[c][d] = gram[bh*168+t] / (nq[c]*nk[d]) * temp[h];
    }
    __syncthreads();
    float dk = *dynk_p;
    if (t < 144){
        int c=t/12, d=t%12; float v = av[c][d];
        int r = 0;
        #pragma unroll
        for (int j=0;j<12;j++){
            float o = av[c][j];
            r += (o > v) ? 1 : ((o == v && j < d) ? 1 : 0);
        }
        mv[c][d] = ((float)r < dk) ? v : -INFINITY;
    }
    __syncthreads();
    if (t < 12){
        float mx = -INFINITY;
        for (int d2=0; d2<12; d2++) mx = fmaxf(mx, mv[t][d2]);
        float e[12]; float s = 0.f;
        for (int d2=0; d2<12; d2++){ e[d2] = expf(mv[t][d2]-mx); s += e[d2]; }
        float sc = (a1[0]+a2[0]+a3[0]+a4[0]) / s;
        for (int d2=0; d2<12; d2++) attnW[(size_t)bh*144 + t*12 + d2] = e[d2]*sc;
    }
}

// ---------- attn apply -> P96 bf16 (V plane input); thread = (pixel, head) ----------
__global__ __launch_bounds__(256) void attn_apply_k(const u16* __restrict__ Vp,
    const float* __restrict__ attnW, u16* __restrict__ P)
{
    int gid = blockIdx.x*256 + threadIdx.x;
    int h = gid % 8; size_t pix = (size_t)(gid / 8);
    int img = (int)(pix >> 14);
    const u16* vp = Vp + pix*96 + h*12;
    float vf[12];
    #pragma unroll
    for (int j=0;j<3;j++){
        short4v v = *(const short4v*)(vp + j*4);
        vf[j*4+0]=b2f((u16)v.x); vf[j*4+1]=b2f((u16)v.y);
        vf[j*4+2]=b2f((u16)v.z); vf[j*4+3]=b2f((u16)v.w);
    }
    const float* awb = attnW + ((size_t)(img*8+h))*144;
    u16 o[12];
    #pragma unroll
    for (int cc=0; cc<12; cc++){
        const float4* ap = (const float4*)(awb + cc*12);
        float4 a0 = ap[0], a1 = ap[1], a2 = ap[2];
        float s = a0.x*vf[0] + a0.y*vf[1] + a0.z*vf[2] + a0.w*vf[3]
                + a1.x*vf[4] + a1.y*vf[5] + a1.z*vf[6] + a1.w*vf[7]
                + a2.x*vf[8] + a2.y*vf[9] + a2.z*vf[10]+ a2.w*vf[11];
        o[cc] = f2b(s);
    }
    u16* op = P + pix*96 + h*12;
    *(short4v*)(op)   = *(short4v*)&o[0];
    *(short4v*)(op+4) = *(short4v*)&o[4];
    *(short4v*)(op+8) = *(short4v*)&o[8];
}

// ---------- FFN multi-scale depthwise, row-sweep; merged kernel, heaviest group FIRST ----------
template<int KS>
__device__ __forceinline__ void ffn_body(const u16* __restrict__ V0,
    const float* __restrict__ wsrc, const float* __restrict__ bsrc, int cbase,
    const float* __restrict__ bn2g, const float* __restrict__ bn2b,
    const float* __restrict__ bn2m, const float* __restrict__ bn2v,
    u16* __restrict__ U, float* wlds, float* bng, float* bnb, float* bnm, float* bnvr,
    int gridx)
{
    constexpr int PAD = KS/2;
    int t = threadIdx.x;
    for (int i=t; i<KS*KS*64; i+=256){
        int tap = i >> 6, cc = i & 63;
        wlds[tap*64 + cc] = wsrc[cc*KS*KS + tap];
    }
    if (t < 64){
        bng[t] = bn2g[cbase+t]; bnb[t] = bn2b[cbase+t];
        bnm[t] = bn2m[cbase+t]; bnvr[t] = rsqrtf(bn2v[cbase+t]+1e-5f);
    }
    __syncthreads();
    int ci = t & 7, seg = t >> 3;
    int bid = blockIdx.x;
    int rowid = (bid & 7)*(gridx >> 3) + (bid >> 3);
    int img = rowid >> 7, hy = rowid & 127;
    int c0r = ci*8;
    int c0 = cbase + c0r;
    int x0 = seg*4;
    float acc[4][8];
    {
        floatx4 b0 = *(const floatx4*)(bsrc + c0r);
        floatx4 b1 = *(const floatx4*)(bsrc + c0r + 4);
        #pragma unroll
        for (int dx=0;dx<4;dx++){
            #pragma unroll
            for (int j=0;j<4;j++){ acc[dx][j]=b0[j]; acc[dx][4+j]=b1[j]; }
        }
    }
    #pragma unroll
    for (int ky=0; ky<KS; ky++){
        int hh = hy + ky - PAD;
        if ((unsigned)hh >= HH) continue;
        float wr[KS][8];
        #pragma unroll
        for (int kx=0; kx<KS; kx++){
            floatx4 wa = *(const floatx4*)&wlds[(ky*KS+kx)*64 + c0r];
            floatx4 wb = *(const floatx4*)&wlds[(ky*KS+kx)*64 + c0r + 4];
            #pragma unroll
            for (int j=0;j<4;j++){ wr[kx][j]=wa[j]; wr[kx][4+j]=wb[j]; }
        }
        const u16* rowp = V0 + ((size_t)(img*HH+hh)*WW)*256 + c0;
        #pragma unroll
        for (int cc=0; cc<4+2*PAD; cc++){
            int cx = x0 - PAD + cc;
            if ((unsigned)cx >= WW) continue;
            short8v v = *(const short8v*)(rowp + (size_t)cx*256);
            float vf[8];
            #pragma unroll
            for (int j=0;j<8;j++) vf[j] = b2f((u16)v[j]);
            #pragma unroll
            for (int dx=0; dx<4; dx++){
                int kx = cc - dx;
                if (kx < 0 || kx >= KS) continue;
                #pragma unroll
                for (int j=0;j<8;j++) acc[dx][j] = fmaf(wr[kx][j], vf[j], acc[dx][j]);
            }
        }
    }
    size_t rbase = (size_t)(img*HH+hy)*WW;
    #pragma unroll
    for (int dx=0; dx<4; dx++){
        size_t pix = rbase + x0 + dx;
        short8v vc = *(const short8v*)(V0 + pix*256 + c0);
        short8v o;
        #pragma unroll
        for (int j=0;j<8;j++){
            float v0c = b2f((u16)vc[j]);
            float u1 = acc[dx][j] + v0c;
            float gl = gelu_fast(u1);
            float bn = (gl - bnm[c0r+j])*bnvr[c0r+j]*bng[c0r+j] + bnb[c0r+j];
            o[j] = (short)f2b(bn*v0c);
        }
        *(short8v*)(U + pix*256 + c0) = o;
    }
}

__global__ __launch_bounds__(256) void ffn_dw_all_k(const u16* __restrict__ V0,
    const float* __restrict__ w0, const float* __restrict__ bb0,
    const float* __restrict__ w1, const float* __restrict__ bb1,
    const float* __restrict__ w2, const float* __restrict__ bb2,
    const float* __restrict__ w3, const float* __restrict__ bb3,
    const float* __restrict__ bn2g, const float* __restrict__ bn2b,
    const float* __restrict__ bn2m, const float* __restrict__ bn2v,
    u16* __restrict__ U)
{
    __shared__ float wlds[49*64];
    __shared__ float bng[64], bnb[64], bnm[64], bnvr[64];
    int gx = gridDim.x;
    switch(blockIdx.y){
        case 0: ffn_body<7>(V0, w3, bb3, 192, bn2g,bn2b,bn2m,bn2v, U, wlds,bng,bnb,bnm,bnvr, gx); break;
        case 1: ffn_body<5>(V0, w2, bb2, 128, bn2g,bn2b,bn2m,bn2v, U, wlds,bng,bnb,bnm,bnvr, gx); break;
        case 2: ffn_body<3>(V0, w1, bb1, 64,  bn2g,bn2b,bn2m,bn2v, U, wlds,bng,bnb,bnm,bnvr, gx); break;
        default: ffn_body<1>(V0, w0, bb0, 0,  bn2g,bn2b,bn2m,bn2v, U, wlds,bng,bnb,bnm,bnvr, gx); break;
    }
}

extern "C" void kernel_launch(void* const* d_in, const int* in_sizes, int n_in,
                              void* d_out, int out_size, void* d_ws, size_t ws_size,
                              hipStream_t stream)
{
    const float* x     = (const float*)d_in[0];
    const float* pos_w = (const float*)d_in[1];
    const float* pos_b = (const float*)d_in[2];
    const float* ln1g  = (const float*)d_in[3];
    const float* ln1b  = (const float*)d_in[4];
    const float* temp  = (const float*)d_in[5];
    const float* qkvw  = (const float*)d_in[6];
    const float* qkvdw = (const float*)d_in[7];
    const float* projw = (const float*)d_in[8];
    const float* gw1   = (const float*)d_in[9];
    const float* gb1   = (const float*)d_in[10];
    const float* gw2   = (const float*)d_in[11];
    const float* gb2   = (const float*)d_in[12];
    const float* a1    = (const float*)d_in[13];
    const float* a2    = (const float*)d_in[14];
    const float* a3    = (const float*)d_in[15];
    const float* a4    = (const float*)d_in[16];
    const float* ln2g  = (const float*)d_in[17];
    const float* ln2b  = (const float*)d_in[18];
    const float* fc1w  = (const float*)d_in[19];
    const float* bn1g  = (const float*)d_in[20];
    const float* bn1b  = (const float*)d_in[21];
    const float* bn1m  = (const float*)d_in[22];
    const float* bn1v  = (const float*)d_in[23];
    const float* bn2g  = (const float*)d_in[24];
    const float* bn2b  = (const float*)d_in[25];
    const float* bn2m  = (const float*)d_in[26];
    const float* bn2v  = (const float*)d_in[27];
    const float* fc2w  = (const float*)d_in[28];
    const float* bn3g  = (const float*)d_in[29];
    const float* bn3b  = (const float*)d_in[30];
    const float* bn3m  = (const float*)d_in[31];
    const float* bn3v  = (const float*)d_in[32];
    const float* dw0w  = (const float*)d_in[33];
    const float* dw0b  = (const float*)d_in[34];
    const float* dw1w  = (const float*)d_in[35];
    const float* dw1b  = (const float*)d_in[36];
    const float* dw2w  = (const float*)d_in[37];
    const float* dw2b  = (const float*)d_in[38];
    const float* dw3w  = (const float*)d_in[39];
    const float* dw3b  = (const float*)d_in[40];

    float* OUT = (float*)d_out;      // final fp32 output (written once by fc2)

    // ---- fixed small buffers + bf16 residual stream A ----
    char* p = (char*)d_ws;
    float* gpix  = (float*)p;                 p += (size_t)NPIX*4;
    float* dynk  = (float*)p;                 p += 256;
    float* gpart = (float*)p;                 p += 64*16*168*4;
    float* gram  = (float*)p;                 p += 64*168*4;
    float* attnW = (float*)p;                 p += 64*144*4;
    float* wposT = (float*)p;                 p += 1728*4;
    u16*   wbf   = (u16*)p;                   p += (size_t)WTOT*2;
    u16*   Abf   = (u16*)p;                   p += (size_t)NPIX*192*2;   // 50.3 MB
    size_t fixedB = (size_t)(p - (char*)d_ws);

    // ---- choose chunk size from ws_size: per-image = Y(192)+B1(288)+B2(288) bf16 ----
    size_t perImg = (size_t)HW*2*(192+288+288);   // 25,165,824
    int CBr = 2;
    if (ws_size >= fixedB + 8*perImg) CBr = 8;
    else if (ws_size >= fixedB + 4*perImg) CBr = 4;
    int NCHUNKr = BB/CBr;
    size_t CHWr = (size_t)CBr*HW;

    u16* Ybf = (u16*)p;                   p += CHWr*192*2;   // two 96-ch planes
    u16* B1  = (u16*)p;                   p += CHWr*288*2;
    u16* B2  = (u16*)p;
    u16* Y0  = Ybf;
    u16* Y1  = Ybf + CHWr*96;
    u16* qkvwb = wbf;
    u16* projwb= wbf + WQ;
    u16* gw1b  = wbf + WQ + WP;
    u16* fc1b  = wbf + WQ + WP + WG;
    u16* fc2b  = wbf + WQ + WP + WG + WF1;
    u16* QKVbf = B1;     // qkv out (288 interleaved)
    u16* QKVdbf= B2;     // qkv_dw out: Q|K|V planes of CHWr*96 each
    u16* P96   = B1;     // attn out (QKV dead)
    u16* Zbf   = B2;     // LN2 out (QKVd dead)
    u16* V0bf  = B1;     // fc1 out (P96 dead)
    u16* Ubf   = B2;     // ffn out (Z dead)

    wprep_k<<<(WTOT+255)/256, 256, 0, stream>>>(qkvw, projw, gw1, fc1w, fc2w,
                                                pos_w, wbf, wposT);
    pos_conv_k<<<NPIX/8, 192, 0, stream>>>(x, wposT, pos_b, Abf);

    // gate phase: LN1 (split planes) -> fused gate GEMM -> gpix
    for (int c=0; c<NCHUNKr; c++){
        const u16* Ab = Abf + (size_t)c*CHWr*192;
        ln_split_k<<<CHWr/4, 256, 0, stream>>>(Ab, ln1g, ln1b, Y0, Y1);
        gate_gemm_k<<<CHWr/128, 256, 0, stream>>>(Y0, Y1, gw1b, gb1, gw2, gb2,
                                                  gpix + (size_t)c*CHWr);
    }
    gate_reduce_k<<<1, 1024, 0, stream>>>(gpix, dynk);

    // main phase
    for (int c=0; c<NCHUNKr; c++){
        u16* Ab = Abf + (size_t)c*CHWr*192;
        if (NCHUNKr > 1)   // single-chunk mode: Y planes from gate phase still valid
            ln_split_k<<<CHWr/4, 256, 0, stream>>>(Ab, ln1g, ln1b, Y0, Y1);
        {   // qkv 1x1: A = dense Y0 plane (K=96), N=288 = 3 x 96-tiles
            dim3 g(CHWr/128, 3);
            gemm_bf16_k<GM_NONE,96,96><<<g, 256, 0, stream>>>(Y0, 96, nullptr, 0,
                qkvwb, QKVbf, 288, nullptr, 0, nullptr,nullptr,nullptr,nullptr, 288);
        }
        size_t pstr = CHWr*96;
        qkv_dw_k<<<CHWr/4*36/256, 256, 0, stream>>>(QKVbf, qkvdw, QKVdbf, pstr);
        { dim3 g(CBr*8, 16); gram_k<<<g, 256, 0, stream>>>(QKVdbf, QKVdbf + pstr, gpart); }
        gram_combine_k<<<(CBr*8*168+255)/256, 256, 0, stream>>>(gpart, gram, CBr*8*168);
        attn_k<<<CBr*8, 256, 0, stream>>>(gram, temp, dynk, a1,a2,a3,a4, attnW);
        attn_apply_k<<<CHWr*8/256, 256, 0, stream>>>(QKVdbf + 2*pstr, attnW, P96);
        {   // proj + residual: A-panels = P96 | Y1 (both dense 96-wide)
            dim3 g(CHWr/128, 2);
            gemm_bf16_k<GM_RES,192,96,true><<<g, 256, 0, stream>>>(P96, 96, Y1, 96,
                projwb, Ab, 192, Ab, 192, nullptr,nullptr,nullptr,nullptr, 192);
        }
        ln_k<<<CHWr/4, 256, 0, stream>>>(Ab, ln2g, ln2b, Zbf);
        {   // fc1: N=256 = 4 x 64-tiles
            dim3 g(CHWr/128, 4);
            gemm_bf16_k<GM_GELU_BN,192,64><<<g, 256, 0, stream>>>(Zbf, 192, nullptr, 0,
                fc1b, V0bf, 256, nullptr, 0, bn1g,bn1b,bn1m,bn1v, 256);
        }
        {   // multi-scale depthwise, heaviest-first merged launch
            int rows = (int)(CHWr/WW);
            dim3 g(rows, 4);
            ffn_dw_all_k<<<g, 256, 0, stream>>>(V0bf, dw0w,dw0b,dw1w,dw1b,dw2w,dw2b,
                                                dw3w,dw3b, bn2g,bn2b,bn2m,bn2v, Ubf);
        }
        {   // fc2 + bn3 + residual -> fp32 OUT: N=192 = 2 x 96-tiles
            dim3 g(CHWr/128, 2);
            gemm_bf16_k<GM_BN_RES,256,96><<<g, 256, 0, stream>>>(Ubf, 256, nullptr, 0,
                fc2b, OUT + (size_t)c*CHWr*192, 192, Ab, 192, bn3g,bn3b,bn3m,bn3v, 192);
        }
    }
}